// Round 8
// baseline (1751.760 us; speedup 1.0000x reference)
//
#include <hip/hip_runtime.h>
#include <math.h>

#define NN 100000
#define NE 1600000
#define DIN 92
#define H 128
#define NB 512
#define DGI 107
#define NL 5

typedef unsigned short u16;
typedef unsigned int u32;
typedef unsigned long long u64;
typedef short bf16x8 __attribute__((ext_vector_type(8)));
typedef float f32x4 __attribute__((ext_vector_type(4)));
typedef _Float16 f16;
typedef _Float16 f16x8 __attribute__((ext_vector_type(8)));
typedef unsigned short u16x8 __attribute__((ext_vector_type(8)));

__device__ __forceinline__ u16 f2bf(float f) {
    unsigned u = __builtin_bit_cast(unsigned, f);
    u += 0x7FFF + ((u >> 16) & 1);
    return (u16)(u >> 16);
}
__device__ __forceinline__ float bf2f(u16 h) {
    unsigned u = ((unsigned)h) << 16;
    return __builtin_bit_cast(float, u);
}

// ---------------- split fp32 -> bf16 hi/lo (activations) ----------------
__global__ void __launch_bounds__(128) k_split(const float* __restrict__ src, int Ksrc, int ld_src,
                                               u16* __restrict__ hi, u16* __restrict__ lo,
                                               int ld_dst, int col_off, int Kfill)
{
    int row = blockIdx.x;
    int k = blockIdx.y * 128 + threadIdx.x;
    if (k >= Kfill) return;
    float v = (k < Ksrc) ? src[(size_t)row * ld_src + k] : 0.f;
    u16 h = f2bf(v);
    float r = v - bf2f(h);
    size_t o = (size_t)row * ld_dst + col_off + k;
    hi[o] = h;
    lo[o] = f2bf(r);
}

// ---------------- all weight splits in ONE launch ----------------
struct WJobs {
    const float* W[9];
    long long eoff[9];
    int K[9];
    int Kpad[9];
};

__global__ void __launch_bounds__(128) k_splitW_all(WJobs jobs, u16* __restrict__ wthi, u16* __restrict__ wtlo)
{
    int j = blockIdx.z;
    int c = blockIdx.x;
    int k = blockIdx.y * 128 + threadIdx.x;
    int Kp = jobs.Kpad[j];
    if (k >= Kp) return;
    const float* W = jobs.W[j];
    float v = (k < jobs.K[j]) ? W[(size_t)k * H + c] : 0.f;
    u16 h = f2bf(v);
    float r = v - bf2f(h);
    size_t o = (size_t)jobs.eoff[j] + (size_t)c * Kp + k;
    wthi[o] = h;
    wtlo[o] = f2bf(r);
}

// ---------------- MFMA GEMM: C[M,128] = act([A1|A2]@W + b), bf16x3 compensated ----------------
// OMODE: 0=f32, 1=bf16 split, 2=fp16 TRANSPOSED slabs [16][NN] int4, 3=fused escore
#define GBM 128

template<int RELU, int OMODE>
__global__ void __launch_bounds__(256) k_mgemm(
    const u16* __restrict__ A1hi, const u16* __restrict__ A1lo, int lda1, int K1,
    const u16* __restrict__ A2hi, const u16* __restrict__ A2lo, int lda2,
    const u16* __restrict__ Wthi, const u16* __restrict__ Wtlo, int Kpad,
    const float* __restrict__ bias,
    float* __restrict__ Cf, u16* __restrict__ Chi, u16* __restrict__ Clo, int ldsp,
    f16* __restrict__ Ch,
    const float* __restrict__ Gow, const float* __restrict__ GobP, float* __restrict__ Esc,
    int M)
{
    __shared__ __align__(16) u16 As[2][128][40];
    __shared__ __align__(16) u16 Ws[2][128][40];
    int tid = threadIdx.x;
    int w = tid >> 6, l = tid & 63;
    int row0 = blockIdx.x * GBM;
    int lr = l & 15, kq = l >> 4;

    f32x4 acc[2][8];
#pragma unroll
    for (int rf = 0; rf < 2; ++rf)
#pragma unroll
        for (int cf = 0; cf < 8; ++cf)
            acc[rf][cf] = (f32x4){0.f, 0.f, 0.f, 0.f};

    for (int k0 = 0; k0 < Kpad; k0 += 32) {
        const u16* sAh = (k0 < K1) ? A1hi : A2hi;
        const u16* sAl = (k0 < K1) ? A1lo : A2lo;
        int ldc = (k0 < K1) ? lda1 : lda2;
        int kc = (k0 < K1) ? k0 : (k0 - K1);
#pragma unroll
        for (int i = 0; i < 2; ++i) {
            int chunk = tid + i * 256;
            int r = chunk >> 2, q = chunk & 3;
            int gr = row0 + r; if (gr >= M) gr = M - 1;
            int4 va = *(const int4*)(sAh + (size_t)gr * ldc + kc + q * 8);
            int4 vb = *(const int4*)(sAl + (size_t)gr * ldc + kc + q * 8);
            int4 wa = *(const int4*)(Wthi + (size_t)r * Kpad + k0 + q * 8);
            int4 wb = *(const int4*)(Wtlo + (size_t)r * Kpad + k0 + q * 8);
            *(int4*)&As[0][r][q * 8] = va;
            *(int4*)&As[1][r][q * 8] = vb;
            *(int4*)&Ws[0][r][q * 8] = wa;
            *(int4*)&Ws[1][r][q * 8] = wb;
        }
        __syncthreads();

        bf16x8 aH[2], aL[2];
#pragma unroll
        for (int rf = 0; rf < 2; ++rf) {
            aH[rf] = *(const bf16x8*)&As[0][w * 32 + rf * 16 + lr][kq * 8];
            aL[rf] = *(const bf16x8*)&As[1][w * 32 + rf * 16 + lr][kq * 8];
        }
#pragma unroll
        for (int cf = 0; cf < 8; ++cf) {
            bf16x8 bH = *(const bf16x8*)&Ws[0][cf * 16 + lr][kq * 8];
            bf16x8 bL = *(const bf16x8*)&Ws[1][cf * 16 + lr][kq * 8];
#pragma unroll
            for (int rf = 0; rf < 2; ++rf) {
                acc[rf][cf] = __builtin_amdgcn_mfma_f32_16x16x32_bf16(aH[rf], bH, acc[rf][cf], 0, 0, 0);
                acc[rf][cf] = __builtin_amdgcn_mfma_f32_16x16x32_bf16(aH[rf], bL, acc[rf][cf], 0, 0, 0);
                acc[rf][cf] = __builtin_amdgcn_mfma_f32_16x16x32_bf16(aL[rf], bH, acc[rf][cf], 0, 0, 0);
            }
        }
        __syncthreads();
    }

    if (OMODE == 3) {
        float gowv[8], bvv[8];
#pragma unroll
        for (int cf = 0; cf < 8; ++cf) {
            gowv[cf] = Gow[cf * 16 + lr];
            bvv[cf] = bias[cf * 16 + lr];
        }
        float gob0 = GobP[0];
#pragma unroll
        for (int rf = 0; rf < 2; ++rf) {
#pragma unroll
            for (int r = 0; r < 4; ++r) {
                float part = 0.f;
#pragma unroll
                for (int cf = 0; cf < 8; ++cf) {
                    float v = fmaxf(acc[rf][cf][r] + bvv[cf], 0.f);
                    part += v * gowv[cf];
                }
                part += __shfl_xor(part, 1);
                part += __shfl_xor(part, 2);
                part += __shfl_xor(part, 4);
                part += __shfl_xor(part, 8);
                int grow = row0 + w * 32 + rf * 16 + kq * 4 + r;
                if (lr == 0 && grow < M) Esc[grow] = part + gob0;
            }
        }
        return;
    }

#pragma unroll
    for (int cf = 0; cf < 8; ++cf) {
        int col = cf * 16 + lr;
        float bv = bias ? bias[col] : 0.f;
#pragma unroll
        for (int rf = 0; rf < 2; ++rf) {
#pragma unroll
            for (int r = 0; r < 4; ++r) {
                int grow = row0 + w * 32 + rf * 16 + kq * 4 + r;
                if (grow < M) {
                    float v = acc[rf][cf][r] + bv;
                    if (RELU) v = fmaxf(v, 0.f);
                    if (OMODE == 0) Cf[(size_t)grow * H + col] = v;
                    if (OMODE == 1) {
                        u16 hh = f2bf(v);
                        Chi[(size_t)grow * ldsp + col] = hh;
                        Clo[(size_t)grow * ldsp + col] = f2bf(v - bf2f(hh));
                    }
                    if (OMODE == 2) {
                        int slab = col >> 3, jj = col & 7;
                        Ch[((size_t)slab * NN + grow) * 8 + jj] = (f16)v;
                    }
                }
            }
        }
    }
}

// ---------------- degree + counts: one packed 64-bit atomic per edge ----------------
__global__ void __launch_bounds__(256) k_deg2(const int* __restrict__ dst, const float* __restrict__ ed,
                                              u64* __restrict__ degcnt, int* __restrict__ rank)
{
    int e = blockIdx.x * 256 + threadIdx.x;
    if (e < NE) {
        int d = dst[e];
        u64 pk = ((u64)1 << 40) | (u64)(ed[e] * 16777216.0f);
        u64 old = atomicAdd(&degcnt[d], pk);
        rank[e] = (int)(old >> 40);
    }
}

__global__ void __launch_bounds__(256) k_dinv2(const u64* __restrict__ degcnt,
                                               float* __restrict__ dinv, float* __restrict__ selfn,
                                               int* __restrict__ cnt)
{
    int n = blockIdx.x * 256 + threadIdx.x;
    if (n < NN) {
        u64 v = degcnt[n];
        int c = (int)(v >> 40);
        float deg = (float)((double)(v & (((u64)1 << 40) - 1)) * (1.0 / 16777216.0));
        float d = deg + 2.0f;
        float dv = 1.0f / sqrtf(d);
        dinv[n] = dv;
        selfn[n] = 2.0f * dv * dv;
        cnt[n] = c;
    }
}

// ---------------- CSR build ----------------
__global__ void __launch_bounds__(256) k_blocksum(const int* __restrict__ cnt, int* __restrict__ bsum, int n)
{
    __shared__ int red[256];
    int t = threadIdx.x;
    int base = blockIdx.x * 1024;
    int s = 0;
#pragma unroll
    for (int j = 0; j < 4; ++j) {
        int i = base + j * 256 + t;
        if (i < n) s += cnt[i];
    }
    red[t] = s; __syncthreads();
    for (int off = 128; off; off >>= 1) {
        if (t < off) red[t] += red[t + off];
        __syncthreads();
    }
    if (t == 0) bsum[blockIdx.x] = red[0];
}

__global__ void k_scanbsum(const int* __restrict__ bsum, int* __restrict__ boff, int nb,
                           int* __restrict__ rp_last, int total)
{
    if (threadIdx.x == 0 && blockIdx.x == 0) {
        int s = 0;
        for (int i = 0; i < nb; ++i) { boff[i] = s; s += bsum[i]; }
        rp_last[0] = total;
    }
}

__global__ void __launch_bounds__(1024) k_scanchunk(const int* __restrict__ cnt, const int* __restrict__ boff,
                                                    int* __restrict__ rp, int n)
{
    __shared__ int sc[1024];
    int t = threadIdx.x;
    int i = blockIdx.x * 1024 + t;
    int own = (i < n) ? cnt[i] : 0;
    sc[t] = own;
    __syncthreads();
    for (int off = 1; off < 1024; off <<= 1) {
        int v = (t >= off) ? sc[t - off] : 0;
        __syncthreads();
        sc[t] += v;
        __syncthreads();
    }
    if (i < n) rp[i] = boff[blockIdx.x] + sc[t] - own;
}

// placement: NO atomics; packed u32 = (f16 w bits [15] << 17) | src (<2^17)
__global__ void __launch_bounds__(256) k_place2(const int* __restrict__ src, const int* __restrict__ dst,
                                                const float* __restrict__ ed, const float* __restrict__ dinv,
                                                const int* __restrict__ rp, const int* __restrict__ rank,
                                                u32* __restrict__ ew)
{
    int e = blockIdx.x * 256 + threadIdx.x;
    if (e < NE) {
        int d = dst[e], s = src[e];
        int pos = rp[d] + rank[e];
        float w = dinv[s] * ed[e] * dinv[d];
        f16 wh = (f16)w;
        u32 wb = (u32)__builtin_bit_cast(u16, wh);
        ew[pos] = (wb << 17) | (u32)s;
    }
}

// ---------------- SpMM: transposed slab gather, feature-group pinned to XCD ----------------
// xT: [16 slabs][NN] int4 (8 fp16 feats per node). group = blockIdx&7 -> XCD (round-robin).
__global__ void __launch_bounds__(256) k_spmmT(
    const int4* __restrict__ xT, const int* __restrict__ rp,
    const u32* __restrict__ ew,
    const float* __restrict__ selfn, const float* __restrict__ cb,
    f16* __restrict__ aggh, double* __restrict__ stats)
{
    int g = blockIdx.x & 7;
    int chunk = blockIdx.x >> 3;
    int tid = threadIdx.x;
    int dslot = tid >> 1;
    int half = tid & 1;
    int slab = g * 2 + half;
    int f0 = slab * 8;
    const int4* xs = xT + (size_t)slab * NN;
    float cbv[8], psum[8], psq[8];
#pragma unroll
    for (int j = 0; j < 8; ++j) { cbv[j] = cb[f0 + j]; psum[j] = 0.f; psq[j] = 0.f; }

    int n = chunk * 128 + dslot;
    if (n < NN) {
        f16x8 xv = __builtin_bit_cast(f16x8, xs[n]);
        float sn = selfn[n];
        float a0[8], a1[8], a2[8], a3[8];
#pragma unroll
        for (int j = 0; j < 8; ++j) {
            a0[j] = sn * (float)xv[j] + cbv[j];
            a1[j] = 0.f; a2[j] = 0.f; a3[j] = 0.f;
        }
        int e = rp[n], end = rp[n + 1];
        for (; e + 4 <= end; e += 4) {
            u32 p0 = ew[e], p1 = ew[e + 1], p2 = ew[e + 2], p3 = ew[e + 3];
            float w0 = (float)__builtin_bit_cast(f16, (u16)(p0 >> 17));
            float w1 = (float)__builtin_bit_cast(f16, (u16)(p1 >> 17));
            float w2 = (float)__builtin_bit_cast(f16, (u16)(p2 >> 17));
            float w3 = (float)__builtin_bit_cast(f16, (u16)(p3 >> 17));
            f16x8 v0 = __builtin_bit_cast(f16x8, xs[p0 & 0x1FFFF]);
            f16x8 v1 = __builtin_bit_cast(f16x8, xs[p1 & 0x1FFFF]);
            f16x8 v2 = __builtin_bit_cast(f16x8, xs[p2 & 0x1FFFF]);
            f16x8 v3 = __builtin_bit_cast(f16x8, xs[p3 & 0x1FFFF]);
#pragma unroll
            for (int j = 0; j < 8; ++j) {
                a0[j] += w0 * (float)v0[j];
                a1[j] += w1 * (float)v1[j];
                a2[j] += w2 * (float)v2[j];
                a3[j] += w3 * (float)v3[j];
            }
        }
        for (; e < end; ++e) {
            u32 p = ew[e];
            float w0 = (float)__builtin_bit_cast(f16, (u16)(p >> 17));
            f16x8 v0 = __builtin_bit_cast(f16x8, xs[p & 0x1FFFF]);
#pragma unroll
            for (int j = 0; j < 8; ++j) a0[j] += w0 * (float)v0[j];
        }
        float ax[8];
        f16x8 ah;
#pragma unroll
        for (int j = 0; j < 8; ++j) {
            ax[j] = (a0[j] + a1[j]) + (a2[j] + a3[j]);
            psum[j] += ax[j];
            psq[j] += ax[j] * ax[j];
            ah[j] = (f16)ax[j];
        }
        *(f16x8*)(aggh + (size_t)n * H + f0) = ah;
    }

    __shared__ float ssum[256][8], ssq[256][8];
#pragma unroll
    for (int j = 0; j < 8; ++j) { ssum[tid][j] = psum[j]; ssq[tid][j] = psq[j]; }
    __syncthreads();
    if (tid < 16) {
        int hf = tid >> 3, j = tid & 7;
        float s = 0.f, q = 0.f;
        for (int d = 0; d < 128; ++d) { s += ssum[2 * d + hf][j]; q += ssq[2 * d + hf][j]; }
        atomicAdd(&stats[g * 16 + tid], (double)s);
        atomicAdd(&stats[128 + g * 16 + tid], (double)q);
    }
}

// finalize BN scale/shift; self-zero stats for next layer
__global__ void k_finalize(double* __restrict__ stats, const float* __restrict__ bn_g,
                           const float* __restrict__ bn_b, float* __restrict__ scale,
                           float* __restrict__ shift)
{
    int f = threadIdx.x; // 128
    double mu = stats[f] / (double)NN;
    double var = stats[128 + f] / (double)NN - mu * mu;
    double rs = 1.0 / sqrt(var + 1e-5);
    float sc = (float)((double)bn_g[f] * rs);
    scale[f] = sc;
    shift[f] = (float)((double)bn_b[f] - mu * (double)sc);
    stats[f] = 0.0;
    stats[128 + f] = 0.0;
}

// BN + residual from fp16 agg; x kept as bf16 hi/lo split
__global__ void __launch_bounds__(256) k_bnres(const f16* __restrict__ aggh, const float* __restrict__ scale,
                                               const float* __restrict__ shift,
                                               u16* __restrict__ xhi, u16* __restrict__ xlo)
{
    int i8 = blockIdx.x * 256 + threadIdx.x;
    if (i8 >= NN * 16) return;
    int f0 = (i8 & 15) * 8;
    f16x8 a = ((const f16x8*)aggh)[i8];
    u16x8 hh = ((const u16x8*)xhi)[i8];
    u16x8 ll = ((const u16x8*)xlo)[i8];
#pragma unroll
    for (int j = 0; j < 8; ++j) {
        float v = bf2f(hh[j]) + bf2f(ll[j]) + (float)a[j] * scale[f0 + j] + shift[f0 + j];
        u16 h = f2bf(v);
        hh[j] = h;
        ll[j] = f2bf(v - bf2f(h));
    }
    ((u16x8*)xhi)[i8] = hh;
    ((u16x8*)xlo)[i8] = ll;
}

// ---------------- segment softmax machinery ----------------
__global__ void __launch_bounds__(256) k_gcnt(const int* __restrict__ batch, int* __restrict__ gcnt)
{
    int n = blockIdx.x * 256 + threadIdx.x;
    if (n < NN) atomicAdd(&gcnt[batch[n]], 1);
}

__global__ void __launch_bounds__(512) k_goff(const int* __restrict__ gcnt, int* __restrict__ goff)
{
    __shared__ int sc[512];
    int t = threadIdx.x;
    sc[t] = gcnt[t];
    __syncthreads();
    for (int off = 1; off < 512; off <<= 1) {
        int v = (t >= off) ? sc[t - off] : 0;
        __syncthreads();
        sc[t] += v;
        __syncthreads();
    }
    goff[t + 1] = sc[t];
    if (t == 0) goff[0] = 0;
}

__global__ void __launch_bounds__(256) k_segsoftmax(const float* __restrict__ e, const int* __restrict__ goff,
                                                    float* __restrict__ w)
{
    int b = blockIdx.x;
    int beg = goff[b], end = goff[b + 1];
    int t = threadIdx.x;
    __shared__ float red[8], red2[8];
    float m = -INFINITY;
    for (int i = beg + t; i < end; i += 256) m = fmaxf(m, e[i]);
    for (int off = 32; off; off >>= 1) m = fmaxf(m, __shfl_down(m, off));
    if ((t & 63) == 0) red[t >> 6] = m;
    __syncthreads();
    float m0 = fmaxf(fmaxf(red[0], red[1]), fmaxf(red[2], red[3]));
    float s = 0.f;
    for (int i = beg + t; i < end; i += 256) s += expf(e[i] - m0);
    for (int off = 32; off; off >>= 1) s += __shfl_down(s, off);
    if ((t & 63) == 0) red2[t >> 6] = s;
    __syncthreads();
    float s0 = red2[0] + red2[1] + red2[2] + red2[3];
    for (int i = beg + t; i < end; i += 256) w[i] = expf(e[i] - m0) / s0;
}

// reconstruct x from split, scale by node weight, write f32 (into xw)
__global__ void __launch_bounds__(256) k_scalex(const u16* __restrict__ xhi, const u16* __restrict__ xlo,
                                                const float* __restrict__ w, float* __restrict__ xf)
{
    int i4 = blockIdx.x * 256 + threadIdx.x;
    if (i4 >= NN * 32) return;
    float ww = w[i4 >> 5];
    ushort4 hh = ((const ushort4*)xhi)[i4];
    ushort4 ll = ((const ushort4*)xlo)[i4];
    float4 v;
    v.x = (bf2f(hh.x) + bf2f(ll.x)) * ww;
    v.y = (bf2f(hh.y) + bf2f(ll.y)) * ww;
    v.z = (bf2f(hh.z) + bf2f(ll.z)) * ww;
    v.w = (bf2f(hh.w) + bf2f(ll.w)) * ww;
    ((float4*)xf)[i4] = v;
}

// ---------------- Set2Set: fused gates + LSTM, 8 graphs per block ----------------
__device__ __forceinline__ float sigmoidf_(float v) { return 1.f / (1.f + expf(-v)); }

__global__ void __launch_bounds__(256) k_gateslstm(
    const float* __restrict__ qstar, const float* __restrict__ Wih, const float* __restrict__ Whh,
    const float* __restrict__ bih, const float* __restrict__ bhh,
    float* __restrict__ cs, float* __restrict__ hs)
{
    __shared__ float qs[8][256];
    __shared__ float hh[8][128];
    __shared__ float gs[8][512];
    int t = threadIdx.x;
    int b0 = blockIdx.x * 8;
    for (int i = t; i < 8 * 256; i += 256) qs[i >> 8][i & 255] = qstar[b0 * 256 + i];
    for (int i = t; i < 8 * 128; i += 256) hh[i >> 7][i & 127] = hs[b0 * 128 + i];
    __syncthreads();
    for (int gg = t; gg < 512; gg += 256) {
        float acc[8];
        float bb = bih[gg] + bhh[gg];
#pragma unroll
        for (int g = 0; g < 8; ++g) acc[g] = bb;
        const float4* w4 = (const float4*)(Wih + (size_t)gg * 256);
        for (int k = 0; k < 64; ++k) {
            float4 w = w4[k];
#pragma unroll
            for (int g = 0; g < 8; ++g) {
                float4 q = *(const float4*)&qs[g][k * 4];
                acc[g] += q.x * w.x + q.y * w.y + q.z * w.z + q.w * w.w;
            }
        }
        const float4* v4 = (const float4*)(Whh + (size_t)gg * 128);
        for (int k = 0; k < 32; ++k) {
            float4 w = v4[k];
#pragma unroll
            for (int g = 0; g < 8; ++g) {
                float4 q = *(const float4*)&hh[g][k * 4];
                acc[g] += q.x * w.x + q.y * w.y + q.z * w.z + q.w * w.w;
            }
        }
#pragma unroll
        for (int g = 0; g < 8; ++g) gs[g][gg] = acc[g];
    }
    __syncthreads();
    for (int i = t; i < 1024; i += 256) {
        int g = i >> 7, f = i & 127;
        int idx = (b0 + g) * 128 + f;
        float gi = gs[g][f], gf = gs[g][128 + f], gg2 = gs[g][256 + f], go = gs[g][384 + f];
        float c = sigmoidf_(gf) * cs[idx] + sigmoidf_(gi) * tanhf(gg2);
        cs[idx] = c;
        hs[idx] = sigmoidf_(go) * tanhf(c);
    }
}

__global__ void __launch_bounds__(256) k_en(const float* __restrict__ x, const float* __restrict__ hs,
                                            const int* __restrict__ batch, float* __restrict__ en)
{
    int wave = threadIdx.x >> 6, lane = threadIdx.x & 63;
    int n = blockIdx.x * 4 + wave;
    if (n >= NN) return;
    int b = batch[n];
    float2 xv = *(const float2*)(x + (size_t)n * H + lane * 2);
    float2 qv = *(const float2*)(hs + (size_t)b * H + lane * 2);
    float p = xv.x * qv.x + xv.y * qv.y;
    for (int off = 32; off; off >>= 1) p += __shfl_down(p, off);
    if (lane == 0) en[n] = p;
}

__global__ void __launch_bounds__(256) k_r(const float* __restrict__ a, const float* __restrict__ x,
                                           const int* __restrict__ goff, const float* __restrict__ hs,
                                           float* __restrict__ qstar)
{
    __shared__ float part[128];
    int b = blockIdx.x, t = threadIdx.x;
    int f = t & 127, half = t >> 7;
    int beg = goff[b], end = goff[b + 1];
    float acc = 0.f;
    for (int i = beg + half; i < end; i += 2) acc += a[i] * x[(size_t)i * H + f];
    if (half) part[f] = acc;
    __syncthreads();
    if (!half) {
        acc += part[f];
        qstar[b * 256 + f] = hs[b * 128 + f];
        qstar[b * 256 + 128 + f] = acc;
    }
}

// ---------------- head ----------------
__global__ void __launch_bounds__(256) k_head1(const float* __restrict__ qstar, const float* __restrict__ W,
                                               const float* __restrict__ bias, float* __restrict__ y1)
{
    __shared__ float qs[256];
    int b = blockIdx.x, t = threadIdx.x;
    qs[t] = qstar[b * 256 + t];
    __syncthreads();
    float acc = bias[t];
    for (int k = 0; k < 256; ++k) acc += qs[k] * W[k * 256 + t];
    y1[b * 256 + t] = fmaxf(acc, 0.f);
}

__global__ void __launch_bounds__(256) k_head2(const float* __restrict__ y1, const float* __restrict__ W1,
                                               const float* __restrict__ b1, const float* __restrict__ W2,
                                               const float* __restrict__ b2, float* __restrict__ out)
{
    __shared__ float ys[256];
    __shared__ float z[32];
    int b = blockIdx.x, t = threadIdx.x;
    ys[t] = y1[b * 256 + t];
    __syncthreads();
    if (t < 32) {
        float acc = b1[t];
        for (int k = 0; k < 256; ++k) acc += ys[k] * W1[k * 32 + t];
        z[t] = fmaxf(acc, 0.f);
    }
    __syncthreads();
    if (t == 0) {
        float s = b2[0];
        for (int j = 0; j < 32; ++j) s += z[j] * W2[j];
        out[b] = s;
    }
}

// ---------------- launch ----------------
extern "C" void kernel_launch(void* const* d_in, const int* in_sizes, int n_in,
                              void* d_out, int out_size, void* d_ws, size_t ws_size,
                              hipStream_t stream)
{
    const float* in_x        = (const float*)d_in[0];
    const int*   edge_index  = (const int*)d_in[1];
    const float* edge_dist   = (const float*)d_in[2];
    const float* global_info = (const float*)d_in[3];
    const int*   batch       = (const int*)d_in[4];
    const float* lin_W  = (const float*)d_in[5];
    const float* lin_b  = (const float*)d_in[6];
    const float* conv_W = (const float*)d_in[7];
    const float* conv_b = (const float*)d_in[8];
    const float* bn_g   = (const float*)d_in[9];
    const float* bn_b   = (const float*)d_in[10];
    const float* gat_in_W  = (const float*)d_in[11];
    const float* gat_in_b  = (const float*)d_in[12];
    const float* gat_lin_W = (const float*)d_in[13];
    const float* gat_lin_b = (const float*)d_in[14];
    const float* gat_out_W = (const float*)d_in[15];
    const float* gat_out_b = (const float*)d_in[16];
    const float* lstm_Wih = (const float*)d_in[17];
    const float* lstm_Whh = (const float*)d_in[18];
    const float* lstm_bih = (const float*)d_in[19];
    const float* lstm_bhh = (const float*)d_in[20];
    const float* mlp_W  = (const float*)d_in[21];
    const float* mlp_b  = (const float*)d_in[22];
    const float* out1_W = (const float*)d_in[23];
    const float* out1_b = (const float*)d_in[24];
    const float* out2_W = (const float*)d_in[25];
    const float* out2_b = (const float*)d_in[26];
    float* out = (float*)d_out;

    const int* e_src = edge_index;
    const int* e_dst = edge_index + NE;

    char* p = (char*)d_ws;
    auto alloc = [&](size_t bytes) -> void* {
        void* r = (void*)p;
        p += (bytes + 255) & ~(size_t)255;
        return r;
    };
    u16*    cx_hi = (u16*)alloc((size_t)NN * H * 2);
    u16*    cx_lo = (u16*)alloc((size_t)NN * H * 2);
    float*  xw    = (float*)alloc((size_t)NN * H * 4);   // xT slabs (conv) / f32 scaled-x (Set2Set)
    float*  agg   = (float*)alloc((size_t)NN * H * 4);   // fp16 aggh; CSR: degcnt+rank; gat: gi split
    u16*    wthi  = (u16*)alloc((size_t)160000 * 2);
    u16*    wtlo  = (u16*)alloc((size_t)160000 * 2);
    float*  dinv  = (float*)alloc((size_t)NN * 4);
    float*  selfn = (float*)alloc((size_t)NN * 4);
    int*    cnt   = (int*)alloc((size_t)NN * 4);
    int*    rp    = (int*)alloc((size_t)(NN + 1) * 4);
    int*    bsum  = (int*)alloc(128 * 4);
    int*    boff  = (int*)alloc(128 * 4);
    u32*    ew    = (u32*)alloc((size_t)NE * 4);         // packed (w:f16<<17 | src); Set2Set aliases
    double* stats = (double*)alloc(256 * 8);
    float*  scale = (float*)alloc(128 * 4);
    float*  shift = (float*)alloc(128 * 4);

    f16*   xTh    = (f16*)xw;                        // transposed slab table (conv stack)
    f16*   aggh   = (f16*)agg;
    u64*   degcnt = (u64*)agg;
    int*   rank   = (int*)((char*)agg + (1 << 20));
    u16*   gi_hi  = (u16*)agg;
    u16*   gi_lo  = gi_hi + (size_t)NN * H;
    float* esc    = dinv;
    float* wn     = selfn;
    int*   gcnt   = cnt;
    int*   goff   = cnt + NB;
    float* hs     = (float*)ew;
    float* csb    = hs + NB * H;
    float* qstar  = csb + NB * H;
    float* y1     = qstar + NB * 2 * H;

    const int GB_E = (NE + 255) / 256;
    const int GB_N = (NN + 255) / 256;
    const int NCH = (NN + 1023) / 1024;
    const int GB_MG = (NN + GBM - 1) / GBM;
    const int GB_SPT = 8 * ((NN + 127) / 128);
    const int GB_V4 = (NN * 32) / 256;
    const int GB_V8 = (NN * 16) / 256 + 1;
    const int GB_W = (NN + 3) / 4;

    // ---- all weight splits, one launch ----
    WJobs jobs;
    const float* Wl[9] = {lin_W, conv_W, conv_W + (size_t)H * H, conv_W + (size_t)2 * H * H,
                          conv_W + (size_t)3 * H * H, conv_W + (size_t)4 * H * H,
                          gat_in_W, gat_lin_W, gat_lin_W + (size_t)H * H};
    int Ks[9]  = {DIN, H, H, H, H, H, H + DGI, H, H};
    int Kps[9] = {96, H, H, H, H, H, 256, H, H};
    long long eoffs[9];
    long long eo = 0;
    for (int i = 0; i < 9; ++i) {
        jobs.W[i] = Wl[i]; jobs.K[i] = Ks[i]; jobs.Kpad[i] = Kps[i]; jobs.eoff[i] = eo;
        eoffs[i] = eo;
        eo += (long long)128 * Kps[i];
    }
    k_splitW_all<<<dim3(128, 2, 9), 128, 0, stream>>>(jobs, wthi, wtlo);

    // ---- graph norm + CSR ----
    hipMemsetAsync(degcnt, 0, (size_t)NN * 8, stream);
    hipMemsetAsync(stats, 0, 256 * 8, stream);
    k_deg2<<<GB_E, 256, 0, stream>>>(e_dst, edge_dist, degcnt, rank);
    k_dinv2<<<GB_N, 256, 0, stream>>>(degcnt, dinv, selfn, cnt);
    k_blocksum<<<NCH, 256, 0, stream>>>(cnt, bsum, NN);
    k_scanbsum<<<1, 64, 0, stream>>>(bsum, boff, NCH, rp + NN, NE);
    k_scanchunk<<<NCH, 1024, 0, stream>>>(cnt, boff, rp, NN);
    k_place2<<<GB_E, 256, 0, stream>>>(e_src, e_dst, edge_dist, dinv, rp, rank, ew);

    // ---- input projection ----
    k_split<<<dim3(NN, 1), 128, 0, stream>>>(in_x, DIN, DIN, cx_hi, cx_lo, H, 0, 96);
    k_mgemm<1, 1><<<GB_MG, 256, 0, stream>>>(cx_hi, cx_lo, H, 96, cx_hi, cx_lo, H,
                                             wthi + eoffs[0], wtlo + eoffs[0], 96, lin_b,
                                             nullptr, cx_hi, cx_lo, H, nullptr,
                                             nullptr, nullptr, nullptr, NN);

    // ---- conv stack ----
    for (int l = 0; l < NL; ++l) {
        k_mgemm<0, 2><<<GB_MG, 256, 0, stream>>>(cx_hi, cx_lo, H, H, cx_hi, cx_lo, H,
                                                 wthi + eoffs[1 + l], wtlo + eoffs[1 + l], H, nullptr,
                                                 nullptr, nullptr, nullptr, 0, xTh,
                                                 nullptr, nullptr, nullptr, NN);
        k_spmmT<<<GB_SPT, 256, 0, stream>>>((const int4*)xTh, rp, ew, selfn,
                                            conv_b + (size_t)l * H, aggh, stats);
        k_finalize<<<1, 128, 0, stream>>>(stats, bn_g, bn_b, scale, shift);
        k_bnres<<<GB_V8, 256, 0, stream>>>(aggh, scale, shift, cx_hi, cx_lo);
    }

    // ---- global attention ----
    k_split<<<dim3(NN, 1), 128, 0, stream>>>(global_info, DGI, DGI, gi_hi, gi_lo, H, 0, H);
    k_mgemm<1, 1><<<GB_MG, 256, 0, stream>>>(cx_hi, cx_lo, H, H, gi_hi, gi_lo, H,
                                             wthi + eoffs[6], wtlo + eoffs[6], 256, gat_in_b,
                                             nullptr, gi_hi, gi_lo, H, nullptr,
                                             nullptr, nullptr, nullptr, NN);
    k_mgemm<1, 1><<<GB_MG, 256, 0, stream>>>(gi_hi, gi_lo, H, H, gi_hi, gi_lo, H,
                                             wthi + eoffs[7], wtlo + eoffs[7], H, gat_lin_b,
                                             nullptr, gi_hi, gi_lo, H, nullptr,
                                             nullptr, nullptr, nullptr, NN);
    k_mgemm<1, 3><<<GB_MG, 256, 0, stream>>>(gi_hi, gi_lo, H, H, gi_hi, gi_lo, H,
                                             wthi + eoffs[8], wtlo + eoffs[8], H, gat_lin_b + H,
                                             nullptr, nullptr, nullptr, 0, nullptr,
                                             gat_out_W, gat_out_b, esc, NN);
    hipMemsetAsync(gcnt, 0, NB * 4, stream);
    k_gcnt<<<GB_N, 256, 0, stream>>>(batch, gcnt);
    k_goff<<<1, 512, 0, stream>>>(gcnt, goff);
    k_segsoftmax<<<NB, 256, 0, stream>>>(esc, goff, wn);
    k_scalex<<<GB_V4, 256, 0, stream>>>(cx_hi, cx_lo, wn, xw);   // overwrites xT region (dead)

    // ---- Set2Set (hs/csb/qstar alias ew region, dead after conv stack) ----
    hipMemsetAsync(hs, 0, (size_t)NB * H * 4, stream);
    hipMemsetAsync(csb, 0, (size_t)NB * H * 4, stream);
    hipMemsetAsync(qstar, 0, (size_t)NB * 2 * H * 4, stream);
    for (int it = 0; it < 3; ++it) {
        k_gateslstm<<<NB / 8, 256, 0, stream>>>(qstar, lstm_Wih, lstm_Whh, lstm_bih, lstm_bhh, csb, hs);
        k_en<<<GB_W, 256, 0, stream>>>(xw, hs, batch, esc);
        k_segsoftmax<<<NB, 256, 0, stream>>>(esc, goff, wn);
        k_r<<<NB, 256, 0, stream>>>(wn, xw, goff, hs, qstar);
    }

    // ---- head ----
    k_head1<<<NB, 256, 0, stream>>>(qstar, mlp_W, mlp_b, y1);
    k_head2<<<NB, 256, 0, stream>>>(y1, out1_W, out1_b, out2_W, out2_b, out);
}

// Round 9
// 1547.339 us; speedup vs baseline: 1.1321x; 1.1321x over previous
//
#include <hip/hip_runtime.h>
#include <math.h>

#define NN 100000
#define NE 1600000
#define DIN 92
#define H 128
#define NB 512
#define DGI 107
#define NL 5

typedef unsigned short u16;
typedef unsigned int u32;
typedef unsigned long long u64;
typedef short bf16x8 __attribute__((ext_vector_type(8)));
typedef float f32x4 __attribute__((ext_vector_type(4)));
typedef _Float16 f16;
typedef _Float16 f16x8 __attribute__((ext_vector_type(8)));
typedef unsigned short u16x8 __attribute__((ext_vector_type(8)));

__device__ __forceinline__ u16 f2bf(float f) {
    unsigned u = __builtin_bit_cast(unsigned, f);
    u += 0x7FFF + ((u >> 16) & 1);
    return (u16)(u >> 16);
}
__device__ __forceinline__ float bf2f(u16 h) {
    unsigned u = ((unsigned)h) << 16;
    return __builtin_bit_cast(float, u);
}

// ---------------- split fp32 -> bf16 hi/lo (activations) ----------------
__global__ void __launch_bounds__(128) k_split(const float* __restrict__ src, int Ksrc, int ld_src,
                                               u16* __restrict__ hi, u16* __restrict__ lo,
                                               int ld_dst, int col_off, int Kfill)
{
    int row = blockIdx.x;
    int k = blockIdx.y * 128 + threadIdx.x;
    if (k >= Kfill) return;
    float v = (k < Ksrc) ? src[(size_t)row * ld_src + k] : 0.f;
    u16 h = f2bf(v);
    float r = v - bf2f(h);
    size_t o = (size_t)row * ld_dst + col_off + k;
    hi[o] = h;
    lo[o] = f2bf(r);
}

// ---------------- all weight splits in ONE launch ----------------
struct WJobs {
    const float* W[9];
    long long eoff[9];
    int K[9];
    int Kpad[9];
};

__global__ void __launch_bounds__(128) k_splitW_all(WJobs jobs, u16* __restrict__ wthi, u16* __restrict__ wtlo)
{
    int j = blockIdx.z;
    int c = blockIdx.x;
    int k = blockIdx.y * 128 + threadIdx.x;
    int Kp = jobs.Kpad[j];
    if (k >= Kp) return;
    const float* W = jobs.W[j];
    float v = (k < jobs.K[j]) ? W[(size_t)k * H + c] : 0.f;
    u16 h = f2bf(v);
    float r = v - bf2f(h);
    size_t o = (size_t)jobs.eoff[j] + (size_t)c * Kp + k;
    wthi[o] = h;
    wtlo[o] = f2bf(r);
}

// ---------------- MFMA GEMM: C[M,128] = act([A1|A2]@W + b), bf16x3 compensated ----------------
// OMODE: 0=f32, 1=bf16 split, 2=fp16 row-major, 3=fused escore
#define GBM 128

template<int RELU, int OMODE>
__global__ void __launch_bounds__(256) k_mgemm(
    const u16* __restrict__ A1hi, const u16* __restrict__ A1lo, int lda1, int K1,
    const u16* __restrict__ A2hi, const u16* __restrict__ A2lo, int lda2,
    const u16* __restrict__ Wthi, const u16* __restrict__ Wtlo, int Kpad,
    const float* __restrict__ bias,
    float* __restrict__ Cf, u16* __restrict__ Chi, u16* __restrict__ Clo, int ldsp,
    f16* __restrict__ Ch,
    const float* __restrict__ Gow, const float* __restrict__ GobP, float* __restrict__ Esc,
    int M)
{
    __shared__ __align__(16) u16 As[2][128][40];
    __shared__ __align__(16) u16 Ws[2][128][40];
    int tid = threadIdx.x;
    int w = tid >> 6, l = tid & 63;
    int row0 = blockIdx.x * GBM;
    int lr = l & 15, kq = l >> 4;

    f32x4 acc[2][8];
#pragma unroll
    for (int rf = 0; rf < 2; ++rf)
#pragma unroll
        for (int cf = 0; cf < 8; ++cf)
            acc[rf][cf] = (f32x4){0.f, 0.f, 0.f, 0.f};

    for (int k0 = 0; k0 < Kpad; k0 += 32) {
        const u16* sAh = (k0 < K1) ? A1hi : A2hi;
        const u16* sAl = (k0 < K1) ? A1lo : A2lo;
        int ldc = (k0 < K1) ? lda1 : lda2;
        int kc = (k0 < K1) ? k0 : (k0 - K1);
#pragma unroll
        for (int i = 0; i < 2; ++i) {
            int chunk = tid + i * 256;
            int r = chunk >> 2, q = chunk & 3;
            int gr = row0 + r; if (gr >= M) gr = M - 1;
            int4 va = *(const int4*)(sAh + (size_t)gr * ldc + kc + q * 8);
            int4 vb = *(const int4*)(sAl + (size_t)gr * ldc + kc + q * 8);
            int4 wa = *(const int4*)(Wthi + (size_t)r * Kpad + k0 + q * 8);
            int4 wb = *(const int4*)(Wtlo + (size_t)r * Kpad + k0 + q * 8);
            *(int4*)&As[0][r][q * 8] = va;
            *(int4*)&As[1][r][q * 8] = vb;
            *(int4*)&Ws[0][r][q * 8] = wa;
            *(int4*)&Ws[1][r][q * 8] = wb;
        }
        __syncthreads();

        bf16x8 aH[2], aL[2];
#pragma unroll
        for (int rf = 0; rf < 2; ++rf) {
            aH[rf] = *(const bf16x8*)&As[0][w * 32 + rf * 16 + lr][kq * 8];
            aL[rf] = *(const bf16x8*)&As[1][w * 32 + rf * 16 + lr][kq * 8];
        }
#pragma unroll
        for (int cf = 0; cf < 8; ++cf) {
            bf16x8 bH = *(const bf16x8*)&Ws[0][cf * 16 + lr][kq * 8];
            bf16x8 bL = *(const bf16x8*)&Ws[1][cf * 16 + lr][kq * 8];
#pragma unroll
            for (int rf = 0; rf < 2; ++rf) {
                acc[rf][cf] = __builtin_amdgcn_mfma_f32_16x16x32_bf16(aH[rf], bH, acc[rf][cf], 0, 0, 0);
                acc[rf][cf] = __builtin_amdgcn_mfma_f32_16x16x32_bf16(aH[rf], bL, acc[rf][cf], 0, 0, 0);
                acc[rf][cf] = __builtin_amdgcn_mfma_f32_16x16x32_bf16(aL[rf], bH, acc[rf][cf], 0, 0, 0);
            }
        }
        __syncthreads();
    }

    if (OMODE == 3) {
        float gowv[8], bvv[8];
#pragma unroll
        for (int cf = 0; cf < 8; ++cf) {
            gowv[cf] = Gow[cf * 16 + lr];
            bvv[cf] = bias[cf * 16 + lr];
        }
        float gob0 = GobP[0];
#pragma unroll
        for (int rf = 0; rf < 2; ++rf) {
#pragma unroll
            for (int r = 0; r < 4; ++r) {
                float part = 0.f;
#pragma unroll
                for (int cf = 0; cf < 8; ++cf) {
                    float v = fmaxf(acc[rf][cf][r] + bvv[cf], 0.f);
                    part += v * gowv[cf];
                }
                part += __shfl_xor(part, 1);
                part += __shfl_xor(part, 2);
                part += __shfl_xor(part, 4);
                part += __shfl_xor(part, 8);
                int grow = row0 + w * 32 + rf * 16 + kq * 4 + r;
                if (lr == 0 && grow < M) Esc[grow] = part + gob0;
            }
        }
        return;
    }

#pragma unroll
    for (int cf = 0; cf < 8; ++cf) {
        int col = cf * 16 + lr;
        float bv = bias ? bias[col] : 0.f;
#pragma unroll
        for (int rf = 0; rf < 2; ++rf) {
#pragma unroll
            for (int r = 0; r < 4; ++r) {
                int grow = row0 + w * 32 + rf * 16 + kq * 4 + r;
                if (grow < M) {
                    float v = acc[rf][cf][r] + bv;
                    if (RELU) v = fmaxf(v, 0.f);
                    if (OMODE == 0) Cf[(size_t)grow * H + col] = v;
                    if (OMODE == 1) {
                        u16 hh = f2bf(v);
                        Chi[(size_t)grow * ldsp + col] = hh;
                        Clo[(size_t)grow * ldsp + col] = f2bf(v - bf2f(hh));
                    }
                    if (OMODE == 2) Ch[(size_t)grow * H + col] = (f16)v;
                }
            }
        }
    }
}

// ---------------- degree + counts: one packed 64-bit atomic per edge ----------------
__global__ void __launch_bounds__(256) k_deg2(const int* __restrict__ dst, const float* __restrict__ ed,
                                              u64* __restrict__ degcnt, int* __restrict__ rank)
{
    int e = blockIdx.x * 256 + threadIdx.x;
    if (e < NE) {
        int d = dst[e];
        u64 pk = ((u64)1 << 40) | (u64)(ed[e] * 16777216.0f);
        u64 old = atomicAdd(&degcnt[d], pk);
        rank[e] = (int)(old >> 40);
    }
}

__global__ void __launch_bounds__(256) k_dinv2(const u64* __restrict__ degcnt,
                                               float* __restrict__ dinv, float* __restrict__ selfn,
                                               int* __restrict__ cnt)
{
    int n = blockIdx.x * 256 + threadIdx.x;
    if (n < NN) {
        u64 v = degcnt[n];
        int c = (int)(v >> 40);
        float deg = (float)((double)(v & (((u64)1 << 40) - 1)) * (1.0 / 16777216.0));
        float d = deg + 2.0f;
        float dv = 1.0f / sqrtf(d);
        dinv[n] = dv;
        selfn[n] = 2.0f * dv * dv;
        cnt[n] = c;
    }
}

// ---------------- CSR build ----------------
__global__ void __launch_bounds__(256) k_blocksum(const int* __restrict__ cnt, int* __restrict__ bsum, int n)
{
    __shared__ int red[256];
    int t = threadIdx.x;
    int base = blockIdx.x * 1024;
    int s = 0;
#pragma unroll
    for (int j = 0; j < 4; ++j) {
        int i = base + j * 256 + t;
        if (i < n) s += cnt[i];
    }
    red[t] = s; __syncthreads();
    for (int off = 128; off; off >>= 1) {
        if (t < off) red[t] += red[t + off];
        __syncthreads();
    }
    if (t == 0) bsum[blockIdx.x] = red[0];
}

__global__ void k_scanbsum(const int* __restrict__ bsum, int* __restrict__ boff, int nb,
                           int* __restrict__ rp_last, int total)
{
    if (threadIdx.x == 0 && blockIdx.x == 0) {
        int s = 0;
        for (int i = 0; i < nb; ++i) { boff[i] = s; s += bsum[i]; }
        rp_last[0] = total;
    }
}

__global__ void __launch_bounds__(1024) k_scanchunk(const int* __restrict__ cnt, const int* __restrict__ boff,
                                                    int* __restrict__ rp, int n)
{
    __shared__ int sc[1024];
    int t = threadIdx.x;
    int i = blockIdx.x * 1024 + t;
    int own = (i < n) ? cnt[i] : 0;
    sc[t] = own;
    __syncthreads();
    for (int off = 1; off < 1024; off <<= 1) {
        int v = (t >= off) ? sc[t - off] : 0;
        __syncthreads();
        sc[t] += v;
        __syncthreads();
    }
    if (i < n) rp[i] = boff[blockIdx.x] + sc[t] - own;
}

// placement: NO atomics; packed u32 = (f16 w bits [15] << 17) | src (<2^17)
__global__ void __launch_bounds__(256) k_place2(const int* __restrict__ src, const int* __restrict__ dst,
                                                const float* __restrict__ ed, const float* __restrict__ dinv,
                                                const int* __restrict__ rp, const int* __restrict__ rank,
                                                u32* __restrict__ ew)
{
    int e = blockIdx.x * 256 + threadIdx.x;
    if (e < NE) {
        int d = dst[e], s = src[e];
        int pos = rp[d] + rank[e];
        float w = dinv[s] * ed[e] * dinv[d];
        f16 wh = (f16)w;
        u32 wb = (u32)__builtin_bit_cast(u16, wh);
        ew[pos] = (wb << 17) | (u32)s;
    }
}

// ---------------- SpMM (fp16 row-major gather, u32 packed edges, nt streams) ----------------
__global__ void __launch_bounds__(256) k_spmm(
    const f16* __restrict__ xwh, const int* __restrict__ rp,
    const u32* __restrict__ ew,
    const float* __restrict__ selfn, const float* __restrict__ cb,
    f16* __restrict__ aggh, double* __restrict__ stats)
{
    int tid = threadIdx.x;
    int slot = tid >> 4;          // 0..15
    int sl = tid & 15;
    int f0 = sl * 8;
    float cbv[8], psum[8], psq[8];
#pragma unroll
    for (int j = 0; j < 8; ++j) { cbv[j] = cb[f0 + j]; psum[j] = 0.f; psq[j] = 0.f; }
    int base = blockIdx.x * 32 + slot * 2;

    for (int i = 0; i < 2; ++i) {
        int n = base + i;
        if (n >= NN) break;
        f16x8 xv = *(const f16x8*)(xwh + (size_t)n * H + f0);
        float sn = selfn[n];
        float a0[8], a1[8], a2[8], a3[8];
#pragma unroll
        for (int j = 0; j < 8; ++j) {
            a0[j] = sn * (float)xv[j] + cbv[j];
            a1[j] = 0.f; a2[j] = 0.f; a3[j] = 0.f;
        }
        int e = rp[n], end = rp[n + 1];
        for (; e + 4 <= end; e += 4) {
            u32 p0 = __builtin_nontemporal_load(ew + e);
            u32 p1 = __builtin_nontemporal_load(ew + e + 1);
            u32 p2 = __builtin_nontemporal_load(ew + e + 2);
            u32 p3 = __builtin_nontemporal_load(ew + e + 3);
            float w0 = (float)__builtin_bit_cast(f16, (u16)(p0 >> 17));
            float w1 = (float)__builtin_bit_cast(f16, (u16)(p1 >> 17));
            float w2 = (float)__builtin_bit_cast(f16, (u16)(p2 >> 17));
            float w3 = (float)__builtin_bit_cast(f16, (u16)(p3 >> 17));
            f16x8 v0 = *(const f16x8*)(xwh + (size_t)(p0 & 0x1FFFF) * H + f0);
            f16x8 v1 = *(const f16x8*)(xwh + (size_t)(p1 & 0x1FFFF) * H + f0);
            f16x8 v2 = *(const f16x8*)(xwh + (size_t)(p2 & 0x1FFFF) * H + f0);
            f16x8 v3 = *(const f16x8*)(xwh + (size_t)(p3 & 0x1FFFF) * H + f0);
#pragma unroll
            for (int j = 0; j < 8; ++j) {
                a0[j] += w0 * (float)v0[j];
                a1[j] += w1 * (float)v1[j];
                a2[j] += w2 * (float)v2[j];
                a3[j] += w3 * (float)v3[j];
            }
        }
        for (; e < end; ++e) {
            u32 p = __builtin_nontemporal_load(ew + e);
            float w0 = (float)__builtin_bit_cast(f16, (u16)(p >> 17));
            f16x8 v0 = *(const f16x8*)(xwh + (size_t)(p & 0x1FFFF) * H + f0);
#pragma unroll
            for (int j = 0; j < 8; ++j) a0[j] += w0 * (float)v0[j];
        }
        float ax[8];
        f16x8 ah;
#pragma unroll
        for (int j = 0; j < 8; ++j) {
            ax[j] = (a0[j] + a1[j]) + (a2[j] + a3[j]);
            psum[j] += ax[j];
            psq[j] += ax[j] * ax[j];
            ah[j] = (f16)ax[j];
        }
        __builtin_nontemporal_store(ah, (f16x8*)(aggh + (size_t)n * H + f0));
    }

    __shared__ float ssum[16][128], ssq[16][128];
#pragma unroll
    for (int j = 0; j < 8; ++j) { ssum[slot][f0 + j] = psum[j]; ssq[slot][f0 + j] = psq[j]; }
    __syncthreads();
    if (tid < 128) {
        float s = 0.f, q = 0.f;
#pragma unroll
        for (int j = 0; j < 16; ++j) { s += ssum[j][tid]; q += ssq[j][tid]; }
        atomicAdd(&stats[tid], (double)s);
        atomicAdd(&stats[128 + tid], (double)q);
    }
}

// finalize BN scale/shift; self-zero stats for next layer
__global__ void k_finalize(double* __restrict__ stats, const float* __restrict__ bn_g,
                           const float* __restrict__ bn_b, float* __restrict__ scale,
                           float* __restrict__ shift)
{
    int f = threadIdx.x; // 128
    double mu = stats[f] / (double)NN;
    double var = stats[128 + f] / (double)NN - mu * mu;
    double rs = 1.0 / sqrt(var + 1e-5);
    float sc = (float)((double)bn_g[f] * rs);
    scale[f] = sc;
    shift[f] = (float)((double)bn_b[f] - mu * (double)sc);
    stats[f] = 0.0;
    stats[128 + f] = 0.0;
}

// BN + residual from fp16 agg; x kept as bf16 hi/lo split
__global__ void __launch_bounds__(256) k_bnres(const f16* __restrict__ aggh, const float* __restrict__ scale,
                                               const float* __restrict__ shift,
                                               u16* __restrict__ xhi, u16* __restrict__ xlo)
{
    int i8 = blockIdx.x * 256 + threadIdx.x;
    if (i8 >= NN * 16) return;
    int f0 = (i8 & 15) * 8;
    f16x8 a = ((const f16x8*)aggh)[i8];
    u16x8 hh = ((const u16x8*)xhi)[i8];
    u16x8 ll = ((const u16x8*)xlo)[i8];
#pragma unroll
    for (int j = 0; j < 8; ++j) {
        float v = bf2f(hh[j]) + bf2f(ll[j]) + (float)a[j] * scale[f0 + j] + shift[f0 + j];
        u16 h = f2bf(v);
        hh[j] = h;
        ll[j] = f2bf(v - bf2f(h));
    }
    ((u16x8*)xhi)[i8] = hh;
    ((u16x8*)xlo)[i8] = ll;
}

// ---------------- goff from SORTED batch: boundary detection, no atomics ----------------
__global__ void __launch_bounds__(256) k_goff2(const int* __restrict__ batch, int* __restrict__ goff)
{
    int n = blockIdx.x * 256 + threadIdx.x;
    if (n >= NN) return;
    int b = batch[n];
    if (n == 0) {
        for (int j = 0; j <= b; ++j) goff[j] = 0;
    }
    int nb = (n == NN - 1) ? NB : batch[n + 1];
    for (int j = b + 1; j <= nb; ++j) goff[j] = n + 1;
}

__global__ void __launch_bounds__(256) k_segsoftmax(const float* __restrict__ e, const int* __restrict__ goff,
                                                    float* __restrict__ w)
{
    int b = blockIdx.x;
    int beg = goff[b], end = goff[b + 1];
    int t = threadIdx.x;
    __shared__ float red[8], red2[8];
    float m = -INFINITY;
    for (int i = beg + t; i < end; i += 256) m = fmaxf(m, e[i]);
    for (int off = 32; off; off >>= 1) m = fmaxf(m, __shfl_down(m, off));
    if ((t & 63) == 0) red[t >> 6] = m;
    __syncthreads();
    float m0 = fmaxf(fmaxf(red[0], red[1]), fmaxf(red[2], red[3]));
    float s = 0.f;
    for (int i = beg + t; i < end; i += 256) s += expf(e[i] - m0);
    for (int off = 32; off; off >>= 1) s += __shfl_down(s, off);
    if ((t & 63) == 0) red2[t >> 6] = s;
    __syncthreads();
    float s0 = red2[0] + red2[1] + red2[2] + red2[3];
    for (int i = beg + t; i < end; i += 256) w[i] = expf(e[i] - m0) / s0;
}

// reconstruct x from split, scale by node weight, write f32 (into xw)
__global__ void __launch_bounds__(256) k_scalex(const u16* __restrict__ xhi, const u16* __restrict__ xlo,
                                                const float* __restrict__ w, float* __restrict__ xf)
{
    int i4 = blockIdx.x * 256 + threadIdx.x;
    if (i4 >= NN * 32) return;
    float ww = w[i4 >> 5];
    ushort4 hh = ((const ushort4*)xhi)[i4];
    ushort4 ll = ((const ushort4*)xlo)[i4];
    float4 v;
    v.x = (bf2f(hh.x) + bf2f(ll.x)) * ww;
    v.y = (bf2f(hh.y) + bf2f(ll.y)) * ww;
    v.z = (bf2f(hh.z) + bf2f(ll.z)) * ww;
    v.w = (bf2f(hh.w) + bf2f(ll.w)) * ww;
    ((float4*)xf)[i4] = v;
}

// ---------------- Set2Set: fused gates + LSTM, 8 graphs per block ----------------
__device__ __forceinline__ float sigmoidf_(float v) { return 1.f / (1.f + expf(-v)); }

__global__ void __launch_bounds__(256) k_gateslstm(
    const float* __restrict__ qstar, const float* __restrict__ Wih, const float* __restrict__ Whh,
    const float* __restrict__ bih, const float* __restrict__ bhh,
    float* __restrict__ cs, float* __restrict__ hs)
{
    __shared__ float qs[8][256];
    __shared__ float hh[8][128];
    __shared__ float gs[8][512];
    int t = threadIdx.x;
    int b0 = blockIdx.x * 8;
    for (int i = t; i < 8 * 256; i += 256) qs[i >> 8][i & 255] = qstar[b0 * 256 + i];
    for (int i = t; i < 8 * 128; i += 256) hh[i >> 7][i & 127] = hs[b0 * 128 + i];
    __syncthreads();
    for (int gg = t; gg < 512; gg += 256) {
        float acc[8];
        float bb = bih[gg] + bhh[gg];
#pragma unroll
        for (int g = 0; g < 8; ++g) acc[g] = bb;
        const float4* w4 = (const float4*)(Wih + (size_t)gg * 256);
        for (int k = 0; k < 64; ++k) {
            float4 w = w4[k];
#pragma unroll
            for (int g = 0; g < 8; ++g) {
                float4 q = *(const float4*)&qs[g][k * 4];
                acc[g] += q.x * w.x + q.y * w.y + q.z * w.z + q.w * w.w;
            }
        }
        const float4* v4 = (const float4*)(Whh + (size_t)gg * 128);
        for (int k = 0; k < 32; ++k) {
            float4 w = v4[k];
#pragma unroll
            for (int g = 0; g < 8; ++g) {
                float4 q = *(const float4*)&hh[g][k * 4];
                acc[g] += q.x * w.x + q.y * w.y + q.z * w.z + q.w * w.w;
            }
        }
#pragma unroll
        for (int g = 0; g < 8; ++g) gs[g][gg] = acc[g];
    }
    __syncthreads();
    for (int i = t; i < 1024; i += 256) {
        int g = i >> 7, f = i & 127;
        int idx = (b0 + g) * 128 + f;
        float gi = gs[g][f], gf = gs[g][128 + f], gg2 = gs[g][256 + f], go = gs[g][384 + f];
        float c = sigmoidf_(gf) * cs[idx] + sigmoidf_(gi) * tanhf(gg2);
        cs[idx] = c;
        hs[idx] = sigmoidf_(go) * tanhf(c);
    }
}

// ---------------- Set2Set fused attention: en + segment softmax + r, one block per graph ----------------
__global__ void __launch_bounds__(256) k_s2s(const float* __restrict__ x, const float* __restrict__ hs,
                                             const int* __restrict__ goff,
                                             float* __restrict__ esc, float* __restrict__ qstar)
{
    __shared__ float q[128];
    __shared__ float red[4], red2[4];
    __shared__ float partr[128];
    int b = blockIdx.x, t = threadIdx.x;
    int beg = goff[b], end = goff[b + 1];
    if (t < 128) q[t] = hs[b * 128 + t];
    __syncthreads();

    int wv = t >> 6, ln = t & 63;
    // pass 1: en scores + wave max
    float m = -INFINITY;
    for (int i = beg + wv; i < end; i += 4) {
        float2 xv = *(const float2*)(x + (size_t)i * H + ln * 2);
        float2 qv = *(const float2*)(q + ln * 2);
        float pd = xv.x * qv.x + xv.y * qv.y;
        for (int off = 32; off; off >>= 1) pd += __shfl_down(pd, off);
        pd = __shfl(pd, 0);
        if (ln == 0) esc[i] = pd;
        m = fmaxf(m, pd);
    }
    if (ln == 0) red[wv] = m;
    __syncthreads();
    float m0 = fmaxf(fmaxf(red[0], red[1]), fmaxf(red[2], red[3]));
    // pass 1b: exp + sum (store unnormalized weight back to esc)
    float s = 0.f;
    for (int i = beg + t; i < end; i += 256) {
        float e = expf(esc[i] - m0);
        esc[i] = e;
        s += e;
    }
    for (int off = 32; off; off >>= 1) s += __shfl_down(s, off);
    if (ln == 0) red2[wv] = s;
    __syncthreads();
    float s0 = red2[0] + red2[1] + red2[2] + red2[3];
    float inv = (s0 > 0.f) ? 1.f / s0 : 0.f;
    // pass 2: r = sum w * x
    int f = t & 127, half = t >> 7;
    float acc = 0.f;
    for (int i = beg + half; i < end; i += 2)
        acc += esc[i] * x[(size_t)i * H + f];
    if (half) partr[f] = acc;
    __syncthreads();
    if (!half) {
        acc += partr[f];
        qstar[b * 256 + f] = q[f];
        qstar[b * 256 + 128 + f] = acc * inv;
    }
}

// ---------------- head ----------------
__global__ void __launch_bounds__(256) k_head1(const float* __restrict__ qstar, const float* __restrict__ W,
                                               const float* __restrict__ bias, float* __restrict__ y1)
{
    __shared__ float qs[256];
    int b = blockIdx.x, t = threadIdx.x;
    qs[t] = qstar[b * 256 + t];
    __syncthreads();
    float acc = bias[t];
    for (int k = 0; k < 256; ++k) acc += qs[k] * W[k * 256 + t];
    y1[b * 256 + t] = fmaxf(acc, 0.f);
}

__global__ void __launch_bounds__(256) k_head2(const float* __restrict__ y1, const float* __restrict__ W1,
                                               const float* __restrict__ b1, const float* __restrict__ W2,
                                               const float* __restrict__ b2, float* __restrict__ out)
{
    __shared__ float ys[256];
    __shared__ float z[32];
    int b = blockIdx.x, t = threadIdx.x;
    ys[t] = y1[b * 256 + t];
    __syncthreads();
    if (t < 32) {
        float acc = b1[t];
        for (int k = 0; k < 256; ++k) acc += ys[k] * W1[k * 32 + t];
        z[t] = fmaxf(acc, 0.f);
    }
    __syncthreads();
    if (t == 0) {
        float s = b2[0];
        for (int j = 0; j < 32; ++j) s += z[j] * W2[j];
        out[b] = s;
    }
}

// ---------------- launch ----------------
extern "C" void kernel_launch(void* const* d_in, const int* in_sizes, int n_in,
                              void* d_out, int out_size, void* d_ws, size_t ws_size,
                              hipStream_t stream)
{
    const float* in_x        = (const float*)d_in[0];
    const int*   edge_index  = (const int*)d_in[1];
    const float* edge_dist   = (const float*)d_in[2];
    const float* global_info = (const float*)d_in[3];
    const int*   batch       = (const int*)d_in[4];
    const float* lin_W  = (const float*)d_in[5];
    const float* lin_b  = (const float*)d_in[6];
    const float* conv_W = (const float*)d_in[7];
    const float* conv_b = (const float*)d_in[8];
    const float* bn_g   = (const float*)d_in[9];
    const float* bn_b   = (const float*)d_in[10];
    const float* gat_in_W  = (const float*)d_in[11];
    const float* gat_in_b  = (const float*)d_in[12];
    const float* gat_lin_W = (const float*)d_in[13];
    const float* gat_lin_b = (const float*)d_in[14];
    const float* gat_out_W = (const float*)d_in[15];
    const float* gat_out_b = (const float*)d_in[16];
    const float* lstm_Wih = (const float*)d_in[17];
    const float* lstm_Whh = (const float*)d_in[18];
    const float* lstm_bih = (const float*)d_in[19];
    const float* lstm_bhh = (const float*)d_in[20];
    const float* mlp_W  = (const float*)d_in[21];
    const float* mlp_b  = (const float*)d_in[22];
    const float* out1_W = (const float*)d_in[23];
    const float* out1_b = (const float*)d_in[24];
    const float* out2_W = (const float*)d_in[25];
    const float* out2_b = (const float*)d_in[26];
    float* out = (float*)d_out;

    const int* e_src = edge_index;
    const int* e_dst = edge_index + NE;

    char* p = (char*)d_ws;
    auto alloc = [&](size_t bytes) -> void* {
        void* r = (void*)p;
        p += (bytes + 255) & ~(size_t)255;
        return r;
    };
    u16*    cx_hi = (u16*)alloc((size_t)NN * H * 2);
    u16*    cx_lo = (u16*)alloc((size_t)NN * H * 2);
    float*  xw    = (float*)alloc((size_t)NN * H * 4);   // fp16 xwh (conv) / f32 scaled-x (Set2Set)
    float*  agg   = (float*)alloc((size_t)NN * H * 4);   // fp16 aggh; CSR: degcnt+rank; gat: gi split
    u16*    wthi  = (u16*)alloc((size_t)160000 * 2);
    u16*    wtlo  = (u16*)alloc((size_t)160000 * 2);
    float*  dinv  = (float*)alloc((size_t)NN * 4);
    float*  selfn = (float*)alloc((size_t)NN * 4);
    int*    cnt   = (int*)alloc((size_t)NN * 4);
    int*    rp    = (int*)alloc((size_t)(NN + 1) * 4);
    int*    bsum  = (int*)alloc(128 * 4);
    int*    boff  = (int*)alloc(128 * 4);
    u32*    ew    = (u32*)alloc((size_t)NE * 4);         // packed (w:f16<<17 | src); Set2Set aliases
    double* stats = (double*)alloc(256 * 8);
    float*  scale = (float*)alloc(128 * 4);
    float*  shift = (float*)alloc(128 * 4);

    f16*   xwh    = (f16*)xw;
    f16*   aggh   = (f16*)agg;
    u64*   degcnt = (u64*)agg;
    int*   rank   = (int*)((char*)agg + (1 << 20));
    u16*   gi_hi  = (u16*)agg;
    u16*   gi_lo  = gi_hi + (size_t)NN * H;
    float* esc    = dinv;
    float* wn     = selfn;
    int*   goff   = cnt;
    float* hs     = (float*)ew;
    float* csb    = hs + NB * H;
    float* qstar  = csb + NB * H;
    float* y1     = qstar + NB * 2 * H;

    const int GB_E = (NE + 255) / 256;
    const int GB_N = (NN + 255) / 256;
    const int NCH = (NN + 1023) / 1024;
    const int GB_MG = (NN + GBM - 1) / GBM;
    const int GB_SPMM = (NN + 31) / 32;
    const int GB_V4 = (NN * 32) / 256;
    const int GB_V8 = (NN * 16) / 256 + 1;

    // ---- all weight splits, one launch ----
    WJobs jobs;
    const float* Wl[9] = {lin_W, conv_W, conv_W + (size_t)H * H, conv_W + (size_t)2 * H * H,
                          conv_W + (size_t)3 * H * H, conv_W + (size_t)4 * H * H,
                          gat_in_W, gat_lin_W, gat_lin_W + (size_t)H * H};
    int Ks[9]  = {DIN, H, H, H, H, H, H + DGI, H, H};
    int Kps[9] = {96, H, H, H, H, H, 256, H, H};
    long long eoffs[9];
    long long eo = 0;
    for (int i = 0; i < 9; ++i) {
        jobs.W[i] = Wl[i]; jobs.K[i] = Ks[i]; jobs.Kpad[i] = Kps[i]; jobs.eoff[i] = eo;
        eoffs[i] = eo;
        eo += (long long)128 * Kps[i];
    }
    k_splitW_all<<<dim3(128, 2, 9), 128, 0, stream>>>(jobs, wthi, wtlo);

    // ---- graph norm + CSR ----
    hipMemsetAsync(degcnt, 0, (size_t)NN * 8, stream);
    hipMemsetAsync(stats, 0, 256 * 8, stream);
    k_deg2<<<GB_E, 256, 0, stream>>>(e_dst, edge_dist, degcnt, rank);
    k_dinv2<<<GB_N, 256, 0, stream>>>(degcnt, dinv, selfn, cnt);
    k_blocksum<<<NCH, 256, 0, stream>>>(cnt, bsum, NN);
    k_scanbsum<<<1, 64, 0, stream>>>(bsum, boff, NCH, rp + NN, NE);
    k_scanchunk<<<NCH, 1024, 0, stream>>>(cnt, boff, rp, NN);
    k_place2<<<GB_E, 256, 0, stream>>>(e_src, e_dst, edge_dist, dinv, rp, rank, ew);

    // ---- input projection ----
    k_split<<<dim3(NN, 1), 128, 0, stream>>>(in_x, DIN, DIN, cx_hi, cx_lo, H, 0, 96);
    k_mgemm<1, 1><<<GB_MG, 256, 0, stream>>>(cx_hi, cx_lo, H, 96, cx_hi, cx_lo, H,
                                             wthi + eoffs[0], wtlo + eoffs[0], 96, lin_b,
                                             nullptr, cx_hi, cx_lo, H, nullptr,
                                             nullptr, nullptr, nullptr, NN);

    // ---- conv stack ----
    for (int l = 0; l < NL; ++l) {
        k_mgemm<0, 2><<<GB_MG, 256, 0, stream>>>(cx_hi, cx_lo, H, H, cx_hi, cx_lo, H,
                                                 wthi + eoffs[1 + l], wtlo + eoffs[1 + l], H, nullptr,
                                                 nullptr, nullptr, nullptr, 0, xwh,
                                                 nullptr, nullptr, nullptr, NN);
        k_spmm<<<GB_SPMM, 256, 0, stream>>>(xwh, rp, ew, selfn, conv_b + (size_t)l * H, aggh, stats);
        k_finalize<<<1, 128, 0, stream>>>(stats, bn_g, bn_b, scale, shift);
        k_bnres<<<GB_V8, 256, 0, stream>>>(aggh, scale, shift, cx_hi, cx_lo);
    }

    // ---- global attention ----
    k_split<<<dim3(NN, 1), 128, 0, stream>>>(global_info, DGI, DGI, gi_hi, gi_lo, H, 0, H);
    k_mgemm<1, 1><<<GB_MG, 256, 0, stream>>>(cx_hi, cx_lo, H, H, gi_hi, gi_lo, H,
                                             wthi + eoffs[6], wtlo + eoffs[6], 256, gat_in_b,
                                             nullptr, gi_hi, gi_lo, H, nullptr,
                                             nullptr, nullptr, nullptr, NN);
    k_mgemm<1, 1><<<GB_MG, 256, 0, stream>>>(gi_hi, gi_lo, H, H, gi_hi, gi_lo, H,
                                             wthi + eoffs[7], wtlo + eoffs[7], H, gat_lin_b,
                                             nullptr, gi_hi, gi_lo, H, nullptr,
                                             nullptr, nullptr, nullptr, NN);
    k_mgemm<1, 3><<<GB_MG, 256, 0, stream>>>(gi_hi, gi_lo, H, H, gi_hi, gi_lo, H,
                                             wthi + eoffs[8], wtlo + eoffs[8], H, gat_lin_b + H,
                                             nullptr, nullptr, nullptr, 0, nullptr,
                                             gat_out_W, gat_out_b, esc, NN);
    k_goff2<<<GB_N, 256, 0, stream>>>(batch, goff);
    k_segsoftmax<<<NB, 256, 0, stream>>>(esc, goff, wn);
    k_scalex<<<GB_V4, 256, 0, stream>>>(cx_hi, cx_lo, wn, xw);   // overwrites xwh region (dead)

    // ---- Set2Set (hs/csb/qstar alias ew region, dead after conv stack) ----
    hipMemsetAsync(hs, 0, (size_t)NB * H * 4, stream);
    hipMemsetAsync(csb, 0, (size_t)NB * H * 4, stream);
    hipMemsetAsync(qstar, 0, (size_t)NB * 2 * H * 4, stream);
    for (int it = 0; it < 3; ++it) {
        k_gateslstm<<<NB / 8, 256, 0, stream>>>(qstar, lstm_Wih, lstm_Whh, lstm_bih, lstm_bhh, csb, hs);
        k_s2s<<<NB, 256, 0, stream>>>(xw, hs, goff, esc, qstar);
    }

    // ---- head ----
    k_head1<<<NB, 256, 0, stream>>>(qstar, mlp_W, mlp_b, y1);
    k_head2<<<NB, 256, 0, stream>>>(y1, out1_W, out1_b, out2_W, out2_b, out);
}

// Round 10
// 1418.956 us; speedup vs baseline: 1.2345x; 1.0905x over previous
//
#include <hip/hip_runtime.h>
#include <math.h>

#define NN 100000
#define NE 1600000
#define DIN 92
#define H 128
#define NB 512
#define DGI 107
#define NL 5

typedef unsigned short u16;
typedef unsigned int u32;
typedef unsigned long long u64;
typedef short bf16x8 __attribute__((ext_vector_type(8)));
typedef float f32x4 __attribute__((ext_vector_type(4)));
typedef _Float16 f16;
typedef _Float16 f16x8 __attribute__((ext_vector_type(8)));
typedef unsigned short u16x8 __attribute__((ext_vector_type(8)));

__device__ __forceinline__ u16 f2bf(float f) {
    unsigned u = __builtin_bit_cast(unsigned, f);
    u += 0x7FFF + ((u >> 16) & 1);
    return (u16)(u >> 16);
}
__device__ __forceinline__ float bf2f(u16 h) {
    unsigned u = ((unsigned)h) << 16;
    return __builtin_bit_cast(float, u);
}

// ---------------- split fp32 -> bf16 hi/lo (activations) ----------------
__global__ void __launch_bounds__(128) k_split(const float* __restrict__ src, int Ksrc, int ld_src,
                                               u16* __restrict__ hi, u16* __restrict__ lo,
                                               int ld_dst, int col_off, int Kfill)
{
    int row = blockIdx.x;
    int k = blockIdx.y * 128 + threadIdx.x;
    if (k >= Kfill) return;
    float v = (k < Ksrc) ? src[(size_t)row * ld_src + k] : 0.f;
    u16 h = f2bf(v);
    float r = v - bf2f(h);
    size_t o = (size_t)row * ld_dst + col_off + k;
    hi[o] = h;
    lo[o] = f2bf(r);
}

// ---------------- all weight splits in ONE launch ----------------
struct WJobs {
    const float* W[9];
    long long eoff[9];
    int K[9];
    int Kpad[9];
};

__global__ void __launch_bounds__(128) k_splitW_all(WJobs jobs, u16* __restrict__ wthi, u16* __restrict__ wtlo)
{
    int j = blockIdx.z;
    int c = blockIdx.x;
    int k = blockIdx.y * 128 + threadIdx.x;
    int Kp = jobs.Kpad[j];
    if (k >= Kp) return;
    const float* W = jobs.W[j];
    float v = (k < jobs.K[j]) ? W[(size_t)k * H + c] : 0.f;
    u16 h = f2bf(v);
    float r = v - bf2f(h);
    size_t o = (size_t)jobs.eoff[j] + (size_t)c * Kp + k;
    wthi[o] = h;
    wtlo[o] = f2bf(r);
}

// ---------------- MFMA GEMM: C[M,128] = act([A1|A2]@W + b), bf16x3 compensated ----------------
// OMODE: 0=f32, 1=bf16 split, 2=fp16 row-major, 3=fused escore. KPAD compile-time -> full unroll.
#define GBM 128

template<int RELU, int OMODE, int KPAD>
__global__ void __launch_bounds__(256) k_mgemm(
    const u16* __restrict__ A1hi, const u16* __restrict__ A1lo, int lda1, int K1,
    const u16* __restrict__ A2hi, const u16* __restrict__ A2lo, int lda2,
    const u16* __restrict__ Wthi, const u16* __restrict__ Wtlo,
    const float* __restrict__ bias,
    float* __restrict__ Cf, u16* __restrict__ Chi, u16* __restrict__ Clo, int ldsp,
    f16* __restrict__ Ch,
    const float* __restrict__ Gow, const float* __restrict__ GobP, float* __restrict__ Esc,
    int M)
{
    __shared__ __align__(16) u16 As[2][128][40];
    __shared__ __align__(16) u16 Ws[2][128][40];
    int tid = threadIdx.x;
    int w = tid >> 6, l = tid & 63;
    int row0 = blockIdx.x * GBM;
    int lr = l & 15, kq = l >> 4;

    f32x4 acc[2][8];
#pragma unroll
    for (int rf = 0; rf < 2; ++rf)
#pragma unroll
        for (int cf = 0; cf < 8; ++cf)
            acc[rf][cf] = (f32x4){0.f, 0.f, 0.f, 0.f};

#pragma unroll
    for (int k0 = 0; k0 < KPAD; k0 += 32) {
        const u16* sAh = (k0 < K1) ? A1hi : A2hi;
        const u16* sAl = (k0 < K1) ? A1lo : A2lo;
        int ldc = (k0 < K1) ? lda1 : lda2;
        int kc = (k0 < K1) ? k0 : (k0 - K1);
#pragma unroll
        for (int i = 0; i < 2; ++i) {
            int chunk = tid + i * 256;
            int r = chunk >> 2, q = chunk & 3;
            int gr = row0 + r; if (gr >= M) gr = M - 1;
            int4 va = *(const int4*)(sAh + (size_t)gr * ldc + kc + q * 8);
            int4 vb = *(const int4*)(sAl + (size_t)gr * ldc + kc + q * 8);
            int4 wa = *(const int4*)(Wthi + (size_t)r * KPAD + k0 + q * 8);
            int4 wb = *(const int4*)(Wtlo + (size_t)r * KPAD + k0 + q * 8);
            *(int4*)&As[0][r][q * 8] = va;
            *(int4*)&As[1][r][q * 8] = vb;
            *(int4*)&Ws[0][r][q * 8] = wa;
            *(int4*)&Ws[1][r][q * 8] = wb;
        }
        __syncthreads();

        bf16x8 aH[2], aL[2];
#pragma unroll
        for (int rf = 0; rf < 2; ++rf) {
            aH[rf] = *(const bf16x8*)&As[0][w * 32 + rf * 16 + lr][kq * 8];
            aL[rf] = *(const bf16x8*)&As[1][w * 32 + rf * 16 + lr][kq * 8];
        }
#pragma unroll
        for (int cf = 0; cf < 8; ++cf) {
            bf16x8 bH = *(const bf16x8*)&Ws[0][cf * 16 + lr][kq * 8];
            bf16x8 bL = *(const bf16x8*)&Ws[1][cf * 16 + lr][kq * 8];
#pragma unroll
            for (int rf = 0; rf < 2; ++rf) {
                acc[rf][cf] = __builtin_amdgcn_mfma_f32_16x16x32_bf16(aH[rf], bH, acc[rf][cf], 0, 0, 0);
                acc[rf][cf] = __builtin_amdgcn_mfma_f32_16x16x32_bf16(aH[rf], bL, acc[rf][cf], 0, 0, 0);
                acc[rf][cf] = __builtin_amdgcn_mfma_f32_16x16x32_bf16(aL[rf], bH, acc[rf][cf], 0, 0, 0);
            }
        }
        __syncthreads();
    }

    if (OMODE == 3) {
        float gowv[8], bvv[8];
#pragma unroll
        for (int cf = 0; cf < 8; ++cf) {
            gowv[cf] = Gow[cf * 16 + lr];
            bvv[cf] = bias[cf * 16 + lr];
        }
        float gob0 = GobP[0];
#pragma unroll
        for (int rf = 0; rf < 2; ++rf) {
#pragma unroll
            for (int r = 0; r < 4; ++r) {
                float part = 0.f;
#pragma unroll
                for (int cf = 0; cf < 8; ++cf) {
                    float v = fmaxf(acc[rf][cf][r] + bvv[cf], 0.f);
                    part += v * gowv[cf];
                }
                part += __shfl_xor(part, 1);
                part += __shfl_xor(part, 2);
                part += __shfl_xor(part, 4);
                part += __shfl_xor(part, 8);
                int grow = row0 + w * 32 + rf * 16 + kq * 4 + r;
                if (lr == 0 && grow < M) Esc[grow] = part + gob0;
            }
        }
        return;
    }

#pragma unroll
    for (int cf = 0; cf < 8; ++cf) {
        int col = cf * 16 + lr;
        float bv = bias ? bias[col] : 0.f;
#pragma unroll
        for (int rf = 0; rf < 2; ++rf) {
#pragma unroll
            for (int r = 0; r < 4; ++r) {
                int grow = row0 + w * 32 + rf * 16 + kq * 4 + r;
                if (grow < M) {
                    float v = acc[rf][cf][r] + bv;
                    if (RELU) v = fmaxf(v, 0.f);
                    if (OMODE == 0) Cf[(size_t)grow * H + col] = v;
                    if (OMODE == 1) {
                        u16 hh = f2bf(v);
                        Chi[(size_t)grow * ldsp + col] = hh;
                        Clo[(size_t)grow * ldsp + col] = f2bf(v - bf2f(hh));
                    }
                    if (OMODE == 2) Ch[(size_t)grow * H + col] = (f16)v;
                }
            }
        }
    }
}

// ---------------- degree + counts: one packed 64-bit atomic per edge ----------------
__global__ void __launch_bounds__(256) k_deg2(const int* __restrict__ dst, const float* __restrict__ ed,
                                              u64* __restrict__ degcnt, int* __restrict__ rank)
{
    int e = blockIdx.x * 256 + threadIdx.x;
    if (e < NE) {
        int d = dst[e];
        u64 pk = ((u64)1 << 40) | (u64)(ed[e] * 16777216.0f);
        u64 old = atomicAdd(&degcnt[d], pk);
        rank[e] = (int)(old >> 40);
    }
}

__global__ void __launch_bounds__(256) k_dinv2(const u64* __restrict__ degcnt,
                                               float* __restrict__ dinv, float* __restrict__ selfn,
                                               int* __restrict__ cnt)
{
    int n = blockIdx.x * 256 + threadIdx.x;
    if (n < NN) {
        u64 v = degcnt[n];
        int c = (int)(v >> 40);
        float deg = (float)((double)(v & (((u64)1 << 40) - 1)) * (1.0 / 16777216.0));
        float d = deg + 2.0f;
        float dv = 1.0f / sqrtf(d);
        dinv[n] = dv;
        selfn[n] = 2.0f * dv * dv;
        cnt[n] = c;
    }
}

// ---------------- CSR build ----------------
__global__ void __launch_bounds__(256) k_blocksum(const int* __restrict__ cnt, int* __restrict__ bsum, int n)
{
    __shared__ int red[256];
    int t = threadIdx.x;
    int base = blockIdx.x * 1024;
    int s = 0;
#pragma unroll
    for (int j = 0; j < 4; ++j) {
        int i = base + j * 256 + t;
        if (i < n) s += cnt[i];
    }
    red[t] = s; __syncthreads();
    for (int off = 128; off; off >>= 1) {
        if (t < off) red[t] += red[t + off];
        __syncthreads();
    }
    if (t == 0) bsum[blockIdx.x] = red[0];
}

__global__ void k_scanbsum(const int* __restrict__ bsum, int* __restrict__ boff, int nb,
                           int* __restrict__ rp_last, int total)
{
    if (threadIdx.x == 0 && blockIdx.x == 0) {
        int s = 0;
        for (int i = 0; i < nb; ++i) { boff[i] = s; s += bsum[i]; }
        rp_last[0] = total;
    }
}

__global__ void __launch_bounds__(1024) k_scanchunk(const int* __restrict__ cnt, const int* __restrict__ boff,
                                                    int* __restrict__ rp, int n)
{
    __shared__ int sc[1024];
    int t = threadIdx.x;
    int i = blockIdx.x * 1024 + t;
    int own = (i < n) ? cnt[i] : 0;
    sc[t] = own;
    __syncthreads();
    for (int off = 1; off < 1024; off <<= 1) {
        int v = (t >= off) ? sc[t - off] : 0;
        __syncthreads();
        sc[t] += v;
        __syncthreads();
    }
    if (i < n) rp[i] = boff[blockIdx.x] + sc[t] - own;
}

// placement: NO atomics; packed u32 = (f16 w bits [15] << 17) | src (<2^17)
__global__ void __launch_bounds__(256) k_place2(const int* __restrict__ src, const int* __restrict__ dst,
                                                const float* __restrict__ ed, const float* __restrict__ dinv,
                                                const int* __restrict__ rp, const int* __restrict__ rank,
                                                u32* __restrict__ ew)
{
    int e = blockIdx.x * 256 + threadIdx.x;
    if (e < NE) {
        int d = dst[e], s = src[e];
        int pos = rp[d] + rank[e];
        float w = dinv[s] * ed[e] * dinv[d];
        f16 wh = (f16)w;
        u32 wb = (u32)__builtin_bit_cast(u16, wh);
        ew[pos] = (wb << 17) | (u32)s;
    }
}

// ---------------- SpMM (fp16 row-major gather, u32 packed edges) ----------------
__global__ void __launch_bounds__(256) k_spmm(
    const f16* __restrict__ xwh, const int* __restrict__ rp,
    const u32* __restrict__ ew,
    const float* __restrict__ selfn, const float* __restrict__ cb,
    f16* __restrict__ aggh, double* __restrict__ stats)
{
    int tid = threadIdx.x;
    int slot = tid >> 4;          // 0..15
    int sl = tid & 15;
    int f0 = sl * 8;
    float cbv[8], psum[8], psq[8];
#pragma unroll
    for (int j = 0; j < 8; ++j) { cbv[j] = cb[f0 + j]; psum[j] = 0.f; psq[j] = 0.f; }
    int base = blockIdx.x * 32 + slot * 2;

    for (int i = 0; i < 2; ++i) {
        int n = base + i;
        if (n >= NN) break;
        f16x8 xv = *(const f16x8*)(xwh + (size_t)n * H + f0);
        float sn = selfn[n];
        float a0[8], a1[8], a2[8], a3[8];
#pragma unroll
        for (int j = 0; j < 8; ++j) {
            a0[j] = sn * (float)xv[j] + cbv[j];
            a1[j] = 0.f; a2[j] = 0.f; a3[j] = 0.f;
        }
        int e = rp[n], end = rp[n + 1];
        for (; e + 4 <= end; e += 4) {
            u32 p0 = ew[e], p1 = ew[e + 1], p2 = ew[e + 2], p3 = ew[e + 3];
            float w0 = (float)__builtin_bit_cast(f16, (u16)(p0 >> 17));
            float w1 = (float)__builtin_bit_cast(f16, (u16)(p1 >> 17));
            float w2 = (float)__builtin_bit_cast(f16, (u16)(p2 >> 17));
            float w3 = (float)__builtin_bit_cast(f16, (u16)(p3 >> 17));
            f16x8 v0 = *(const f16x8*)(xwh + (size_t)(p0 & 0x1FFFF) * H + f0);
            f16x8 v1 = *(const f16x8*)(xwh + (size_t)(p1 & 0x1FFFF) * H + f0);
            f16x8 v2 = *(const f16x8*)(xwh + (size_t)(p2 & 0x1FFFF) * H + f0);
            f16x8 v3 = *(const f16x8*)(xwh + (size_t)(p3 & 0x1FFFF) * H + f0);
#pragma unroll
            for (int j = 0; j < 8; ++j) {
                a0[j] += w0 * (float)v0[j];
                a1[j] += w1 * (float)v1[j];
                a2[j] += w2 * (float)v2[j];
                a3[j] += w3 * (float)v3[j];
            }
        }
        for (; e < end; ++e) {
            u32 p = ew[e];
            float w0 = (float)__builtin_bit_cast(f16, (u16)(p >> 17));
            f16x8 v0 = *(const f16x8*)(xwh + (size_t)(p & 0x1FFFF) * H + f0);
#pragma unroll
            for (int j = 0; j < 8; ++j) a0[j] += w0 * (float)v0[j];
        }
        float ax[8];
        f16x8 ah;
#pragma unroll
        for (int j = 0; j < 8; ++j) {
            ax[j] = (a0[j] + a1[j]) + (a2[j] + a3[j]);
            psum[j] += ax[j];
            psq[j] += ax[j] * ax[j];
            ah[j] = (f16)ax[j];
        }
        __builtin_nontemporal_store(ah, (f16x8*)(aggh + (size_t)n * H + f0));
    }

    __shared__ float ssum[16][128], ssq[16][128];
#pragma unroll
    for (int j = 0; j < 8; ++j) { ssum[slot][f0 + j] = psum[j]; ssq[slot][f0 + j] = psq[j]; }
    __syncthreads();
    if (tid < 128) {
        float s = 0.f, q = 0.f;
#pragma unroll
        for (int j = 0; j < 16; ++j) { s += ssum[j][tid]; q += ssq[j][tid]; }
        atomicAdd(&stats[tid], (double)s);
        atomicAdd(&stats[128 + tid], (double)q);
    }
}

// finalize BN scale/shift; self-zero stats for next layer
__global__ void k_finalize(double* __restrict__ stats, const float* __restrict__ bn_g,
                           const float* __restrict__ bn_b, float* __restrict__ scale,
                           float* __restrict__ shift)
{
    int f = threadIdx.x; // 128
    double mu = stats[f] / (double)NN;
    double var = stats[128 + f] / (double)NN - mu * mu;
    double rs = 1.0 / sqrt(var + 1e-5);
    float sc = (float)((double)bn_g[f] * rs);
    scale[f] = sc;
    shift[f] = (float)((double)bn_b[f] - mu * (double)sc);
    stats[f] = 0.0;
    stats[128 + f] = 0.0;
}

// BN + residual from fp16 agg; x kept as bf16 hi/lo split
__global__ void __launch_bounds__(256) k_bnres(const f16* __restrict__ aggh, const float* __restrict__ scale,
                                               const float* __restrict__ shift,
                                               u16* __restrict__ xhi, u16* __restrict__ xlo)
{
    int i8 = blockIdx.x * 256 + threadIdx.x;
    if (i8 >= NN * 16) return;
    int f0 = (i8 & 15) * 8;
    f16x8 a = ((const f16x8*)aggh)[i8];
    u16x8 hh = ((const u16x8*)xhi)[i8];
    u16x8 ll = ((const u16x8*)xlo)[i8];
#pragma unroll
    for (int j = 0; j < 8; ++j) {
        float v = bf2f(hh[j]) + bf2f(ll[j]) + (float)a[j] * scale[f0 + j] + shift[f0 + j];
        u16 h = f2bf(v);
        hh[j] = h;
        ll[j] = f2bf(v - bf2f(h));
    }
    ((u16x8*)xhi)[i8] = hh;
    ((u16x8*)xlo)[i8] = ll;
}

// ---------------- goff from SORTED batch: boundary detection, no atomics ----------------
__global__ void __launch_bounds__(256) k_goff2(const int* __restrict__ batch, int* __restrict__ goff)
{
    int n = blockIdx.x * 256 + threadIdx.x;
    if (n >= NN) return;
    int b = batch[n];
    if (n == 0) {
        for (int j = 0; j <= b; ++j) goff[j] = 0;
    }
    int nb = (n == NN - 1) ? NB : batch[n + 1];
    for (int j = b + 1; j <= nb; ++j) goff[j] = n + 1;
}

__global__ void __launch_bounds__(256) k_segsoftmax(const float* __restrict__ e, const int* __restrict__ goff,
                                                    float* __restrict__ w)
{
    int b = blockIdx.x;
    int beg = goff[b], end = goff[b + 1];
    int t = threadIdx.x;
    __shared__ float red[8], red2[8];
    float m = -INFINITY;
    for (int i = beg + t; i < end; i += 256) m = fmaxf(m, e[i]);
    for (int off = 32; off; off >>= 1) m = fmaxf(m, __shfl_down(m, off));
    if ((t & 63) == 0) red[t >> 6] = m;
    __syncthreads();
    float m0 = fmaxf(fmaxf(red[0], red[1]), fmaxf(red[2], red[3]));
    float s = 0.f;
    for (int i = beg + t; i < end; i += 256) s += expf(e[i] - m0);
    for (int off = 32; off; off >>= 1) s += __shfl_down(s, off);
    if ((t & 63) == 0) red2[t >> 6] = s;
    __syncthreads();
    float s0 = red2[0] + red2[1] + red2[2] + red2[3];
    for (int i = beg + t; i < end; i += 256) w[i] = expf(e[i] - m0) / s0;
}

// reconstruct x from split, scale by node weight, write fp16 (into xw region)
__global__ void __launch_bounds__(256) k_scalex16(const u16* __restrict__ xhi, const u16* __restrict__ xlo,
                                                  const float* __restrict__ w, f16* __restrict__ xf)
{
    int i8 = blockIdx.x * 256 + threadIdx.x;
    if (i8 >= NN * 16) return;
    float ww = w[i8 >> 4];
    u16x8 hh = ((const u16x8*)xhi)[i8];
    u16x8 ll = ((const u16x8*)xlo)[i8];
    f16x8 v;
#pragma unroll
    for (int j = 0; j < 8; ++j)
        v[j] = (f16)((bf2f(hh[j]) + bf2f(ll[j])) * ww);
    ((f16x8*)xf)[i8] = v;
}

// ---------------- Set2Set: fused gates + LSTM, 8 graphs per block ----------------
__device__ __forceinline__ float sigmoidf_(float v) { return 1.f / (1.f + expf(-v)); }

__global__ void __launch_bounds__(256) k_gateslstm(
    const float* __restrict__ qstar, const float* __restrict__ Wih, const float* __restrict__ Whh,
    const float* __restrict__ bih, const float* __restrict__ bhh,
    float* __restrict__ cs, float* __restrict__ hs)
{
    __shared__ float qs[8][256];
    __shared__ float hh[8][128];
    __shared__ float gs[8][512];
    int t = threadIdx.x;
    int b0 = blockIdx.x * 8;
    for (int i = t; i < 8 * 256; i += 256) qs[i >> 8][i & 255] = qstar[b0 * 256 + i];
    for (int i = t; i < 8 * 128; i += 256) hh[i >> 7][i & 127] = hs[b0 * 128 + i];
    __syncthreads();
    for (int gg = t; gg < 512; gg += 256) {
        float acc[8];
        float bb = bih[gg] + bhh[gg];
#pragma unroll
        for (int g = 0; g < 8; ++g) acc[g] = bb;
        const float4* w4 = (const float4*)(Wih + (size_t)gg * 256);
        for (int k = 0; k < 64; ++k) {
            float4 w = w4[k];
#pragma unroll
            for (int g = 0; g < 8; ++g) {
                float4 q = *(const float4*)&qs[g][k * 4];
                acc[g] += q.x * w.x + q.y * w.y + q.z * w.z + q.w * w.w;
            }
        }
        const float4* v4 = (const float4*)(Whh + (size_t)gg * 128);
        for (int k = 0; k < 32; ++k) {
            float4 w = v4[k];
#pragma unroll
            for (int g = 0; g < 8; ++g) {
                float4 q = *(const float4*)&hh[g][k * 4];
                acc[g] += q.x * w.x + q.y * w.y + q.z * w.z + q.w * w.w;
            }
        }
#pragma unroll
        for (int g = 0; g < 8; ++g) gs[g][gg] = acc[g];
    }
    __syncthreads();
    for (int i = t; i < 1024; i += 256) {
        int g = i >> 7, f = i & 127;
        int idx = (b0 + g) * 128 + f;
        float gi = gs[g][f], gf = gs[g][128 + f], gg2 = gs[g][256 + f], go = gs[g][384 + f];
        float c = sigmoidf_(gf) * cs[idx] + sigmoidf_(gi) * tanhf(gg2);
        cs[idx] = c;
        hs[idx] = sigmoidf_(go) * tanhf(c);
    }
}

// ---------------- Set2Set fused attention: en + softmax + r, one block per graph, fp16 x ----------------
__global__ void __launch_bounds__(256) k_s2s(const f16* __restrict__ x16, const float* __restrict__ hs,
                                             const int* __restrict__ goff,
                                             float* __restrict__ esc, float* __restrict__ qstar)
{
    __shared__ float q[128];
    __shared__ float red[4], red2[4];
    __shared__ float partr[3][128];
    int b = blockIdx.x, t = threadIdx.x;
    int beg = goff[b], end = goff[b + 1];
    if (t < 128) q[t] = hs[b * 128 + t];
    __syncthreads();

    int wv = t >> 6, ln = t & 63;
    // pass 1: en scores (64 lanes x 2 feats) + wave max
    float m = -INFINITY;
    for (int i = beg + wv; i < end; i += 4) {
        u32 xp = *(const u32*)(x16 + (size_t)i * H + ln * 2);
        float xl = (float)__builtin_bit_cast(f16, (u16)(xp & 0xFFFF));
        float xh = (float)__builtin_bit_cast(f16, (u16)(xp >> 16));
        float pd = xl * q[ln * 2] + xh * q[ln * 2 + 1];
        for (int off = 32; off; off >>= 1) pd += __shfl_down(pd, off);
        pd = __shfl(pd, 0);
        if (ln == 0) esc[i] = pd;
        m = fmaxf(m, pd);
    }
    if (ln == 0) red[wv] = m;
    __syncthreads();
    float m0 = fmaxf(fmaxf(red[0], red[1]), fmaxf(red[2], red[3]));
    // pass 1b: exp + sum (store unnormalized weight back to esc)
    float s = 0.f;
    for (int i = beg + t; i < end; i += 256) {
        float e = expf(esc[i] - m0);
        esc[i] = e;
        s += e;
    }
    for (int off = 32; off; off >>= 1) s += __shfl_down(s, off);
    if (ln == 0) red2[wv] = s;
    __syncthreads();
    float s0 = red2[0] + red2[1] + red2[2] + red2[3];
    float inv = (s0 > 0.f) ? 1.f / s0 : 0.f;
    // pass 2: r = sum w * x ; thread covers feat pair f2, quarter q4
    int q4 = t >> 6, f2 = (t & 63) * 2;
    float a0 = 0.f, a1 = 0.f;
    for (int i = beg + q4; i < end; i += 4) {
        float w = esc[i];
        u32 xp = *(const u32*)(x16 + (size_t)i * H + f2);
        a0 += w * (float)__builtin_bit_cast(f16, (u16)(xp & 0xFFFF));
        a1 += w * (float)__builtin_bit_cast(f16, (u16)(xp >> 16));
    }
    if (q4 > 0) { partr[q4 - 1][f2] = a0; partr[q4 - 1][f2 + 1] = a1; }
    __syncthreads();
    if (q4 == 0) {
        a0 += partr[0][f2] + partr[1][f2] + partr[2][f2];
        a1 += partr[0][f2 + 1] + partr[1][f2 + 1] + partr[2][f2 + 1];
        qstar[b * 256 + f2] = q[f2];
        qstar[b * 256 + f2 + 1] = q[f2 + 1];
        qstar[b * 256 + 128 + f2] = a0 * inv;
        qstar[b * 256 + 128 + f2 + 1] = a1 * inv;
    }
}

// ---------------- head ----------------
__global__ void __launch_bounds__(256) k_head1(const float* __restrict__ qstar, const float* __restrict__ W,
                                               const float* __restrict__ bias, float* __restrict__ y1)
{
    __shared__ float qs[256];
    int b = blockIdx.x, t = threadIdx.x;
    qs[t] = qstar[b * 256 + t];
    __syncthreads();
    float acc = bias[t];
    for (int k = 0; k < 256; ++k) acc += qs[k] * W[k * 256 + t];
    y1[b * 256 + t] = fmaxf(acc, 0.f);
}

__global__ void __launch_bounds__(256) k_head2(const float* __restrict__ y1, const float* __restrict__ W1,
                                               const float* __restrict__ b1, const float* __restrict__ W2,
                                               const float* __restrict__ b2, float* __restrict__ out)
{
    __shared__ float ys[256];
    __shared__ float z[32];
    int b = blockIdx.x, t = threadIdx.x;
    ys[t] = y1[b * 256 + t];
    __syncthreads();
    if (t < 32) {
        float acc = b1[t];
        for (int k = 0; k < 256; ++k) acc += ys[k] * W1[k * 32 + t];
        z[t] = fmaxf(acc, 0.f);
    }
    __syncthreads();
    if (t == 0) {
        float s = b2[0];
        for (int j = 0; j < 32; ++j) s += z[j] * W2[j];
        out[b] = s;
    }
}

// ---------------- launch ----------------
extern "C" void kernel_launch(void* const* d_in, const int* in_sizes, int n_in,
                              void* d_out, int out_size, void* d_ws, size_t ws_size,
                              hipStream_t stream)
{
    const float* in_x        = (const float*)d_in[0];
    const int*   edge_index  = (const int*)d_in[1];
    const float* edge_dist   = (const float*)d_in[2];
    const float* global_info = (const float*)d_in[3];
    const int*   batch       = (const int*)d_in[4];
    const float* lin_W  = (const float*)d_in[5];
    const float* lin_b  = (const float*)d_in[6];
    const float* conv_W = (const float*)d_in[7];
    const float* conv_b = (const float*)d_in[8];
    const float* bn_g   = (const float*)d_in[9];
    const float* bn_b   = (const float*)d_in[10];
    const float* gat_in_W  = (const float*)d_in[11];
    const float* gat_in_b  = (const float*)d_in[12];
    const float* gat_lin_W = (const float*)d_in[13];
    const float* gat_lin_b = (const float*)d_in[14];
    const float* gat_out_W = (const float*)d_in[15];
    const float* gat_out_b = (const float*)d_in[16];
    const float* lstm_Wih = (const float*)d_in[17];
    const float* lstm_Whh = (const float*)d_in[18];
    const float* lstm_bih = (const float*)d_in[19];
    const float* lstm_bhh = (const float*)d_in[20];
    const float* mlp_W  = (const float*)d_in[21];
    const float* mlp_b  = (const float*)d_in[22];
    const float* out1_W = (const float*)d_in[23];
    const float* out1_b = (const float*)d_in[24];
    const float* out2_W = (const float*)d_in[25];
    const float* out2_b = (const float*)d_in[26];
    float* out = (float*)d_out;

    const int* e_src = edge_index;
    const int* e_dst = edge_index + NE;

    char* p = (char*)d_ws;
    auto alloc = [&](size_t bytes) -> void* {
        void* r = (void*)p;
        p += (bytes + 255) & ~(size_t)255;
        return r;
    };
    u16*    cx_hi = (u16*)alloc((size_t)NN * H * 2);
    u16*    cx_lo = (u16*)alloc((size_t)NN * H * 2);
    float*  xw    = (float*)alloc((size_t)NN * H * 4);   // fp16 xwh (conv) / fp16 scaled-x (Set2Set)
    float*  agg   = (float*)alloc((size_t)NN * H * 4);   // fp16 aggh; CSR: degcnt+rank; gat: gi split
    u16*    wthi  = (u16*)alloc((size_t)160000 * 2);
    u16*    wtlo  = (u16*)alloc((size_t)160000 * 2);
    float*  dinv  = (float*)alloc((size_t)NN * 4);
    float*  selfn = (float*)alloc((size_t)NN * 4);
    int*    cnt   = (int*)alloc((size_t)NN * 4);
    int*    rp    = (int*)alloc((size_t)(NN + 1) * 4);
    int*    bsum  = (int*)alloc(128 * 4);
    int*    boff  = (int*)alloc(128 * 4);
    u32*    ew    = (u32*)alloc((size_t)NE * 4);         // packed (w:f16<<17 | src); Set2Set aliases
    double* stats = (double*)alloc(256 * 8);
    float*  scale = (float*)alloc(128 * 4);
    float*  shift = (float*)alloc(128 * 4);

    f16*   xwh    = (f16*)xw;
    f16*   aggh   = (f16*)agg;
    u64*   degcnt = (u64*)agg;
    int*   rank   = (int*)((char*)agg + (1 << 20));
    u16*   gi_hi  = (u16*)agg;
    u16*   gi_lo  = gi_hi + (size_t)NN * H;
    float* esc    = dinv;
    float* wn     = selfn;
    int*   goff   = cnt;
    float* hs     = (float*)ew;
    float* csb    = hs + NB * H;
    float* qstar  = csb + NB * H;
    float* y1     = qstar + NB * 2 * H;

    const int GB_E = (NE + 255) / 256;
    const int GB_N = (NN + 255) / 256;
    const int NCH = (NN + 1023) / 1024;
    const int GB_MG = (NN + GBM - 1) / GBM;
    const int GB_SPMM = (NN + 31) / 32;
    const int GB_V8 = (NN * 16) / 256 + 1;

    // ---- all weight splits, one launch ----
    WJobs jobs;
    const float* Wl[9] = {lin_W, conv_W, conv_W + (size_t)H * H, conv_W + (size_t)2 * H * H,
                          conv_W + (size_t)3 * H * H, conv_W + (size_t)4 * H * H,
                          gat_in_W, gat_lin_W, gat_lin_W + (size_t)H * H};
    int Ks[9]  = {DIN, H, H, H, H, H, H + DGI, H, H};
    int Kps[9] = {96, H, H, H, H, H, 256, H, H};
    long long eoffs[9];
    long long eo = 0;
    for (int i = 0; i < 9; ++i) {
        jobs.W[i] = Wl[i]; jobs.K[i] = Ks[i]; jobs.Kpad[i] = Kps[i]; jobs.eoff[i] = eo;
        eoffs[i] = eo;
        eo += (long long)128 * Kps[i];
    }
    k_splitW_all<<<dim3(128, 2, 9), 128, 0, stream>>>(jobs, wthi, wtlo);

    // ---- graph norm + CSR ----
    hipMemsetAsync(degcnt, 0, (size_t)NN * 8, stream);
    hipMemsetAsync(stats, 0, 256 * 8, stream);
    k_deg2<<<GB_E, 256, 0, stream>>>(e_dst, edge_dist, degcnt, rank);
    k_dinv2<<<GB_N, 256, 0, stream>>>(degcnt, dinv, selfn, cnt);
    k_blocksum<<<NCH, 256, 0, stream>>>(cnt, bsum, NN);
    k_scanbsum<<<1, 64, 0, stream>>>(bsum, boff, NCH, rp + NN, NE);
    k_scanchunk<<<NCH, 1024, 0, stream>>>(cnt, boff, rp, NN);
    k_place2<<<GB_E, 256, 0, stream>>>(e_src, e_dst, edge_dist, dinv, rp, rank, ew);

    // ---- input projection ----
    k_split<<<dim3(NN, 1), 128, 0, stream>>>(in_x, DIN, DIN, cx_hi, cx_lo, H, 0, 96);
    k_mgemm<1, 1, 96><<<GB_MG, 256, 0, stream>>>(cx_hi, cx_lo, H, 96, cx_hi, cx_lo, H,
                                                 wthi + eoffs[0], wtlo + eoffs[0], lin_b,
                                                 nullptr, cx_hi, cx_lo, H, nullptr,
                                                 nullptr, nullptr, nullptr, NN);

    // ---- conv stack ----
    for (int l = 0; l < NL; ++l) {
        k_mgemm<0, 2, 128><<<GB_MG, 256, 0, stream>>>(cx_hi, cx_lo, H, H, cx_hi, cx_lo, H,
                                                      wthi + eoffs[1 + l], wtlo + eoffs[1 + l], nullptr,
                                                      nullptr, nullptr, nullptr, 0, xwh,
                                                      nullptr, nullptr, nullptr, NN);
        k_spmm<<<GB_SPMM, 256, 0, stream>>>(xwh, rp, ew, selfn, conv_b + (size_t)l * H, aggh, stats);
        k_finalize<<<1, 128, 0, stream>>>(stats, bn_g, bn_b, scale, shift);
        k_bnres<<<GB_V8, 256, 0, stream>>>(aggh, scale, shift, cx_hi, cx_lo);
    }

    // ---- global attention ----
    k_split<<<dim3(NN, 1), 128, 0, stream>>>(global_info, DGI, DGI, gi_hi, gi_lo, H, 0, H);
    k_mgemm<1, 1, 256><<<GB_MG, 256, 0, stream>>>(cx_hi, cx_lo, H, H, gi_hi, gi_lo, H,
                                                  wthi + eoffs[6], wtlo + eoffs[6], gat_in_b,
                                                  nullptr, gi_hi, gi_lo, H, nullptr,
                                                  nullptr, nullptr, nullptr, NN);
    k_mgemm<1, 1, 128><<<GB_MG, 256, 0, stream>>>(gi_hi, gi_lo, H, H, gi_hi, gi_lo, H,
                                                  wthi + eoffs[7], wtlo + eoffs[7], gat_lin_b,
                                                  nullptr, gi_hi, gi_lo, H, nullptr,
                                                  nullptr, nullptr, nullptr, NN);
    k_mgemm<1, 3, 128><<<GB_MG, 256, 0, stream>>>(gi_hi, gi_lo, H, H, gi_hi, gi_lo, H,
                                                  wthi + eoffs[8], wtlo + eoffs[8], gat_lin_b + H,
                                                  nullptr, nullptr, nullptr, 0, nullptr,
                                                  gat_out_W, gat_out_b, esc, NN);
    k_goff2<<<GB_N, 256, 0, stream>>>(batch, goff);
    k_segsoftmax<<<NB, 256, 0, stream>>>(esc, goff, wn);
    k_scalex16<<<GB_V8, 256, 0, stream>>>(cx_hi, cx_lo, wn, (f16*)xw);  // xwh region dead

    // ---- Set2Set (hs/csb/qstar alias ew region, dead after conv stack) ----
    hipMemsetAsync(hs, 0, (size_t)NB * H * 4, stream);
    hipMemsetAsync(csb, 0, (size_t)NB * H * 4, stream);
    hipMemsetAsync(qstar, 0, (size_t)NB * 2 * H * 4, stream);
    for (int it = 0; it < 3; ++it) {
        k_gateslstm<<<NB / 8, 256, 0, stream>>>(qstar, lstm_Wih, lstm_Whh, lstm_bih, lstm_bhh, csb, hs);
        k_s2s<<<NB, 256, 0, stream>>>((const f16*)xw, hs, goff, esc, qstar);
    }

    // ---- head ----
    k_head1<<<NB, 256, 0, stream>>>(qstar, mlp_W, mlp_b, y1);
    k_head2<<<NB, 256, 0, stream>>>(y1, out1_W, out1_b, out2_W, out2_b, out);
}

// Round 11
// 1409.535 us; speedup vs baseline: 1.2428x; 1.0067x over previous
//
#include <hip/hip_runtime.h>
#include <math.h>

#define NN 100000
#define NE 1600000
#define DIN 92
#define H 128
#define NB 512
#define DGI 107
#define NL 5

typedef unsigned short u16;
typedef unsigned int u32;
typedef unsigned long long u64;
typedef short bf16x8 __attribute__((ext_vector_type(8)));
typedef float f32x4 __attribute__((ext_vector_type(4)));
typedef _Float16 f16;
typedef _Float16 f16x8 __attribute__((ext_vector_type(8)));
typedef unsigned short u16x8 __attribute__((ext_vector_type(8)));

__device__ __forceinline__ u16 f2bf(float f) {
    unsigned u = __builtin_bit_cast(unsigned, f);
    u += 0x7FFF + ((u >> 16) & 1);
    return (u16)(u >> 16);
}
__device__ __forceinline__ float bf2f(u16 h) {
    unsigned u = ((unsigned)h) << 16;
    return __builtin_bit_cast(float, u);
}

// ---------------- split fp32 -> bf16 hi/lo (activations) ----------------
__global__ void __launch_bounds__(128) k_split(const float* __restrict__ src, int Ksrc, int ld_src,
                                               u16* __restrict__ hi, u16* __restrict__ lo,
                                               int ld_dst, int col_off, int Kfill)
{
    int row = blockIdx.x;
    int k = blockIdx.y * 128 + threadIdx.x;
    if (k >= Kfill) return;
    float v = (k < Ksrc) ? src[(size_t)row * ld_src + k] : 0.f;
    u16 h = f2bf(v);
    float r = v - bf2f(h);
    size_t o = (size_t)row * ld_dst + col_off + k;
    hi[o] = h;
    lo[o] = f2bf(r);
}

// ---------------- all weight splits in ONE launch ----------------
struct WJobs {
    const float* W[9];
    long long eoff[9];
    int K[9];
    int Kpad[9];
};

__global__ void __launch_bounds__(128) k_splitW_all(WJobs jobs, u16* __restrict__ wthi, u16* __restrict__ wtlo)
{
    int j = blockIdx.z;
    int c = blockIdx.x;
    int k = blockIdx.y * 128 + threadIdx.x;
    int Kp = jobs.Kpad[j];
    if (k >= Kp) return;
    const float* W = jobs.W[j];
    float v = (k < jobs.K[j]) ? W[(size_t)k * H + c] : 0.f;
    u16 h = f2bf(v);
    float r = v - bf2f(h);
    size_t o = (size_t)jobs.eoff[j] + (size_t)c * Kp + k;
    wthi[o] = h;
    wtlo[o] = f2bf(r);
}

// ---------------- MFMA GEMM: C[M,128] = act([A1|A2]@W + b), bf16x3 compensated ----------------
// OMODE: 0=f32, 1=bf16 split, 2=fp16 row-major, 3=fused escore. KPAD compile-time.
// AMODE: 0=plain pre-split A; 1=A1 staged as bnres(cx, aggh, scale, shift) with write-back
#define GBM 128

template<int RELU, int OMODE, int KPAD, int AMODE>
__global__ void __launch_bounds__(256) k_mgemm(
    const u16* __restrict__ A1hi, const u16* __restrict__ A1lo, int lda1, int K1,
    const u16* __restrict__ A2hi, const u16* __restrict__ A2lo, int lda2,
    const u16* __restrict__ Wthi, const u16* __restrict__ Wtlo,
    const float* __restrict__ bias,
    float* __restrict__ Cf, u16* __restrict__ Chi, u16* __restrict__ Clo, int ldsp,
    f16* __restrict__ Ch,
    const float* __restrict__ Gow, const float* __restrict__ GobP, float* __restrict__ Esc,
    const f16* __restrict__ Agg, const float* __restrict__ Sc, const float* __restrict__ Sh,
    u16* __restrict__ WBhi, u16* __restrict__ WBlo,
    int M)
{
    __shared__ __align__(16) u16 As[2][128][40];
    __shared__ __align__(16) u16 Ws[2][128][40];
    int tid = threadIdx.x;
    int w = tid >> 6, l = tid & 63;
    int row0 = blockIdx.x * GBM;
    int lr = l & 15, kq = l >> 4;

    f32x4 acc[2][8];
#pragma unroll
    for (int rf = 0; rf < 2; ++rf)
#pragma unroll
        for (int cf = 0; cf < 8; ++cf)
            acc[rf][cf] = (f32x4){0.f, 0.f, 0.f, 0.f};

#pragma unroll
    for (int k0 = 0; k0 < KPAD; k0 += 32) {
        const u16* sAh = (k0 < K1) ? A1hi : A2hi;
        const u16* sAl = (k0 < K1) ? A1lo : A2lo;
        int ldc = (k0 < K1) ? lda1 : lda2;
        int kc = (k0 < K1) ? k0 : (k0 - K1);
#pragma unroll
        for (int i = 0; i < 2; ++i) {
            int chunk = tid + i * 256;
            int r = chunk >> 2, q = chunk & 3;
            int gr = row0 + r; if (gr >= M) gr = M - 1;
            int col0 = kc + q * 8;
            int4 va = *(const int4*)(sAh + (size_t)gr * ldc + col0);
            int4 vb = *(const int4*)(sAl + (size_t)gr * ldc + col0);
            if (AMODE == 1 && k0 < K1) {
                // fused bnres: new_x = old_x + agg*scale + shift; re-split; write back
                f16x8 av = *(const f16x8*)(Agg + (size_t)gr * H + col0);
                u16x8 hh = __builtin_bit_cast(u16x8, va);
                u16x8 ll = __builtin_bit_cast(u16x8, vb);
                float4 sc0 = *(const float4*)(Sc + col0);
                float4 sc1 = *(const float4*)(Sc + col0 + 4);
                float4 sh0 = *(const float4*)(Sh + col0);
                float4 sh1 = *(const float4*)(Sh + col0 + 4);
                float scv[8] = {sc0.x, sc0.y, sc0.z, sc0.w, sc1.x, sc1.y, sc1.z, sc1.w};
                float shv[8] = {sh0.x, sh0.y, sh0.z, sh0.w, sh1.x, sh1.y, sh1.z, sh1.w};
#pragma unroll
                for (int j = 0; j < 8; ++j) {
                    float v = bf2f(hh[j]) + bf2f(ll[j]) + (float)av[j] * scv[j] + shv[j];
                    u16 h = f2bf(v);
                    hh[j] = h;
                    ll[j] = f2bf(v - bf2f(h));
                }
                va = __builtin_bit_cast(int4, hh);
                vb = __builtin_bit_cast(int4, ll);
                *(int4*)(WBhi + (size_t)gr * lda1 + col0) = va;
                *(int4*)(WBlo + (size_t)gr * lda1 + col0) = vb;
            }
            int4 wa = *(const int4*)(Wthi + (size_t)r * KPAD + k0 + q * 8);
            int4 wb = *(const int4*)(Wtlo + (size_t)r * KPAD + k0 + q * 8);
            *(int4*)&As[0][r][q * 8] = va;
            *(int4*)&As[1][r][q * 8] = vb;
            *(int4*)&Ws[0][r][q * 8] = wa;
            *(int4*)&Ws[1][r][q * 8] = wb;
        }
        __syncthreads();

        bf16x8 aH[2], aL[2];
#pragma unroll
        for (int rf = 0; rf < 2; ++rf) {
            aH[rf] = *(const bf16x8*)&As[0][w * 32 + rf * 16 + lr][kq * 8];
            aL[rf] = *(const bf16x8*)&As[1][w * 32 + rf * 16 + lr][kq * 8];
        }
#pragma unroll
        for (int cf = 0; cf < 8; ++cf) {
            bf16x8 bH = *(const bf16x8*)&Ws[0][cf * 16 + lr][kq * 8];
            bf16x8 bL = *(const bf16x8*)&Ws[1][cf * 16 + lr][kq * 8];
#pragma unroll
            for (int rf = 0; rf < 2; ++rf) {
                acc[rf][cf] = __builtin_amdgcn_mfma_f32_16x16x32_bf16(aH[rf], bH, acc[rf][cf], 0, 0, 0);
                acc[rf][cf] = __builtin_amdgcn_mfma_f32_16x16x32_bf16(aH[rf], bL, acc[rf][cf], 0, 0, 0);
                acc[rf][cf] = __builtin_amdgcn_mfma_f32_16x16x32_bf16(aL[rf], bH, acc[rf][cf], 0, 0, 0);
            }
        }
        __syncthreads();
    }

    if (OMODE == 3) {
        float gowv[8], bvv[8];
#pragma unroll
        for (int cf = 0; cf < 8; ++cf) {
            gowv[cf] = Gow[cf * 16 + lr];
            bvv[cf] = bias[cf * 16 + lr];
        }
        float gob0 = GobP[0];
#pragma unroll
        for (int rf = 0; rf < 2; ++rf) {
#pragma unroll
            for (int r = 0; r < 4; ++r) {
                float part = 0.f;
#pragma unroll
                for (int cf = 0; cf < 8; ++cf) {
                    float v = fmaxf(acc[rf][cf][r] + bvv[cf], 0.f);
                    part += v * gowv[cf];
                }
                part += __shfl_xor(part, 1);
                part += __shfl_xor(part, 2);
                part += __shfl_xor(part, 4);
                part += __shfl_xor(part, 8);
                int grow = row0 + w * 32 + rf * 16 + kq * 4 + r;
                if (lr == 0 && grow < M) Esc[grow] = part + gob0;
            }
        }
        return;
    }

#pragma unroll
    for (int cf = 0; cf < 8; ++cf) {
        int col = cf * 16 + lr;
        float bv = bias ? bias[col] : 0.f;
#pragma unroll
        for (int rf = 0; rf < 2; ++rf) {
#pragma unroll
            for (int r = 0; r < 4; ++r) {
                int grow = row0 + w * 32 + rf * 16 + kq * 4 + r;
                if (grow < M) {
                    float v = acc[rf][cf][r] + bv;
                    if (RELU) v = fmaxf(v, 0.f);
                    if (OMODE == 0) Cf[(size_t)grow * H + col] = v;
                    if (OMODE == 1) {
                        u16 hh = f2bf(v);
                        Chi[(size_t)grow * ldsp + col] = hh;
                        Clo[(size_t)grow * ldsp + col] = f2bf(v - bf2f(hh));
                    }
                    if (OMODE == 2) Ch[(size_t)grow * H + col] = (f16)v;
                }
            }
        }
    }
}

// ---------------- degree + counts: one packed 64-bit atomic per edge ----------------
__global__ void __launch_bounds__(256) k_deg2(const int* __restrict__ dst, const float* __restrict__ ed,
                                              u64* __restrict__ degcnt, int* __restrict__ rank)
{
    int e = blockIdx.x * 256 + threadIdx.x;
    if (e < NE) {
        int d = dst[e];
        u64 pk = ((u64)1 << 40) | (u64)(ed[e] * 16777216.0f);
        u64 old = atomicAdd(&degcnt[d], pk);
        rank[e] = (int)(old >> 40);
    }
}

__global__ void __launch_bounds__(256) k_dinv2(const u64* __restrict__ degcnt,
                                               float* __restrict__ dinv, float* __restrict__ selfn,
                                               int* __restrict__ cnt)
{
    int n = blockIdx.x * 256 + threadIdx.x;
    if (n < NN) {
        u64 v = degcnt[n];
        int c = (int)(v >> 40);
        float deg = (float)((double)(v & (((u64)1 << 40) - 1)) * (1.0 / 16777216.0));
        float d = deg + 2.0f;
        float dv = 1.0f / sqrtf(d);
        dinv[n] = dv;
        selfn[n] = 2.0f * dv * dv;
        cnt[n] = c;
    }
}

// ---------------- CSR build ----------------
__global__ void __launch_bounds__(256) k_blocksum(const int* __restrict__ cnt, int* __restrict__ bsum, int n)
{
    __shared__ int red[256];
    int t = threadIdx.x;
    int base = blockIdx.x * 1024;
    int s = 0;
#pragma unroll
    for (int j = 0; j < 4; ++j) {
        int i = base + j * 256 + t;
        if (i < n) s += cnt[i];
    }
    red[t] = s; __syncthreads();
    for (int off = 128; off; off >>= 1) {
        if (t < off) red[t] += red[t + off];
        __syncthreads();
    }
    if (t == 0) bsum[blockIdx.x] = red[0];
}

__global__ void k_scanbsum(const int* __restrict__ bsum, int* __restrict__ boff, int nb,
                           int* __restrict__ rp_last, int total)
{
    if (threadIdx.x == 0 && blockIdx.x == 0) {
        int s = 0;
        for (int i = 0; i < nb; ++i) { boff[i] = s; s += bsum[i]; }
        rp_last[0] = total;
    }
}

__global__ void __launch_bounds__(1024) k_scanchunk(const int* __restrict__ cnt, const int* __restrict__ boff,
                                                    int* __restrict__ rp, int n)
{
    __shared__ int sc[1024];
    int t = threadIdx.x;
    int i = blockIdx.x * 1024 + t;
    int own = (i < n) ? cnt[i] : 0;
    sc[t] = own;
    __syncthreads();
    for (int off = 1; off < 1024; off <<= 1) {
        int v = (t >= off) ? sc[t - off] : 0;
        __syncthreads();
        sc[t] += v;
        __syncthreads();
    }
    if (i < n) rp[i] = boff[blockIdx.x] + sc[t] - own;
}

// placement: NO atomics; packed u32 = (f16 w bits [15] << 17) | src (<2^17)
__global__ void __launch_bounds__(256) k_place2(const int* __restrict__ src, const int* __restrict__ dst,
                                                const float* __restrict__ ed, const float* __restrict__ dinv,
                                                const int* __restrict__ rp, const int* __restrict__ rank,
                                                u32* __restrict__ ew)
{
    int e = blockIdx.x * 256 + threadIdx.x;
    if (e < NE) {
        int d = dst[e], s = src[e];
        int pos = rp[d] + rank[e];
        float w = dinv[s] * ed[e] * dinv[d];
        f16 wh = (f16)w;
        u32 wb = (u32)__builtin_bit_cast(u16, wh);
        ew[pos] = (wb << 17) | (u32)s;
    }
}

// ---------------- SpMM (fp16 row-major gather, u32 packed edges) ----------------
__global__ void __launch_bounds__(256) k_spmm(
    const f16* __restrict__ xwh, const int* __restrict__ rp,
    const u32* __restrict__ ew,
    const float* __restrict__ selfn, const float* __restrict__ cb,
    f16* __restrict__ aggh, double* __restrict__ stats)
{
    int tid = threadIdx.x;
    int slot = tid >> 4;          // 0..15
    int sl = tid & 15;
    int f0 = sl * 8;
    float cbv[8], psum[8], psq[8];
#pragma unroll
    for (int j = 0; j < 8; ++j) { cbv[j] = cb[f0 + j]; psum[j] = 0.f; psq[j] = 0.f; }
    int base = blockIdx.x * 32 + slot * 2;

    for (int i = 0; i < 2; ++i) {
        int n = base + i;
        if (n >= NN) break;
        f16x8 xv = *(const f16x8*)(xwh + (size_t)n * H + f0);
        float sn = selfn[n];
        float a0[8], a1[8], a2[8], a3[8];
#pragma unroll
        for (int j = 0; j < 8; ++j) {
            a0[j] = sn * (float)xv[j] + cbv[j];
            a1[j] = 0.f; a2[j] = 0.f; a3[j] = 0.f;
        }
        int e = rp[n], end = rp[n + 1];
        for (; e + 4 <= end; e += 4) {
            u32 p0 = ew[e], p1 = ew[e + 1], p2 = ew[e + 2], p3 = ew[e + 3];
            float w0 = (float)__builtin_bit_cast(f16, (u16)(p0 >> 17));
            float w1 = (float)__builtin_bit_cast(f16, (u16)(p1 >> 17));
            float w2 = (float)__builtin_bit_cast(f16, (u16)(p2 >> 17));
            float w3 = (float)__builtin_bit_cast(f16, (u16)(p3 >> 17));
            f16x8 v0 = *(const f16x8*)(xwh + (size_t)(p0 & 0x1FFFF) * H + f0);
            f16x8 v1 = *(const f16x8*)(xwh + (size_t)(p1 & 0x1FFFF) * H + f0);
            f16x8 v2 = *(const f16x8*)(xwh + (size_t)(p2 & 0x1FFFF) * H + f0);
            f16x8 v3 = *(const f16x8*)(xwh + (size_t)(p3 & 0x1FFFF) * H + f0);
#pragma unroll
            for (int j = 0; j < 8; ++j) {
                a0[j] += w0 * (float)v0[j];
                a1[j] += w1 * (float)v1[j];
                a2[j] += w2 * (float)v2[j];
                a3[j] += w3 * (float)v3[j];
            }
        }
        for (; e < end; ++e) {
            u32 p = ew[e];
            float w0 = (float)__builtin_bit_cast(f16, (u16)(p >> 17));
            f16x8 v0 = *(const f16x8*)(xwh + (size_t)(p & 0x1FFFF) * H + f0);
#pragma unroll
            for (int j = 0; j < 8; ++j) a0[j] += w0 * (float)v0[j];
        }
        float ax[8];
        f16x8 ah;
#pragma unroll
        for (int j = 0; j < 8; ++j) {
            ax[j] = (a0[j] + a1[j]) + (a2[j] + a3[j]);
            psum[j] += ax[j];
            psq[j] += ax[j] * ax[j];
            ah[j] = (f16)ax[j];
        }
        __builtin_nontemporal_store(ah, (f16x8*)(aggh + (size_t)n * H + f0));
    }

    __shared__ float ssum[16][128], ssq[16][128];
#pragma unroll
    for (int j = 0; j < 8; ++j) { ssum[slot][f0 + j] = psum[j]; ssq[slot][f0 + j] = psq[j]; }
    __syncthreads();
    if (tid < 128) {
        float s = 0.f, q = 0.f;
#pragma unroll
        for (int j = 0; j < 16; ++j) { s += ssum[j][tid]; q += ssq[j][tid]; }
        atomicAdd(&stats[tid], (double)s);
        atomicAdd(&stats[128 + tid], (double)q);
    }
}

// finalize BN scale/shift; self-zero stats for next layer
__global__ void k_finalize(double* __restrict__ stats, const float* __restrict__ bn_g,
                           const float* __restrict__ bn_b, float* __restrict__ scale,
                           float* __restrict__ shift)
{
    int f = threadIdx.x; // 128
    double mu = stats[f] / (double)NN;
    double var = stats[128 + f] / (double)NN - mu * mu;
    double rs = 1.0 / sqrt(var + 1e-5);
    float sc = (float)((double)bn_g[f] * rs);
    scale[f] = sc;
    shift[f] = (float)((double)bn_b[f] - mu * (double)sc);
    stats[f] = 0.0;
    stats[128 + f] = 0.0;
}

// ---------------- goff from SORTED batch: boundary detection, no atomics ----------------
__global__ void __launch_bounds__(256) k_goff2(const int* __restrict__ batch, int* __restrict__ goff)
{
    int n = blockIdx.x * 256 + threadIdx.x;
    if (n >= NN) return;
    int b = batch[n];
    if (n == 0) {
        for (int j = 0; j <= b; ++j) goff[j] = 0;
    }
    int nb = (n == NN - 1) ? NB : batch[n + 1];
    for (int j = b + 1; j <= nb; ++j) goff[j] = n + 1;
}

__global__ void __launch_bounds__(256) k_segsoftmax(const float* __restrict__ e, const int* __restrict__ goff,
                                                    float* __restrict__ w)
{
    int b = blockIdx.x;
    int beg = goff[b], end = goff[b + 1];
    int t = threadIdx.x;
    __shared__ float red[8], red2[8];
    float m = -INFINITY;
    for (int i = beg + t; i < end; i += 256) m = fmaxf(m, e[i]);
    for (int off = 32; off; off >>= 1) m = fmaxf(m, __shfl_down(m, off));
    if ((t & 63) == 0) red[t >> 6] = m;
    __syncthreads();
    float m0 = fmaxf(fmaxf(red[0], red[1]), fmaxf(red[2], red[3]));
    float s = 0.f;
    for (int i = beg + t; i < end; i += 256) s += expf(e[i] - m0);
    for (int off = 32; off; off >>= 1) s += __shfl_down(s, off);
    if ((t & 63) == 0) red2[t >> 6] = s;
    __syncthreads();
    float s0 = red2[0] + red2[1] + red2[2] + red2[3];
    for (int i = beg + t; i < end; i += 256) w[i] = expf(e[i] - m0) / s0;
}

// reconstruct x from split, scale by node weight, write fp16 (into xw region)
__global__ void __launch_bounds__(256) k_scalex16(const u16* __restrict__ xhi, const u16* __restrict__ xlo,
                                                  const float* __restrict__ w, f16* __restrict__ xf)
{
    int i8 = blockIdx.x * 256 + threadIdx.x;
    if (i8 >= NN * 16) return;
    float ww = w[i8 >> 4];
    u16x8 hh = ((const u16x8*)xhi)[i8];
    u16x8 ll = ((const u16x8*)xlo)[i8];
    f16x8 v;
#pragma unroll
    for (int j = 0; j < 8; ++j)
        v[j] = (f16)((bf2f(hh[j]) + bf2f(ll[j])) * ww);
    ((f16x8*)xf)[i8] = v;
}

// ---------------- Set2Set: fused gates + LSTM, 8 graphs per block ----------------
__device__ __forceinline__ float sigmoidf_(float v) { return 1.f / (1.f + expf(-v)); }

__global__ void __launch_bounds__(256) k_gateslstm(
    const float* __restrict__ qstar, const float* __restrict__ Wih, const float* __restrict__ Whh,
    const float* __restrict__ bih, const float* __restrict__ bhh,
    float* __restrict__ cs, float* __restrict__ hs)
{
    __shared__ float qs[8][256];
    __shared__ float hh[8][128];
    __shared__ float gs[8][512];
    int t = threadIdx.x;
    int b0 = blockIdx.x * 8;
    for (int i = t; i < 8 * 256; i += 256) qs[i >> 8][i & 255] = qstar[b0 * 256 + i];
    for (int i = t; i < 8 * 128; i += 256) hh[i >> 7][i & 127] = hs[b0 * 128 + i];
    __syncthreads();
    for (int gg = t; gg < 512; gg += 256) {
        float acc[8];
        float bb = bih[gg] + bhh[gg];
#pragma unroll
        for (int g = 0; g < 8; ++g) acc[g] = bb;
        const float4* w4 = (const float4*)(Wih + (size_t)gg * 256);
        for (int k = 0; k < 64; ++k) {
            float4 w = w4[k];
#pragma unroll
            for (int g = 0; g < 8; ++g) {
                float4 q = *(const float4*)&qs[g][k * 4];
                acc[g] += q.x * w.x + q.y * w.y + q.z * w.z + q.w * w.w;
            }
        }
        const float4* v4 = (const float4*)(Whh + (size_t)gg * 128);
        for (int k = 0; k < 32; ++k) {
            float4 w = v4[k];
#pragma unroll
            for (int g = 0; g < 8; ++g) {
                float4 q = *(const float4*)&hh[g][k * 4];
                acc[g] += q.x * w.x + q.y * w.y + q.z * w.z + q.w * w.w;
            }
        }
#pragma unroll
        for (int g = 0; g < 8; ++g) gs[g][gg] = acc[g];
    }
    __syncthreads();
    for (int i = t; i < 1024; i += 256) {
        int g = i >> 7, f = i & 127;
        int idx = (b0 + g) * 128 + f;
        float gi = gs[g][f], gf = gs[g][128 + f], gg2 = gs[g][256 + f], go = gs[g][384 + f];
        float c = sigmoidf_(gf) * cs[idx] + sigmoidf_(gi) * tanhf(gg2);
        cs[idx] = c;
        hs[idx] = sigmoidf_(go) * tanhf(c);
    }
}

// ---------------- Set2Set fused attention: en + softmax + r, one block per graph, fp16 x ----------------
__global__ void __launch_bounds__(256) k_s2s(const f16* __restrict__ x16, const float* __restrict__ hs,
                                             const int* __restrict__ goff,
                                             float* __restrict__ esc, float* __restrict__ qstar)
{
    __shared__ float q[128];
    __shared__ float red[4], red2[4];
    __shared__ float partr[3][128];
    int b = blockIdx.x, t = threadIdx.x;
    int beg = goff[b], end = goff[b + 1];
    if (t < 128) q[t] = hs[b * 128 + t];
    __syncthreads();

    int wv = t >> 6, ln = t & 63;
    // pass 1: en scores (64 lanes x 2 feats) + wave max
    float m = -INFINITY;
    for (int i = beg + wv; i < end; i += 4) {
        u32 xp = *(const u32*)(x16 + (size_t)i * H + ln * 2);
        float xl = (float)__builtin_bit_cast(f16, (u16)(xp & 0xFFFF));
        float xh = (float)__builtin_bit_cast(f16, (u16)(xp >> 16));
        float pd = xl * q[ln * 2] + xh * q[ln * 2 + 1];
        for (int off = 32; off; off >>= 1) pd += __shfl_down(pd, off);
        pd = __shfl(pd, 0);
        if (ln == 0) esc[i] = pd;
        m = fmaxf(m, pd);
    }
    if (ln == 0) red[wv] = m;
    __syncthreads();
    float m0 = fmaxf(fmaxf(red[0], red[1]), fmaxf(red[2], red[3]));
    // pass 1b: exp + sum (store unnormalized weight back to esc)
    float s = 0.f;
    for (int i = beg + t; i < end; i += 256) {
        float e = expf(esc[i] - m0);
        esc[i] = e;
        s += e;
    }
    for (int off = 32; off; off >>= 1) s += __shfl_down(s, off);
    if (ln == 0) red2[wv] = s;
    __syncthreads();
    float s0 = red2[0] + red2[1] + red2[2] + red2[3];
    float inv = (s0 > 0.f) ? 1.f / s0 : 0.f;
    // pass 2: r = sum w * x ; thread covers feat pair f2, quarter q4
    int q4 = t >> 6, f2 = (t & 63) * 2;
    float a0 = 0.f, a1 = 0.f;
    for (int i = beg + q4; i < end; i += 4) {
        float w = esc[i];
        u32 xp = *(const u32*)(x16 + (size_t)i * H + f2);
        a0 += w * (float)__builtin_bit_cast(f16, (u16)(xp & 0xFFFF));
        a1 += w * (float)__builtin_bit_cast(f16, (u16)(xp >> 16));
    }
    if (q4 > 0) { partr[q4 - 1][f2] = a0; partr[q4 - 1][f2 + 1] = a1; }
    __syncthreads();
    if (q4 == 0) {
        a0 += partr[0][f2] + partr[1][f2] + partr[2][f2];
        a1 += partr[0][f2 + 1] + partr[1][f2 + 1] + partr[2][f2 + 1];
        qstar[b * 256 + f2] = q[f2];
        qstar[b * 256 + f2 + 1] = q[f2 + 1];
        qstar[b * 256 + 128 + f2] = a0 * inv;
        qstar[b * 256 + 128 + f2 + 1] = a1 * inv;
    }
}

// ---------------- head ----------------
__global__ void __launch_bounds__(256) k_head1(const float* __restrict__ qstar, const float* __restrict__ W,
                                               const float* __restrict__ bias, float* __restrict__ y1)
{
    __shared__ float qs[256];
    int b = blockIdx.x, t = threadIdx.x;
    qs[t] = qstar[b * 256 + t];
    __syncthreads();
    float acc = bias[t];
    for (int k = 0; k < 256; ++k) acc += qs[k] * W[k * 256 + t];
    y1[b * 256 + t] = fmaxf(acc, 0.f);
}

__global__ void __launch_bounds__(256) k_head2(const float* __restrict__ y1, const float* __restrict__ W1,
                                               const float* __restrict__ b1, const float* __restrict__ W2,
                                               const float* __restrict__ b2, float* __restrict__ out)
{
    __shared__ float ys[256];
    __shared__ float z[32];
    int b = blockIdx.x, t = threadIdx.x;
    ys[t] = y1[b * 256 + t];
    __syncthreads();
    if (t < 32) {
        float acc = b1[t];
        for (int k = 0; k < 256; ++k) acc += ys[k] * W1[k * 32 + t];
        z[t] = fmaxf(acc, 0.f);
    }
    __syncthreads();
    if (t == 0) {
        float s = b2[0];
        for (int j = 0; j < 32; ++j) s += z[j] * W2[j];
        out[b] = s;
    }
}

// ---------------- launch ----------------
extern "C" void kernel_launch(void* const* d_in, const int* in_sizes, int n_in,
                              void* d_out, int out_size, void* d_ws, size_t ws_size,
                              hipStream_t stream)
{
    const float* in_x        = (const float*)d_in[0];
    const int*   edge_index  = (const int*)d_in[1];
    const float* edge_dist   = (const float*)d_in[2];
    const float* global_info = (const float*)d_in[3];
    const int*   batch       = (const int*)d_in[4];
    const float* lin_W  = (const float*)d_in[5];
    const float* lin_b  = (const float*)d_in[6];
    const float* conv_W = (const float*)d_in[7];
    const float* conv_b = (const float*)d_in[8];
    const float* bn_g   = (const float*)d_in[9];
    const float* bn_b   = (const float*)d_in[10];
    const float* gat_in_W  = (const float*)d_in[11];
    const float* gat_in_b  = (const float*)d_in[12];
    const float* gat_lin_W = (const float*)d_in[13];
    const float* gat_lin_b = (const float*)d_in[14];
    const float* gat_out_W = (const float*)d_in[15];
    const float* gat_out_b = (const float*)d_in[16];
    const float* lstm_Wih = (const float*)d_in[17];
    const float* lstm_Whh = (const float*)d_in[18];
    const float* lstm_bih = (const float*)d_in[19];
    const float* lstm_bhh = (const float*)d_in[20];
    const float* mlp_W  = (const float*)d_in[21];
    const float* mlp_b  = (const float*)d_in[22];
    const float* out1_W = (const float*)d_in[23];
    const float* out1_b = (const float*)d_in[24];
    const float* out2_W = (const float*)d_in[25];
    const float* out2_b = (const float*)d_in[26];
    float* out = (float*)d_out;

    const int* e_src = edge_index;
    const int* e_dst = edge_index + NE;

    char* p = (char*)d_ws;
    auto alloc = [&](size_t bytes) -> void* {
        void* r = (void*)p;
        p += (bytes + 255) & ~(size_t)255;
        return r;
    };
    u16*    cx_hi = (u16*)alloc((size_t)NN * H * 2);
    u16*    cx_lo = (u16*)alloc((size_t)NN * H * 2);
    float*  xw    = (float*)alloc((size_t)NN * H * 4);   // fp16 xwh (conv) / gi split (gat) / fp16 x (s2s)
    float*  agg   = (float*)alloc((size_t)NN * H * 4);   // fp16 aggh; CSR: degcnt+rank
    u16*    wthi  = (u16*)alloc((size_t)160000 * 2);
    u16*    wtlo  = (u16*)alloc((size_t)160000 * 2);
    float*  dinv  = (float*)alloc((size_t)NN * 4);
    float*  selfn = (float*)alloc((size_t)NN * 4);
    int*    cnt   = (int*)alloc((size_t)NN * 4);
    int*    rp    = (int*)alloc((size_t)(NN + 1) * 4);
    int*    bsum  = (int*)alloc(128 * 4);
    int*    boff  = (int*)alloc(128 * 4);
    u32*    ew    = (u32*)alloc((size_t)NE * 4);         // packed (w:f16<<17 | src); Set2Set aliases
    double* stats = (double*)alloc(256 * 8);
    float*  scale = (float*)alloc(128 * 4);
    float*  shift = (float*)alloc(128 * 4);

    f16*   xwh    = (f16*)xw;
    f16*   aggh   = (f16*)agg;
    u64*   degcnt = (u64*)agg;
    int*   rank   = (int*)((char*)agg + (1 << 20));
    u16*   gi_hi  = (u16*)xw;                        // gat phase: gi/gb split in xw region
    u16*   gi_lo  = gi_hi + (size_t)NN * H;
    float* esc    = dinv;
    float* wn     = selfn;
    int*   goff   = cnt;
    float* hs     = (float*)ew;
    float* csb    = hs + NB * H;
    float* qstar  = csb + NB * H;
    float* y1     = qstar + NB * 2 * H;

    const int GB_E = (NE + 255) / 256;
    const int GB_N = (NN + 255) / 256;
    const int NCH = (NN + 1023) / 1024;
    const int GB_MG = (NN + GBM - 1) / GBM;
    const int GB_SPMM = (NN + 31) / 32;
    const int GB_V8 = (NN * 16) / 256 + 1;

    // ---- all weight splits, one launch ----
    WJobs jobs;
    const float* Wl[9] = {lin_W, conv_W, conv_W + (size_t)H * H, conv_W + (size_t)2 * H * H,
                          conv_W + (size_t)3 * H * H, conv_W + (size_t)4 * H * H,
                          gat_in_W, gat_lin_W, gat_lin_W + (size_t)H * H};
    int Ks[9]  = {DIN, H, H, H, H, H, H + DGI, H, H};
    int Kps[9] = {96, H, H, H, H, H, 256, H, H};
    long long eoffs[9];
    long long eo = 0;
    for (int i = 0; i < 9; ++i) {
        jobs.W[i] = Wl[i]; jobs.K[i] = Ks[i]; jobs.Kpad[i] = Kps[i]; jobs.eoff[i] = eo;
        eoffs[i] = eo;
        eo += (long long)128 * Kps[i];
    }
    k_splitW_all<<<dim3(128, 2, 9), 128, 0, stream>>>(jobs, wthi, wtlo);

    // ---- graph norm + CSR ----
    hipMemsetAsync(degcnt, 0, (size_t)NN * 8, stream);
    hipMemsetAsync(stats, 0, 256 * 8, stream);
    k_deg2<<<GB_E, 256, 0, stream>>>(e_dst, edge_dist, degcnt, rank);
    k_dinv2<<<GB_N, 256, 0, stream>>>(degcnt, dinv, selfn, cnt);
    k_blocksum<<<NCH, 256, 0, stream>>>(cnt, bsum, NN);
    k_scanbsum<<<1, 64, 0, stream>>>(bsum, boff, NCH, rp + NN, NE);
    k_scanchunk<<<NCH, 1024, 0, stream>>>(cnt, boff, rp, NN);
    k_place2<<<GB_E, 256, 0, stream>>>(e_src, e_dst, edge_dist, dinv, rp, rank, ew);

    // ---- input projection ----
    k_split<<<dim3(NN, 1), 128, 0, stream>>>(in_x, DIN, DIN, cx_hi, cx_lo, H, 0, 96);
    k_mgemm<1, 1, 96, 0><<<GB_MG, 256, 0, stream>>>(cx_hi, cx_lo, H, 96, cx_hi, cx_lo, H,
                                                    wthi + eoffs[0], wtlo + eoffs[0], lin_b,
                                                    nullptr, cx_hi, cx_lo, H, nullptr,
                                                    nullptr, nullptr, nullptr,
                                                    nullptr, nullptr, nullptr, nullptr, nullptr, NN);

    // ---- conv stack (bnres of layer l-1 fused into A-staging of mgemm l) ----
    for (int l = 0; l < NL; ++l) {
        if (l == 0) {
            k_mgemm<0, 2, 128, 0><<<GB_MG, 256, 0, stream>>>(cx_hi, cx_lo, H, H, cx_hi, cx_lo, H,
                                                             wthi + eoffs[1 + l], wtlo + eoffs[1 + l], nullptr,
                                                             nullptr, nullptr, nullptr, 0, xwh,
                                                             nullptr, nullptr, nullptr,
                                                             nullptr, nullptr, nullptr, nullptr, nullptr, NN);
        } else {
            k_mgemm<0, 2, 128, 1><<<GB_MG, 256, 0, stream>>>(cx_hi, cx_lo, H, H, cx_hi, cx_lo, H,
                                                             wthi + eoffs[1 + l], wtlo + eoffs[1 + l], nullptr,
                                                             nullptr, nullptr, nullptr, 0, xwh,
                                                             nullptr, nullptr, nullptr,
                                                             aggh, scale, shift, cx_hi, cx_lo, NN);
        }
        k_spmm<<<GB_SPMM, 256, 0, stream>>>(xwh, rp, ew, selfn, conv_b + (size_t)l * H, aggh, stats);
        k_finalize<<<1, 128, 0, stream>>>(stats, bn_g, bn_b, scale, shift);
    }

    // ---- global attention (layer-4 bnres fused into gat-in mgemm; gi split in xw region) ----
    k_split<<<dim3(NN, 1), 128, 0, stream>>>(global_info, DGI, DGI, gi_hi, gi_lo, H, 0, H);
    k_mgemm<1, 1, 256, 1><<<GB_MG, 256, 0, stream>>>(cx_hi, cx_lo, H, H, gi_hi, gi_lo, H,
                                                     wthi + eoffs[6], wtlo + eoffs[6], gat_in_b,
                                                     nullptr, gi_hi, gi_lo, H, nullptr,
                                                     nullptr, nullptr, nullptr,
                                                     aggh, scale, shift, cx_hi, cx_lo, NN);
    k_mgemm<1, 1, 128, 0><<<GB_MG, 256, 0, stream>>>(gi_hi, gi_lo, H, H, gi_hi, gi_lo, H,
                                                     wthi + eoffs[7], wtlo + eoffs[7], gat_lin_b,
                                                     nullptr, gi_hi, gi_lo, H, nullptr,
                                                     nullptr, nullptr, nullptr,
                                                     nullptr, nullptr, nullptr, nullptr, nullptr, NN);
    k_mgemm<1, 3, 128, 0><<<GB_MG, 256, 0, stream>>>(gi_hi, gi_lo, H, H, gi_hi, gi_lo, H,
                                                     wthi + eoffs[8], wtlo + eoffs[8], gat_lin_b + H,
                                                     nullptr, nullptr, nullptr, 0, nullptr,
                                                     gat_out_W, gat_out_b, esc,
                                                     nullptr, nullptr, nullptr, nullptr, nullptr, NN);
    k_goff2<<<GB_N, 256, 0, stream>>>(batch, goff);
    k_segsoftmax<<<NB, 256, 0, stream>>>(esc, goff, wn);
    k_scalex16<<<GB_V8, 256, 0, stream>>>(cx_hi, cx_lo, wn, (f16*)xw);  // gi region dead after gat3

    // ---- Set2Set (hs/csb/qstar alias ew region, dead after conv stack) ----
    hipMemsetAsync(hs, 0, (size_t)NB * H * 4, stream);
    hipMemsetAsync(csb, 0, (size_t)NB * H * 4, stream);
    hipMemsetAsync(qstar, 0, (size_t)NB * 2 * H * 4, stream);
    for (int it = 0; it < 3; ++it) {
        k_gateslstm<<<NB / 8, 256, 0, stream>>>(qstar, lstm_Wih, lstm_Whh, lstm_bih, lstm_bhh, csb, hs);
        k_s2s<<<NB, 256, 0, stream>>>((const f16*)xw, hs, goff, esc, qstar);
    }

    // ---- head ----
    k_head1<<<NB, 256, 0, stream>>>(qstar, mlp_W, mlp_b, y1);
    k_head2<<<NB, 256, 0, stream>>>(y1, out1_W, out1_b, out2_W, out2_b, out);
}

// Round 12
// 1379.098 us; speedup vs baseline: 1.2702x; 1.0221x over previous
//
#include <hip/hip_runtime.h>
#include <math.h>

#define NN 100000
#define NE 1600000
#define DIN 92
#define H 128
#define NB 512
#define DGI 107
#define NL 5

typedef unsigned short u16;
typedef unsigned int u32;
typedef unsigned long long u64;
typedef short bf16x8 __attribute__((ext_vector_type(8)));
typedef float f32x4 __attribute__((ext_vector_type(4)));
typedef _Float16 f16;
typedef _Float16 f16x8 __attribute__((ext_vector_type(8)));
typedef unsigned short u16x8 __attribute__((ext_vector_type(8)));

__device__ __forceinline__ u16 f2bf(float f) {
    unsigned u = __builtin_bit_cast(unsigned, f);
    u += 0x7FFF + ((u >> 16) & 1);
    return (u16)(u >> 16);
}
__device__ __forceinline__ float bf2f(u16 h) {
    unsigned u = ((unsigned)h) << 16;
    return __builtin_bit_cast(float, u);
}

// ---------------- all weight splits in ONE launch ----------------
struct WJobs {
    const float* W[9];
    long long eoff[9];
    int K[9];
    int Kpad[9];
};

__global__ void __launch_bounds__(128) k_splitW_all(WJobs jobs, u16* __restrict__ wthi, u16* __restrict__ wtlo)
{
    int j = blockIdx.z;
    int c = blockIdx.x;
    int k = blockIdx.y * 128 + threadIdx.x;
    int Kp = jobs.Kpad[j];
    if (k >= Kp) return;
    const float* W = jobs.W[j];
    float v = (k < jobs.K[j]) ? W[(size_t)k * H + c] : 0.f;
    u16 h = f2bf(v);
    float r = v - bf2f(h);
    size_t o = (size_t)jobs.eoff[j] + (size_t)c * Kp + k;
    wthi[o] = h;
    wtlo[o] = f2bf(r);
}

// ---------------- MFMA GEMM: C[M,128] = act([A1|A2]@W + b), bf16x3 compensated ----------------
// OMODE: 0=f32, 1=bf16 split, 2=fp16 row-major, 3=fused escore. KPAD compile-time.
// AMODE: 0=plain; 1=A1 bnres-fused (cx+agg, write-back); 2=A1 from fp32 Fsrc (on-the-fly split);
//        3=A1 bnres-fused + A2 from fp32 Fsrc
#define GBM 128

template<int RELU, int OMODE, int KPAD, int AMODE>
__global__ void __launch_bounds__(256) k_mgemm(
    const u16* __restrict__ A1hi, const u16* __restrict__ A1lo, int lda1, int K1,
    const u16* __restrict__ A2hi, const u16* __restrict__ A2lo, int lda2,
    const u16* __restrict__ Wthi, const u16* __restrict__ Wtlo,
    const float* __restrict__ bias,
    float* __restrict__ Cf, u16* __restrict__ Chi, u16* __restrict__ Clo, int ldsp,
    f16* __restrict__ Ch,
    const float* __restrict__ Gow, const float* __restrict__ GobP, float* __restrict__ Esc,
    const f16* __restrict__ Agg, const float* __restrict__ Sc, const float* __restrict__ Sh,
    u16* __restrict__ WBhi, u16* __restrict__ WBlo,
    const float* __restrict__ Fsrc, int FW,
    int M)
{
    __shared__ __align__(16) u16 As[2][128][40];
    __shared__ __align__(16) u16 Ws[2][128][40];
    int tid = threadIdx.x;
    int w = tid >> 6, l = tid & 63;
    int row0 = blockIdx.x * GBM;
    int lr = l & 15, kq = l >> 4;

    f32x4 acc[2][8];
#pragma unroll
    for (int rf = 0; rf < 2; ++rf)
#pragma unroll
        for (int cf = 0; cf < 8; ++cf)
            acc[rf][cf] = (f32x4){0.f, 0.f, 0.f, 0.f};

#pragma unroll
    for (int k0 = 0; k0 < KPAD; k0 += 32) {
        const u16* sAh = (k0 < K1) ? A1hi : A2hi;
        const u16* sAl = (k0 < K1) ? A1lo : A2lo;
        int ldc = (k0 < K1) ? lda1 : lda2;
        int kc = (k0 < K1) ? k0 : (k0 - K1);
#pragma unroll
        for (int i = 0; i < 2; ++i) {
            int chunk = tid + i * 256;
            int r = chunk >> 2, q = chunk & 3;
            int gr = row0 + r; if (gr >= M) gr = M - 1;
            int col0 = kc + q * 8;
            int4 va, vb;
            bool fsplit = (AMODE == 2 && k0 < K1) || (AMODE == 3 && k0 >= K1);
            if (fsplit) {
                // on-the-fly split from fp32 source (guarded, zero-pad >= FW)
                u16x8 hh, ll;
#pragma unroll
                for (int j = 0; j < 8; ++j) {
                    int c = col0 + j;
                    float v = (c < FW) ? Fsrc[(size_t)gr * FW + c] : 0.f;
                    u16 h = f2bf(v);
                    hh[j] = h;
                    ll[j] = f2bf(v - bf2f(h));
                }
                va = __builtin_bit_cast(int4, hh);
                vb = __builtin_bit_cast(int4, ll);
            } else {
                va = *(const int4*)(sAh + (size_t)gr * ldc + col0);
                vb = *(const int4*)(sAl + (size_t)gr * ldc + col0);
                if ((AMODE == 1 || AMODE == 3) && k0 < K1) {
                    // fused bnres: new_x = old_x + agg*scale + shift; re-split; write back
                    f16x8 av = *(const f16x8*)(Agg + (size_t)gr * H + col0);
                    u16x8 hh = __builtin_bit_cast(u16x8, va);
                    u16x8 ll = __builtin_bit_cast(u16x8, vb);
                    float4 sc0 = *(const float4*)(Sc + col0);
                    float4 sc1 = *(const float4*)(Sc + col0 + 4);
                    float4 sh0 = *(const float4*)(Sh + col0);
                    float4 sh1 = *(const float4*)(Sh + col0 + 4);
                    float scv[8] = {sc0.x, sc0.y, sc0.z, sc0.w, sc1.x, sc1.y, sc1.z, sc1.w};
                    float shv[8] = {sh0.x, sh0.y, sh0.z, sh0.w, sh1.x, sh1.y, sh1.z, sh1.w};
#pragma unroll
                    for (int j = 0; j < 8; ++j) {
                        float v = bf2f(hh[j]) + bf2f(ll[j]) + (float)av[j] * scv[j] + shv[j];
                        u16 h = f2bf(v);
                        hh[j] = h;
                        ll[j] = f2bf(v - bf2f(h));
                    }
                    va = __builtin_bit_cast(int4, hh);
                    vb = __builtin_bit_cast(int4, ll);
                    *(int4*)(WBhi + (size_t)gr * lda1 + col0) = va;
                    *(int4*)(WBlo + (size_t)gr * lda1 + col0) = vb;
                }
            }
            int4 wa = *(const int4*)(Wthi + (size_t)r * KPAD + k0 + q * 8);
            int4 wb = *(const int4*)(Wtlo + (size_t)r * KPAD + k0 + q * 8);
            *(int4*)&As[0][r][q * 8] = va;
            *(int4*)&As[1][r][q * 8] = vb;
            *(int4*)&Ws[0][r][q * 8] = wa;
            *(int4*)&Ws[1][r][q * 8] = wb;
        }
        __syncthreads();

        bf16x8 aH[2], aL[2];
#pragma unroll
        for (int rf = 0; rf < 2; ++rf) {
            aH[rf] = *(const bf16x8*)&As[0][w * 32 + rf * 16 + lr][kq * 8];
            aL[rf] = *(const bf16x8*)&As[1][w * 32 + rf * 16 + lr][kq * 8];
        }
#pragma unroll
        for (int cf = 0; cf < 8; ++cf) {
            bf16x8 bH = *(const bf16x8*)&Ws[0][cf * 16 + lr][kq * 8];
            bf16x8 bL = *(const bf16x8*)&Ws[1][cf * 16 + lr][kq * 8];
#pragma unroll
            for (int rf = 0; rf < 2; ++rf) {
                acc[rf][cf] = __builtin_amdgcn_mfma_f32_16x16x32_bf16(aH[rf], bH, acc[rf][cf], 0, 0, 0);
                acc[rf][cf] = __builtin_amdgcn_mfma_f32_16x16x32_bf16(aH[rf], bL, acc[rf][cf], 0, 0, 0);
                acc[rf][cf] = __builtin_amdgcn_mfma_f32_16x16x32_bf16(aL[rf], bH, acc[rf][cf], 0, 0, 0);
            }
        }
        __syncthreads();
    }

    if (OMODE == 3) {
        float gowv[8], bvv[8];
#pragma unroll
        for (int cf = 0; cf < 8; ++cf) {
            gowv[cf] = Gow[cf * 16 + lr];
            bvv[cf] = bias[cf * 16 + lr];
        }
        float gob0 = GobP[0];
#pragma unroll
        for (int rf = 0; rf < 2; ++rf) {
#pragma unroll
            for (int r = 0; r < 4; ++r) {
                float part = 0.f;
#pragma unroll
                for (int cf = 0; cf < 8; ++cf) {
                    float v = fmaxf(acc[rf][cf][r] + bvv[cf], 0.f);
                    part += v * gowv[cf];
                }
                part += __shfl_xor(part, 1);
                part += __shfl_xor(part, 2);
                part += __shfl_xor(part, 4);
                part += __shfl_xor(part, 8);
                int grow = row0 + w * 32 + rf * 16 + kq * 4 + r;
                if (lr == 0 && grow < M) Esc[grow] = part + gob0;
            }
        }
        return;
    }

#pragma unroll
    for (int cf = 0; cf < 8; ++cf) {
        int col = cf * 16 + lr;
        float bv = bias ? bias[col] : 0.f;
#pragma unroll
        for (int rf = 0; rf < 2; ++rf) {
#pragma unroll
            for (int r = 0; r < 4; ++r) {
                int grow = row0 + w * 32 + rf * 16 + kq * 4 + r;
                if (grow < M) {
                    float v = acc[rf][cf][r] + bv;
                    if (RELU) v = fmaxf(v, 0.f);
                    if (OMODE == 0) Cf[(size_t)grow * H + col] = v;
                    if (OMODE == 1) {
                        u16 hh = f2bf(v);
                        Chi[(size_t)grow * ldsp + col] = hh;
                        Clo[(size_t)grow * ldsp + col] = f2bf(v - bf2f(hh));
                    }
                    if (OMODE == 2) Ch[(size_t)grow * H + col] = (f16)v;
                }
            }
        }
    }
}

// ---------------- degree + counts: one packed 64-bit atomic per edge ----------------
__global__ void __launch_bounds__(256) k_deg2(const int* __restrict__ dst, const float* __restrict__ ed,
                                              u64* __restrict__ degcnt, int* __restrict__ rank)
{
    int e = blockIdx.x * 256 + threadIdx.x;
    if (e < NE) {
        int d = dst[e];
        u64 pk = ((u64)1 << 40) | (u64)(ed[e] * 16777216.0f);
        u64 old = atomicAdd(&degcnt[d], pk);
        rank[e] = (int)(old >> 40);
    }
}

__global__ void __launch_bounds__(256) k_dinv2(const u64* __restrict__ degcnt,
                                               float* __restrict__ dinv, float* __restrict__ selfn,
                                               int* __restrict__ cnt)
{
    int n = blockIdx.x * 256 + threadIdx.x;
    if (n < NN) {
        u64 v = degcnt[n];
        int c = (int)(v >> 40);
        float deg = (float)((double)(v & (((u64)1 << 40) - 1)) * (1.0 / 16777216.0));
        float d = deg + 2.0f;
        float dv = 1.0f / sqrtf(d);
        dinv[n] = dv;
        selfn[n] = 2.0f * dv * dv;
        cnt[n] = c;
    }
}

// ---------------- CSR build ----------------
__global__ void __launch_bounds__(256) k_blocksum(const int* __restrict__ cnt, int* __restrict__ bsum, int n)
{
    __shared__ int red[256];
    int t = threadIdx.x;
    int base = blockIdx.x * 1024;
    int s = 0;
#pragma unroll
    for (int j = 0; j < 4; ++j) {
        int i = base + j * 256 + t;
        if (i < n) s += cnt[i];
    }
    red[t] = s; __syncthreads();
    for (int off = 128; off; off >>= 1) {
        if (t < off) red[t] += red[t + off];
        __syncthreads();
    }
    if (t == 0) bsum[blockIdx.x] = red[0];
}

__global__ void k_scanbsum(const int* __restrict__ bsum, int* __restrict__ boff, int nb,
                           int* __restrict__ rp_last, int total)
{
    if (threadIdx.x == 0 && blockIdx.x == 0) {
        int s = 0;
        for (int i = 0; i < nb; ++i) { boff[i] = s; s += bsum[i]; }
        rp_last[0] = total;
    }
}

__global__ void __launch_bounds__(1024) k_scanchunk(const int* __restrict__ cnt, const int* __restrict__ boff,
                                                    int* __restrict__ rp, int n)
{
    __shared__ int sc[1024];
    int t = threadIdx.x;
    int i = blockIdx.x * 1024 + t;
    int own = (i < n) ? cnt[i] : 0;
    sc[t] = own;
    __syncthreads();
    for (int off = 1; off < 1024; off <<= 1) {
        int v = (t >= off) ? sc[t - off] : 0;
        __syncthreads();
        sc[t] += v;
        __syncthreads();
    }
    if (i < n) rp[i] = boff[blockIdx.x] + sc[t] - own;
}

// placement: NO atomics; packed u32 = (f16 w bits [15] << 17) | src (<2^17)
__global__ void __launch_bounds__(256) k_place2(const int* __restrict__ src, const int* __restrict__ dst,
                                                const float* __restrict__ ed, const float* __restrict__ dinv,
                                                const int* __restrict__ rp, const int* __restrict__ rank,
                                                u32* __restrict__ ew)
{
    int e = blockIdx.x * 256 + threadIdx.x;
    if (e < NE) {
        int d = dst[e], s = src[e];
        int pos = rp[d] + rank[e];
        float w = dinv[s] * ed[e] * dinv[d];
        f16 wh = (f16)w;
        u32 wb = (u32)__builtin_bit_cast(u16, wh);
        ew[pos] = (wb << 17) | (u32)s;
    }
}

// ---------------- SpMM (fp16 row-major gather, u32 packed edges) ----------------
__global__ void __launch_bounds__(256) k_spmm(
    const f16* __restrict__ xwh, const int* __restrict__ rp,
    const u32* __restrict__ ew,
    const float* __restrict__ selfn, const float* __restrict__ cb,
    f16* __restrict__ aggh, double* __restrict__ stats)
{
    int tid = threadIdx.x;
    int slot = tid >> 4;          // 0..15
    int sl = tid & 15;
    int f0 = sl * 8;
    float cbv[8], psum[8], psq[8];
#pragma unroll
    for (int j = 0; j < 8; ++j) { cbv[j] = cb[f0 + j]; psum[j] = 0.f; psq[j] = 0.f; }
    int base = blockIdx.x * 32 + slot * 2;

    for (int i = 0; i < 2; ++i) {
        int n = base + i;
        if (n >= NN) break;
        f16x8 xv = *(const f16x8*)(xwh + (size_t)n * H + f0);
        float sn = selfn[n];
        float a0[8], a1[8], a2[8], a3[8];
#pragma unroll
        for (int j = 0; j < 8; ++j) {
            a0[j] = sn * (float)xv[j] + cbv[j];
            a1[j] = 0.f; a2[j] = 0.f; a3[j] = 0.f;
        }
        int e = rp[n], end = rp[n + 1];
        for (; e + 4 <= end; e += 4) {
            u32 p0 = ew[e], p1 = ew[e + 1], p2 = ew[e + 2], p3 = ew[e + 3];
            float w0 = (float)__builtin_bit_cast(f16, (u16)(p0 >> 17));
            float w1 = (float)__builtin_bit_cast(f16, (u16)(p1 >> 17));
            float w2 = (float)__builtin_bit_cast(f16, (u16)(p2 >> 17));
            float w3 = (float)__builtin_bit_cast(f16, (u16)(p3 >> 17));
            f16x8 v0 = *(const f16x8*)(xwh + (size_t)(p0 & 0x1FFFF) * H + f0);
            f16x8 v1 = *(const f16x8*)(xwh + (size_t)(p1 & 0x1FFFF) * H + f0);
            f16x8 v2 = *(const f16x8*)(xwh + (size_t)(p2 & 0x1FFFF) * H + f0);
            f16x8 v3 = *(const f16x8*)(xwh + (size_t)(p3 & 0x1FFFF) * H + f0);
#pragma unroll
            for (int j = 0; j < 8; ++j) {
                a0[j] += w0 * (float)v0[j];
                a1[j] += w1 * (float)v1[j];
                a2[j] += w2 * (float)v2[j];
                a3[j] += w3 * (float)v3[j];
            }
        }
        for (; e < end; ++e) {
            u32 p = ew[e];
            float w0 = (float)__builtin_bit_cast(f16, (u16)(p >> 17));
            f16x8 v0 = *(const f16x8*)(xwh + (size_t)(p & 0x1FFFF) * H + f0);
#pragma unroll
            for (int j = 0; j < 8; ++j) a0[j] += w0 * (float)v0[j];
        }
        float ax[8];
        f16x8 ah;
#pragma unroll
        for (int j = 0; j < 8; ++j) {
            ax[j] = (a0[j] + a1[j]) + (a2[j] + a3[j]);
            psum[j] += ax[j];
            psq[j] += ax[j] * ax[j];
            ah[j] = (f16)ax[j];
        }
        __builtin_nontemporal_store(ah, (f16x8*)(aggh + (size_t)n * H + f0));
    }

    __shared__ float ssum[16][128], ssq[16][128];
#pragma unroll
    for (int j = 0; j < 8; ++j) { ssum[slot][f0 + j] = psum[j]; ssq[slot][f0 + j] = psq[j]; }
    __syncthreads();
    if (tid < 128) {
        float s = 0.f, q = 0.f;
#pragma unroll
        for (int j = 0; j < 16; ++j) { s += ssum[j][tid]; q += ssq[j][tid]; }
        atomicAdd(&stats[tid], (double)s);
        atomicAdd(&stats[128 + tid], (double)q);
    }
}

// finalize BN scale/shift; self-zero stats for next layer
__global__ void k_finalize(double* __restrict__ stats, const float* __restrict__ bn_g,
                           const float* __restrict__ bn_b, float* __restrict__ scale,
                           float* __restrict__ shift)
{
    int f = threadIdx.x; // 128
    double mu = stats[f] / (double)NN;
    double var = stats[128 + f] / (double)NN - mu * mu;
    double rs = 1.0 / sqrt(var + 1e-5);
    float sc = (float)((double)bn_g[f] * rs);
    scale[f] = sc;
    shift[f] = (float)((double)bn_b[f] - mu * (double)sc);
    stats[f] = 0.0;
    stats[128 + f] = 0.0;
}

// ---------------- goff from SORTED batch: boundary detection, no atomics ----------------
__global__ void __launch_bounds__(256) k_goff2(const int* __restrict__ batch, int* __restrict__ goff)
{
    int n = blockIdx.x * 256 + threadIdx.x;
    if (n >= NN) return;
    int b = batch[n];
    if (n == 0) {
        for (int j = 0; j <= b; ++j) goff[j] = 0;
    }
    int nb = (n == NN - 1) ? NB : batch[n + 1];
    for (int j = b + 1; j <= nb; ++j) goff[j] = n + 1;
}

__global__ void __launch_bounds__(256) k_segsoftmax(const float* __restrict__ e, const int* __restrict__ goff,
                                                    float* __restrict__ w)
{
    int b = blockIdx.x;
    int beg = goff[b], end = goff[b + 1];
    int t = threadIdx.x;
    __shared__ float red[8], red2[8];
    float m = -INFINITY;
    for (int i = beg + t; i < end; i += 256) m = fmaxf(m, e[i]);
    for (int off = 32; off; off >>= 1) m = fmaxf(m, __shfl_down(m, off));
    if ((t & 63) == 0) red[t >> 6] = m;
    __syncthreads();
    float m0 = fmaxf(fmaxf(red[0], red[1]), fmaxf(red[2], red[3]));
    float s = 0.f;
    for (int i = beg + t; i < end; i += 256) s += expf(e[i] - m0);
    for (int off = 32; off; off >>= 1) s += __shfl_down(s, off);
    if ((t & 63) == 0) red2[t >> 6] = s;
    __syncthreads();
    float s0 = red2[0] + red2[1] + red2[2] + red2[3];
    for (int i = beg + t; i < end; i += 256) w[i] = expf(e[i] - m0) / s0;
}

// reconstruct x from split, scale by node weight, write fp16 (into xw region)
__global__ void __launch_bounds__(256) k_scalex16(const u16* __restrict__ xhi, const u16* __restrict__ xlo,
                                                  const float* __restrict__ w, f16* __restrict__ xf)
{
    int i8 = blockIdx.x * 256 + threadIdx.x;
    if (i8 >= NN * 16) return;
    float ww = w[i8 >> 4];
    u16x8 hh = ((const u16x8*)xhi)[i8];
    u16x8 ll = ((const u16x8*)xlo)[i8];
    f16x8 v;
#pragma unroll
    for (int j = 0; j < 8; ++j)
        v[j] = (f16)((bf2f(hh[j]) + bf2f(ll[j])) * ww);
    ((f16x8*)xf)[i8] = v;
}

// ---------------- Set2Set: fused gates + LSTM, 8 graphs per block ----------------
__device__ __forceinline__ float sigmoidf_(float v) { return 1.f / (1.f + expf(-v)); }

__global__ void __launch_bounds__(256) k_gateslstm(
    const float* __restrict__ qstar, const float* __restrict__ Wih, const float* __restrict__ Whh,
    const float* __restrict__ bih, const float* __restrict__ bhh,
    float* __restrict__ cs, float* __restrict__ hs)
{
    __shared__ float qs[8][256];
    __shared__ float hh[8][128];
    __shared__ float gs[8][512];
    int t = threadIdx.x;
    int b0 = blockIdx.x * 8;
    for (int i = t; i < 8 * 256; i += 256) qs[i >> 8][i & 255] = qstar[b0 * 256 + i];
    for (int i = t; i < 8 * 128; i += 256) hh[i >> 7][i & 127] = hs[b0 * 128 + i];
    __syncthreads();
    for (int gg = t; gg < 512; gg += 256) {
        float acc[8];
        float bb = bih[gg] + bhh[gg];
#pragma unroll
        for (int g = 0; g < 8; ++g) acc[g] = bb;
        const float4* w4 = (const float4*)(Wih + (size_t)gg * 256);
        for (int k = 0; k < 64; ++k) {
            float4 w = w4[k];
#pragma unroll
            for (int g = 0; g < 8; ++g) {
                float4 q = *(const float4*)&qs[g][k * 4];
                acc[g] += q.x * w.x + q.y * w.y + q.z * w.z + q.w * w.w;
            }
        }
        const float4* v4 = (const float4*)(Whh + (size_t)gg * 128);
        for (int k = 0; k < 32; ++k) {
            float4 w = v4[k];
#pragma unroll
            for (int g = 0; g < 8; ++g) {
                float4 q = *(const float4*)&hh[g][k * 4];
                acc[g] += q.x * w.x + q.y * w.y + q.z * w.z + q.w * w.w;
            }
        }
#pragma unroll
        for (int g = 0; g < 8; ++g) gs[g][gg] = acc[g];
    }
    __syncthreads();
    for (int i = t; i < 1024; i += 256) {
        int g = i >> 7, f = i & 127;
        int idx = (b0 + g) * 128 + f;
        float gi = gs[g][f], gf = gs[g][128 + f], gg2 = gs[g][256 + f], go = gs[g][384 + f];
        float c = sigmoidf_(gf) * cs[idx] + sigmoidf_(gi) * tanhf(gg2);
        cs[idx] = c;
        hs[idx] = sigmoidf_(go) * tanhf(c);
    }
}

// ---------------- Set2Set fused attention: en + softmax + r, one block per graph, fp16 x ----------------
__global__ void __launch_bounds__(256) k_s2s(const f16* __restrict__ x16, const float* __restrict__ hs,
                                             const int* __restrict__ goff,
                                             float* __restrict__ esc, float* __restrict__ qstar)
{
    __shared__ float q[128];
    __shared__ float red[4], red2[4];
    __shared__ float partr[3][128];
    int b = blockIdx.x, t = threadIdx.x;
    int beg = goff[b], end = goff[b + 1];
    if (t < 128) q[t] = hs[b * 128 + t];
    __syncthreads();

    int wv = t >> 6, ln = t & 63;
    // pass 1: en scores (64 lanes x 2 feats) + wave max
    float m = -INFINITY;
    for (int i = beg + wv; i < end; i += 4) {
        u32 xp = *(const u32*)(x16 + (size_t)i * H + ln * 2);
        float xl = (float)__builtin_bit_cast(f16, (u16)(xp & 0xFFFF));
        float xh = (float)__builtin_bit_cast(f16, (u16)(xp >> 16));
        float pd = xl * q[ln * 2] + xh * q[ln * 2 + 1];
        for (int off = 32; off; off >>= 1) pd += __shfl_down(pd, off);
        pd = __shfl(pd, 0);
        if (ln == 0) esc[i] = pd;
        m = fmaxf(m, pd);
    }
    if (ln == 0) red[wv] = m;
    __syncthreads();
    float m0 = fmaxf(fmaxf(red[0], red[1]), fmaxf(red[2], red[3]));
    // pass 1b: exp + sum (store unnormalized weight back to esc)
    float s = 0.f;
    for (int i = beg + t; i < end; i += 256) {
        float e = expf(esc[i] - m0);
        esc[i] = e;
        s += e;
    }
    for (int off = 32; off; off >>= 1) s += __shfl_down(s, off);
    if (ln == 0) red2[wv] = s;
    __syncthreads();
    float s0 = red2[0] + red2[1] + red2[2] + red2[3];
    float inv = (s0 > 0.f) ? 1.f / s0 : 0.f;
    // pass 2: r = sum w * x ; thread covers feat pair f2, quarter q4
    int q4 = t >> 6, f2 = (t & 63) * 2;
    float a0 = 0.f, a1 = 0.f;
    for (int i = beg + q4; i < end; i += 4) {
        float w = esc[i];
        u32 xp = *(const u32*)(x16 + (size_t)i * H + f2);
        a0 += w * (float)__builtin_bit_cast(f16, (u16)(xp & 0xFFFF));
        a1 += w * (float)__builtin_bit_cast(f16, (u16)(xp >> 16));
    }
    if (q4 > 0) { partr[q4 - 1][f2] = a0; partr[q4 - 1][f2 + 1] = a1; }
    __syncthreads();
    if (q4 == 0) {
        a0 += partr[0][f2] + partr[1][f2] + partr[2][f2];
        a1 += partr[0][f2 + 1] + partr[1][f2 + 1] + partr[2][f2 + 1];
        qstar[b * 256 + f2] = q[f2];
        qstar[b * 256 + f2 + 1] = q[f2 + 1];
        qstar[b * 256 + 128 + f2] = a0 * inv;
        qstar[b * 256 + 128 + f2 + 1] = a1 * inv;
    }
}

// ---------------- head ----------------
__global__ void __launch_bounds__(256) k_head1(const float* __restrict__ qstar, const float* __restrict__ W,
                                               const float* __restrict__ bias, float* __restrict__ y1)
{
    __shared__ float qs[256];
    int b = blockIdx.x, t = threadIdx.x;
    qs[t] = qstar[b * 256 + t];
    __syncthreads();
    float acc = bias[t];
    for (int k = 0; k < 256; ++k) acc += qs[k] * W[k * 256 + t];
    y1[b * 256 + t] = fmaxf(acc, 0.f);
}

__global__ void __launch_bounds__(256) k_head2(const float* __restrict__ y1, const float* __restrict__ W1,
                                               const float* __restrict__ b1, const float* __restrict__ W2,
                                               const float* __restrict__ b2, float* __restrict__ out)
{
    __shared__ float ys[256];
    __shared__ float z[32];
    int b = blockIdx.x, t = threadIdx.x;
    ys[t] = y1[b * 256 + t];
    __syncthreads();
    if (t < 32) {
        float acc = b1[t];
        for (int k = 0; k < 256; ++k) acc += ys[k] * W1[k * 32 + t];
        z[t] = fmaxf(acc, 0.f);
    }
    __syncthreads();
    if (t == 0) {
        float s = b2[0];
        for (int j = 0; j < 32; ++j) s += z[j] * W2[j];
        out[b] = s;
    }
}

// ---------------- launch ----------------
extern "C" void kernel_launch(void* const* d_in, const int* in_sizes, int n_in,
                              void* d_out, int out_size, void* d_ws, size_t ws_size,
                              hipStream_t stream)
{
    const float* in_x        = (const float*)d_in[0];
    const int*   edge_index  = (const int*)d_in[1];
    const float* edge_dist   = (const float*)d_in[2];
    const float* global_info = (const float*)d_in[3];
    const int*   batch       = (const int*)d_in[4];
    const float* lin_W  = (const float*)d_in[5];
    const float* lin_b  = (const float*)d_in[6];
    const float* conv_W = (const float*)d_in[7];
    const float* conv_b = (const float*)d_in[8];
    const float* bn_g   = (const float*)d_in[9];
    const float* bn_b   = (const float*)d_in[10];
    const float* gat_in_W  = (const float*)d_in[11];
    const float* gat_in_b  = (const float*)d_in[12];
    const float* gat_lin_W = (const float*)d_in[13];
    const float* gat_lin_b = (const float*)d_in[14];
    const float* gat_out_W = (const float*)d_in[15];
    const float* gat_out_b = (const float*)d_in[16];
    const float* lstm_Wih = (const float*)d_in[17];
    const float* lstm_Whh = (const float*)d_in[18];
    const float* lstm_bih = (const float*)d_in[19];
    const float* lstm_bhh = (const float*)d_in[20];
    const float* mlp_W  = (const float*)d_in[21];
    const float* mlp_b  = (const float*)d_in[22];
    const float* out1_W = (const float*)d_in[23];
    const float* out1_b = (const float*)d_in[24];
    const float* out2_W = (const float*)d_in[25];
    const float* out2_b = (const float*)d_in[26];
    float* out = (float*)d_out;

    const int* e_src = edge_index;
    const int* e_dst = edge_index + NE;

    char* p = (char*)d_ws;
    auto alloc = [&](size_t bytes) -> void* {
        void* r = (void*)p;
        p += (bytes + 255) & ~(size_t)255;
        return r;
    };
    u16*    cx_hi = (u16*)alloc((size_t)NN * H * 2);
    u16*    cx_lo = (u16*)alloc((size_t)NN * H * 2);
    float*  xw    = (float*)alloc((size_t)NN * H * 4);   // fp16 xwh (conv) / gi split (gat) / fp16 x (s2s)
    float*  agg   = (float*)alloc((size_t)NN * H * 4);   // fp16 aggh; CSR: degcnt+rank
    u16*    wthi  = (u16*)alloc((size_t)160000 * 2);
    u16*    wtlo  = (u16*)alloc((size_t)160000 * 2);
    float*  dinv  = (float*)alloc((size_t)NN * 4);
    float*  selfn = (float*)alloc((size_t)NN * 4);
    int*    cnt   = (int*)alloc((size_t)NN * 4);
    int*    rp    = (int*)alloc((size_t)(NN + 1) * 4);
    int*    bsum  = (int*)alloc(128 * 4);
    int*    boff  = (int*)alloc(128 * 4);
    u32*    ew    = (u32*)alloc((size_t)NE * 4);         // packed (w:f16<<17 | src); Set2Set aliases
    double* stats = (double*)alloc(256 * 8);
    float*  scale = (float*)alloc(128 * 4);
    float*  shift = (float*)alloc(128 * 4);

    f16*   xwh    = (f16*)xw;
    f16*   aggh   = (f16*)agg;
    u64*   degcnt = (u64*)agg;
    int*   rank   = (int*)((char*)agg + (1 << 20));
    u16*   gi_hi  = (u16*)xw;                        // gat phase: g split lives in xw region
    u16*   gi_lo  = gi_hi + (size_t)NN * H;
    float* esc    = dinv;
    float* wn     = selfn;
    int*   goff   = cnt;
    float* hs     = (float*)ew;
    float* csb    = hs + NB * H;
    float* qstar  = csb + NB * H;
    float* y1     = qstar + NB * 2 * H;

    const int GB_E = (NE + 255) / 256;
    const int GB_N = (NN + 255) / 256;
    const int NCH = (NN + 1023) / 1024;
    const int GB_MG = (NN + GBM - 1) / GBM;
    const int GB_SPMM = (NN + 31) / 32;
    const int GB_V8 = (NN * 16) / 256 + 1;

    // ---- all weight splits, one launch ----
    WJobs jobs;
    const float* Wl[9] = {lin_W, conv_W, conv_W + (size_t)H * H, conv_W + (size_t)2 * H * H,
                          conv_W + (size_t)3 * H * H, conv_W + (size_t)4 * H * H,
                          gat_in_W, gat_lin_W, gat_lin_W + (size_t)H * H};
    int Ks[9]  = {DIN, H, H, H, H, H, H + DGI, H, H};
    int Kps[9] = {96, H, H, H, H, H, 256, H, H};
    long long eoffs[9];
    long long eo = 0;
    for (int i = 0; i < 9; ++i) {
        jobs.W[i] = Wl[i]; jobs.K[i] = Ks[i]; jobs.Kpad[i] = Kps[i]; jobs.eoff[i] = eo;
        eoffs[i] = eo;
        eo += (long long)128 * Kps[i];
    }
    k_splitW_all<<<dim3(128, 2, 9), 128, 0, stream>>>(jobs, wthi, wtlo);

    // ---- graph norm + CSR ----
    hipMemsetAsync(degcnt, 0, (size_t)NN * 8, stream);
    hipMemsetAsync(stats, 0, 256 * 8, stream);
    k_deg2<<<GB_E, 256, 0, stream>>>(e_dst, edge_dist, degcnt, rank);
    k_dinv2<<<GB_N, 256, 0, stream>>>(degcnt, dinv, selfn, cnt);
    k_blocksum<<<NCH, 256, 0, stream>>>(cnt, bsum, NN);
    k_scanbsum<<<1, 64, 0, stream>>>(bsum, boff, NCH, rp + NN, NE);
    k_scanchunk<<<NCH, 1024, 0, stream>>>(cnt, boff, rp, NN);
    k_place2<<<GB_E, 256, 0, stream>>>(e_src, e_dst, edge_dist, dinv, rp, rank, ew);

    // ---- input projection: A staged directly from fp32 in_x (on-the-fly split) ----
    k_mgemm<1, 1, 96, 2><<<GB_MG, 256, 0, stream>>>(nullptr, nullptr, H, 96, nullptr, nullptr, H,
                                                    wthi + eoffs[0], wtlo + eoffs[0], lin_b,
                                                    nullptr, cx_hi, cx_lo, H, nullptr,
                                                    nullptr, nullptr, nullptr,
                                                    nullptr, nullptr, nullptr, nullptr, nullptr,
                                                    in_x, DIN, NN);

    // ---- conv stack (bnres of layer l-1 fused into A-staging of mgemm l) ----
    for (int l = 0; l < NL; ++l) {
        if (l == 0) {
            k_mgemm<0, 2, 128, 0><<<GB_MG, 256, 0, stream>>>(cx_hi, cx_lo, H, H, cx_hi, cx_lo, H,
                                                             wthi + eoffs[1 + l], wtlo + eoffs[1 + l], nullptr,
                                                             nullptr, nullptr, nullptr, 0, xwh,
                                                             nullptr, nullptr, nullptr,
                                                             nullptr, nullptr, nullptr, nullptr, nullptr,
                                                             nullptr, 0, NN);
        } else {
            k_mgemm<0, 2, 128, 1><<<GB_MG, 256, 0, stream>>>(cx_hi, cx_lo, H, H, cx_hi, cx_lo, H,
                                                             wthi + eoffs[1 + l], wtlo + eoffs[1 + l], nullptr,
                                                             nullptr, nullptr, nullptr, 0, xwh,
                                                             nullptr, nullptr, nullptr,
                                                             aggh, scale, shift, cx_hi, cx_lo,
                                                             nullptr, 0, NN);
        }
        k_spmm<<<GB_SPMM, 256, 0, stream>>>(xwh, rp, ew, selfn, conv_b + (size_t)l * H, aggh, stats);
        k_finalize<<<1, 128, 0, stream>>>(stats, bn_g, bn_b, scale, shift);
    }

    // ---- global attention ----
    // gat1: A1 = bnres-fused cx; A2 staged directly from fp32 global_info
    k_mgemm<1, 1, 256, 3><<<GB_MG, 256, 0, stream>>>(cx_hi, cx_lo, H, H, nullptr, nullptr, H,
                                                     wthi + eoffs[6], wtlo + eoffs[6], gat_in_b,
                                                     nullptr, gi_hi, gi_lo, H, nullptr,
                                                     nullptr, nullptr, nullptr,
                                                     aggh, scale, shift, cx_hi, cx_lo,
                                                     global_info, DGI, NN);
    k_mgemm<1, 1, 128, 0><<<GB_MG, 256, 0, stream>>>(gi_hi, gi_lo, H, H, gi_hi, gi_lo, H,
                                                     wthi + eoffs[7], wtlo + eoffs[7], gat_lin_b,
                                                     nullptr, gi_hi, gi_lo, H, nullptr,
                                                     nullptr, nullptr, nullptr,
                                                     nullptr, nullptr, nullptr, nullptr, nullptr,
                                                     nullptr, 0, NN);
    k_mgemm<1, 3, 128, 0><<<GB_MG, 256, 0, stream>>>(gi_hi, gi_lo, H, H, gi_hi, gi_lo, H,
                                                     wthi + eoffs[8], wtlo + eoffs[8], gat_lin_b + H,
                                                     nullptr, nullptr, nullptr, 0, nullptr,
                                                     gat_out_W, gat_out_b, esc,
                                                     nullptr, nullptr, nullptr, nullptr, nullptr,
                                                     nullptr, 0, NN);
    k_goff2<<<GB_N, 256, 0, stream>>>(batch, goff);
    k_segsoftmax<<<NB, 256, 0, stream>>>(esc, goff, wn);
    k_scalex16<<<GB_V8, 256, 0, stream>>>(cx_hi, cx_lo, wn, (f16*)xw);  // gi region dead after gat3

    // ---- Set2Set (hs/csb/qstar alias ew region, dead after conv stack) ----
    hipMemsetAsync(hs, 0, (size_t)NB * H * 4, stream);
    hipMemsetAsync(csb, 0, (size_t)NB * H * 4, stream);
    hipMemsetAsync(qstar, 0, (size_t)NB * 2 * H * 4, stream);
    for (int it = 0; it < 3; ++it) {
        k_gateslstm<<<NB / 8, 256, 0, stream>>>(qstar, lstm_Wih, lstm_Whh, lstm_bih, lstm_bhh, csb, hs);
        k_s2s<<<NB, 256, 0, stream>>>((const f16*)xw, hs, goff, esc, qstar);
    }

    // ---- head ----
    k_head1<<<NB, 256, 0, stream>>>(qstar, mlp_W, mlp_b, y1);
    k_head2<<<NB, 256, 0, stream>>>(y1, out1_W, out1_b, out2_W, out2_b, out);
}

// Round 13
// 1357.249 us; speedup vs baseline: 1.2907x; 1.0161x over previous
//
#include <hip/hip_runtime.h>
#include <math.h>

#define NN 100000
#define NE 1600000
#define DIN 92
#define H 128
#define NB 512
#define DGI 107
#define NL 5

typedef unsigned short u16;
typedef unsigned int u32;
typedef unsigned long long u64;
typedef short bf16x8 __attribute__((ext_vector_type(8)));
typedef float f32x4 __attribute__((ext_vector_type(4)));
typedef _Float16 f16;
typedef _Float16 f16x8 __attribute__((ext_vector_type(8)));
typedef unsigned short u16x8 __attribute__((ext_vector_type(8)));

__device__ __forceinline__ u16 f2bf(float f) {
    unsigned u = __builtin_bit_cast(unsigned, f);
    u += 0x7FFF + ((u >> 16) & 1);
    return (u16)(u >> 16);
}
__device__ __forceinline__ float bf2f(u16 h) {
    unsigned u = ((unsigned)h) << 16;
    return __builtin_bit_cast(float, u);
}

// ---------------- all weight splits in ONE launch ----------------
struct WJobs {
    const float* W[9];
    long long eoff[9];
    int K[9];
    int Kpad[9];
};

__global__ void __launch_bounds__(128) k_splitW_all(WJobs jobs, u16* __restrict__ wthi, u16* __restrict__ wtlo)
{
    int j = blockIdx.z;
    int c = blockIdx.x;
    int k = blockIdx.y * 128 + threadIdx.x;
    int Kp = jobs.Kpad[j];
    if (k >= Kp) return;
    const float* W = jobs.W[j];
    float v = (k < jobs.K[j]) ? W[(size_t)k * H + c] : 0.f;
    u16 h = f2bf(v);
    float r = v - bf2f(h);
    size_t o = (size_t)jobs.eoff[j] + (size_t)c * Kp + k;
    wthi[o] = h;
    wtlo[o] = f2bf(r);
}

// ---------------- MFMA GEMM: C[M,128] = act([A1|A2]@W + b), bf16x3 compensated ----------------
// OMODE: 0=f32, 1=bf16 split, 2=fp16 row-major, 3=fused escore, 4=bf16 hi-only. KPAD compile-time.
// AMODE: 0=plain; 1=A1 bnres-fused (cx+agg, write-back); 2=A1 from fp32 Fsrc; 3=A1 bnres + A2 from Fsrc
// ALO: 1=use A lo plane (3 MFMA); 0=A hi only (2 MFMA, no lo load)
#define GBM 128

template<int RELU, int OMODE, int KPAD, int AMODE, int ALO>
__global__ void __launch_bounds__(256) k_mgemm(
    const u16* __restrict__ A1hi, const u16* __restrict__ A1lo, int lda1, int K1,
    const u16* __restrict__ A2hi, const u16* __restrict__ A2lo, int lda2,
    const u16* __restrict__ Wthi, const u16* __restrict__ Wtlo,
    const float* __restrict__ bias,
    float* __restrict__ Cf, u16* __restrict__ Chi, u16* __restrict__ Clo, int ldsp,
    f16* __restrict__ Ch,
    const float* __restrict__ Gow, const float* __restrict__ GobP, float* __restrict__ Esc,
    const f16* __restrict__ Agg, const float* __restrict__ Sc, const float* __restrict__ Sh,
    u16* __restrict__ WBhi, u16* __restrict__ WBlo,
    const float* __restrict__ Fsrc, int FW,
    int M)
{
    __shared__ __align__(16) u16 As[2][128][40];
    __shared__ __align__(16) u16 Ws[2][128][40];
    int tid = threadIdx.x;
    int w = tid >> 6, l = tid & 63;
    int row0 = blockIdx.x * GBM;
    int lr = l & 15, kq = l >> 4;

    f32x4 acc[2][8];
#pragma unroll
    for (int rf = 0; rf < 2; ++rf)
#pragma unroll
        for (int cf = 0; cf < 8; ++cf)
            acc[rf][cf] = (f32x4){0.f, 0.f, 0.f, 0.f};

#pragma unroll
    for (int k0 = 0; k0 < KPAD; k0 += 32) {
        const u16* sAh = (k0 < K1) ? A1hi : A2hi;
        const u16* sAl = (k0 < K1) ? A1lo : A2lo;
        int ldc = (k0 < K1) ? lda1 : lda2;
        int kc = (k0 < K1) ? k0 : (k0 - K1);
#pragma unroll
        for (int i = 0; i < 2; ++i) {
            int chunk = tid + i * 256;
            int r = chunk >> 2, q = chunk & 3;
            int gr = row0 + r; if (gr >= M) gr = M - 1;
            int col0 = kc + q * 8;
            int4 va, vb;
            vb = (int4){0, 0, 0, 0};
            bool fsplit = (AMODE == 2 && k0 < K1) || (AMODE == 3 && k0 >= K1);
            if (fsplit) {
                u16x8 hh, ll;
#pragma unroll
                for (int j = 0; j < 8; ++j) {
                    int c = col0 + j;
                    float v = (c < FW) ? Fsrc[(size_t)gr * FW + c] : 0.f;
                    u16 h = f2bf(v);
                    hh[j] = h;
                    ll[j] = f2bf(v - bf2f(h));
                }
                va = __builtin_bit_cast(int4, hh);
                vb = __builtin_bit_cast(int4, ll);
            } else {
                va = *(const int4*)(sAh + (size_t)gr * ldc + col0);
                if (ALO) vb = *(const int4*)(sAl + (size_t)gr * ldc + col0);
                if ((AMODE == 1 || AMODE == 3) && k0 < K1) {
                    f16x8 av = *(const f16x8*)(Agg + (size_t)gr * H + col0);
                    u16x8 hh = __builtin_bit_cast(u16x8, va);
                    u16x8 ll = __builtin_bit_cast(u16x8, vb);
                    float4 sc0 = *(const float4*)(Sc + col0);
                    float4 sc1 = *(const float4*)(Sc + col0 + 4);
                    float4 sh0 = *(const float4*)(Sh + col0);
                    float4 sh1 = *(const float4*)(Sh + col0 + 4);
                    float scv[8] = {sc0.x, sc0.y, sc0.z, sc0.w, sc1.x, sc1.y, sc1.z, sc1.w};
                    float shv[8] = {sh0.x, sh0.y, sh0.z, sh0.w, sh1.x, sh1.y, sh1.z, sh1.w};
#pragma unroll
                    for (int j = 0; j < 8; ++j) {
                        float v = bf2f(hh[j]) + bf2f(ll[j]) + (float)av[j] * scv[j] + shv[j];
                        u16 h = f2bf(v);
                        hh[j] = h;
                        ll[j] = f2bf(v - bf2f(h));
                    }
                    va = __builtin_bit_cast(int4, hh);
                    vb = __builtin_bit_cast(int4, ll);
                    *(int4*)(WBhi + (size_t)gr * lda1 + col0) = va;
                    *(int4*)(WBlo + (size_t)gr * lda1 + col0) = vb;
                }
            }
            int4 wa = *(const int4*)(Wthi + (size_t)r * KPAD + k0 + q * 8);
            int4 wb = *(const int4*)(Wtlo + (size_t)r * KPAD + k0 + q * 8);
            *(int4*)&As[0][r][q * 8] = va;
            if (ALO) *(int4*)&As[1][r][q * 8] = vb;
            *(int4*)&Ws[0][r][q * 8] = wa;
            *(int4*)&Ws[1][r][q * 8] = wb;
        }
        __syncthreads();

        bf16x8 aH[2], aL[2];
#pragma unroll
        for (int rf = 0; rf < 2; ++rf) {
            aH[rf] = *(const bf16x8*)&As[0][w * 32 + rf * 16 + lr][kq * 8];
            if (ALO) aL[rf] = *(const bf16x8*)&As[1][w * 32 + rf * 16 + lr][kq * 8];
        }
#pragma unroll
        for (int cf = 0; cf < 8; ++cf) {
            bf16x8 bH = *(const bf16x8*)&Ws[0][cf * 16 + lr][kq * 8];
            bf16x8 bL = *(const bf16x8*)&Ws[1][cf * 16 + lr][kq * 8];
#pragma unroll
            for (int rf = 0; rf < 2; ++rf) {
                acc[rf][cf] = __builtin_amdgcn_mfma_f32_16x16x32_bf16(aH[rf], bH, acc[rf][cf], 0, 0, 0);
                acc[rf][cf] = __builtin_amdgcn_mfma_f32_16x16x32_bf16(aH[rf], bL, acc[rf][cf], 0, 0, 0);
                if (ALO)
                    acc[rf][cf] = __builtin_amdgcn_mfma_f32_16x16x32_bf16(aL[rf], bH, acc[rf][cf], 0, 0, 0);
            }
        }
        __syncthreads();
    }

    if (OMODE == 3) {
        float gowv[8], bvv[8];
#pragma unroll
        for (int cf = 0; cf < 8; ++cf) {
            gowv[cf] = Gow[cf * 16 + lr];
            bvv[cf] = bias[cf * 16 + lr];
        }
        float gob0 = GobP[0];
#pragma unroll
        for (int rf = 0; rf < 2; ++rf) {
#pragma unroll
            for (int r = 0; r < 4; ++r) {
                float part = 0.f;
#pragma unroll
                for (int cf = 0; cf < 8; ++cf) {
                    float v = fmaxf(acc[rf][cf][r] + bvv[cf], 0.f);
                    part += v * gowv[cf];
                }
                part += __shfl_xor(part, 1);
                part += __shfl_xor(part, 2);
                part += __shfl_xor(part, 4);
                part += __shfl_xor(part, 8);
                int grow = row0 + w * 32 + rf * 16 + kq * 4 + r;
                if (lr == 0 && grow < M) Esc[grow] = part + gob0;
            }
        }
        return;
    }

#pragma unroll
    for (int cf = 0; cf < 8; ++cf) {
        int col = cf * 16 + lr;
        float bv = bias ? bias[col] : 0.f;
#pragma unroll
        for (int rf = 0; rf < 2; ++rf) {
#pragma unroll
            for (int r = 0; r < 4; ++r) {
                int grow = row0 + w * 32 + rf * 16 + kq * 4 + r;
                if (grow < M) {
                    float v = acc[rf][cf][r] + bv;
                    if (RELU) v = fmaxf(v, 0.f);
                    if (OMODE == 0) Cf[(size_t)grow * H + col] = v;
                    if (OMODE == 1) {
                        u16 hh = f2bf(v);
                        Chi[(size_t)grow * ldsp + col] = hh;
                        Clo[(size_t)grow * ldsp + col] = f2bf(v - bf2f(hh));
                    }
                    if (OMODE == 2) Ch[(size_t)grow * H + col] = (f16)v;
                    if (OMODE == 4) Chi[(size_t)grow * ldsp + col] = f2bf(v);
                }
            }
        }
    }
}

// ---------------- degree + counts: one packed 64-bit atomic per edge ----------------
__global__ void __launch_bounds__(256) k_deg2(const int* __restrict__ dst, const float* __restrict__ ed,
                                              u64* __restrict__ degcnt, int* __restrict__ rank)
{
    int e = blockIdx.x * 256 + threadIdx.x;
    if (e < NE) {
        int d = dst[e];
        u64 pk = ((u64)1 << 40) | (u64)(ed[e] * 16777216.0f);
        u64 old = atomicAdd(&degcnt[d], pk);
        rank[e] = (int)(old >> 40);
    }
}

__global__ void __launch_bounds__(256) k_dinv2(const u64* __restrict__ degcnt,
                                               float* __restrict__ dinv, float* __restrict__ selfn,
                                               int* __restrict__ cnt)
{
    int n = blockIdx.x * 256 + threadIdx.x;
    if (n < NN) {
        u64 v = degcnt[n];
        int c = (int)(v >> 40);
        float deg = (float)((double)(v & (((u64)1 << 40) - 1)) * (1.0 / 16777216.0));
        float d = deg + 2.0f;
        float dv = 1.0f / sqrtf(d);
        dinv[n] = dv;
        selfn[n] = 2.0f * dv * dv;
        cnt[n] = c;
    }
}

// ---------------- CSR build ----------------
__global__ void __launch_bounds__(256) k_blocksum(const int* __restrict__ cnt, int* __restrict__ bsum, int n)
{
    __shared__ int red[256];
    int t = threadIdx.x;
    int base = blockIdx.x * 1024;
    int s = 0;
#pragma unroll
    for (int j = 0; j < 4; ++j) {
        int i = base + j * 256 + t;
        if (i < n) s += cnt[i];
    }
    red[t] = s; __syncthreads();
    for (int off = 128; off; off >>= 1) {
        if (t < off) red[t] += red[t + off];
        __syncthreads();
    }
    if (t == 0) bsum[blockIdx.x] = red[0];
}

__global__ void k_scanbsum(const int* __restrict__ bsum, int* __restrict__ boff, int nb,
                           int* __restrict__ rp_last, int total)
{
    if (threadIdx.x == 0 && blockIdx.x == 0) {
        int s = 0;
        for (int i = 0; i < nb; ++i) { boff[i] = s; s += bsum[i]; }
        rp_last[0] = total;
    }
}

__global__ void __launch_bounds__(1024) k_scanchunk(const int* __restrict__ cnt, const int* __restrict__ boff,
                                                    int* __restrict__ rp, int n)
{
    __shared__ int sc[1024];
    int t = threadIdx.x;
    int i = blockIdx.x * 1024 + t;
    int own = (i < n) ? cnt[i] : 0;
    sc[t] = own;
    __syncthreads();
    for (int off = 1; off < 1024; off <<= 1) {
        int v = (t >= off) ? sc[t - off] : 0;
        __syncthreads();
        sc[t] += v;
        __syncthreads();
    }
    if (i < n) rp[i] = boff[blockIdx.x] + sc[t] - own;
}

// placement: NO atomics; packed u32 = (f16 w bits [15] << 17) | src (<2^17)
__global__ void __launch_bounds__(256) k_place2(const int* __restrict__ src, const int* __restrict__ dst,
                                                const float* __restrict__ ed, const float* __restrict__ dinv,
                                                const int* __restrict__ rp, const int* __restrict__ rank,
                                                u32* __restrict__ ew)
{
    int e = blockIdx.x * 256 + threadIdx.x;
    if (e < NE) {
        int d = dst[e], s = src[e];
        int pos = rp[d] + rank[e];
        float w = dinv[s] * ed[e] * dinv[d];
        f16 wh = (f16)w;
        u32 wb = (u32)__builtin_bit_cast(u16, wh);
        ew[pos] = (wb << 17) | (u32)s;
    }
}

// ---------------- SpMM (fp16 row-major gather, u32 packed edges) ----------------
__global__ void __launch_bounds__(256) k_spmm(
    const f16* __restrict__ xwh, const int* __restrict__ rp,
    const u32* __restrict__ ew,
    const float* __restrict__ selfn, const float* __restrict__ cb,
    f16* __restrict__ aggh, double* __restrict__ stats)
{
    int tid = threadIdx.x;
    int slot = tid >> 4;          // 0..15
    int sl = tid & 15;
    int f0 = sl * 8;
    float cbv[8], psum[8], psq[8];
#pragma unroll
    for (int j = 0; j < 8; ++j) { cbv[j] = cb[f0 + j]; psum[j] = 0.f; psq[j] = 0.f; }
    int base = blockIdx.x * 32 + slot * 2;

    for (int i = 0; i < 2; ++i) {
        int n = base + i;
        if (n >= NN) break;
        f16x8 xv = *(const f16x8*)(xwh + (size_t)n * H + f0);
        float sn = selfn[n];
        float a0[8], a1[8], a2[8], a3[8];
#pragma unroll
        for (int j = 0; j < 8; ++j) {
            a0[j] = sn * (float)xv[j] + cbv[j];
            a1[j] = 0.f; a2[j] = 0.f; a3[j] = 0.f;
        }
        int e = rp[n], end = rp[n + 1];
        for (; e + 4 <= end; e += 4) {
            u32 p0 = ew[e], p1 = ew[e + 1], p2 = ew[e + 2], p3 = ew[e + 3];
            float w0 = (float)__builtin_bit_cast(f16, (u16)(p0 >> 17));
            float w1 = (float)__builtin_bit_cast(f16, (u16)(p1 >> 17));
            float w2 = (float)__builtin_bit_cast(f16, (u16)(p2 >> 17));
            float w3 = (float)__builtin_bit_cast(f16, (u16)(p3 >> 17));
            f16x8 v0 = *(const f16x8*)(xwh + (size_t)(p0 & 0x1FFFF) * H + f0);
            f16x8 v1 = *(const f16x8*)(xwh + (size_t)(p1 & 0x1FFFF) * H + f0);
            f16x8 v2 = *(const f16x8*)(xwh + (size_t)(p2 & 0x1FFFF) * H + f0);
            f16x8 v3 = *(const f16x8*)(xwh + (size_t)(p3 & 0x1FFFF) * H + f0);
#pragma unroll
            for (int j = 0; j < 8; ++j) {
                a0[j] += w0 * (float)v0[j];
                a1[j] += w1 * (float)v1[j];
                a2[j] += w2 * (float)v2[j];
                a3[j] += w3 * (float)v3[j];
            }
        }
        for (; e < end; ++e) {
            u32 p = ew[e];
            float w0 = (float)__builtin_bit_cast(f16, (u16)(p >> 17));
            f16x8 v0 = *(const f16x8*)(xwh + (size_t)(p & 0x1FFFF) * H + f0);
#pragma unroll
            for (int j = 0; j < 8; ++j) a0[j] += w0 * (float)v0[j];
        }
        float ax[8];
        f16x8 ah;
#pragma unroll
        for (int j = 0; j < 8; ++j) {
            ax[j] = (a0[j] + a1[j]) + (a2[j] + a3[j]);
            psum[j] += ax[j];
            psq[j] += ax[j] * ax[j];
            ah[j] = (f16)ax[j];
        }
        __builtin_nontemporal_store(ah, (f16x8*)(aggh + (size_t)n * H + f0));
    }

    __shared__ float ssum[16][128], ssq[16][128];
#pragma unroll
    for (int j = 0; j < 8; ++j) { ssum[slot][f0 + j] = psum[j]; ssq[slot][f0 + j] = psq[j]; }
    __syncthreads();
    if (tid < 128) {
        float s = 0.f, q = 0.f;
#pragma unroll
        for (int j = 0; j < 16; ++j) { s += ssum[j][tid]; q += ssq[j][tid]; }
        atomicAdd(&stats[tid], (double)s);
        atomicAdd(&stats[128 + tid], (double)q);
    }
}

// finalize BN scale/shift; self-zero stats for next layer
__global__ void k_finalize(double* __restrict__ stats, const float* __restrict__ bn_g,
                           const float* __restrict__ bn_b, float* __restrict__ scale,
                           float* __restrict__ shift)
{
    int f = threadIdx.x; // 128
    double mu = stats[f] / (double)NN;
    double var = stats[128 + f] / (double)NN - mu * mu;
    double rs = 1.0 / sqrt(var + 1e-5);
    float sc = (float)((double)bn_g[f] * rs);
    scale[f] = sc;
    shift[f] = (float)((double)bn_b[f] - mu * (double)sc);
    stats[f] = 0.0;
    stats[128 + f] = 0.0;
}

// ---------------- goff from SORTED batch: boundary detection, no atomics ----------------
__global__ void __launch_bounds__(256) k_goff2(const int* __restrict__ batch, int* __restrict__ goff)
{
    int n = blockIdx.x * 256 + threadIdx.x;
    if (n >= NN) return;
    int b = batch[n];
    if (n == 0) {
        for (int j = 0; j <= b; ++j) goff[j] = 0;
    }
    int nb = (n == NN - 1) ? NB : batch[n + 1];
    for (int j = b + 1; j <= nb; ++j) goff[j] = n + 1;
}

// ---------------- fused segment softmax + x scale (block per graph) ----------------
__global__ void __launch_bounds__(256) k_ssmx(float* __restrict__ esc, const int* __restrict__ goff,
                                              const u16* __restrict__ xhi, const u16* __restrict__ xlo,
                                              f16* __restrict__ x16)
{
    int b = blockIdx.x, t = threadIdx.x;
    int beg = goff[b], end = goff[b + 1];
    __shared__ float red[4], red2[4];
    int wv = t >> 6, ln = t & 63;
    float m = -INFINITY;
    for (int i = beg + t; i < end; i += 256) m = fmaxf(m, esc[i]);
    for (int off = 32; off; off >>= 1) m = fmaxf(m, __shfl_down(m, off));
    if (ln == 0) red[wv] = m;
    __syncthreads();
    float m0 = fmaxf(fmaxf(red[0], red[1]), fmaxf(red[2], red[3]));
    float s = 0.f;
    for (int i = beg + t; i < end; i += 256) {
        float e = expf(esc[i] - m0);
        esc[i] = e;
        s += e;
    }
    for (int off = 32; off; off >>= 1) s += __shfl_down(s, off);
    if (ln == 0) red2[wv] = s;
    __syncthreads();
    float s0 = red2[0] + red2[1] + red2[2] + red2[3];
    float inv = (s0 > 0.f) ? 1.f / s0 : 0.f;
    // scale rows: slot = node, lane = 8 feats
    int slot = t >> 4, sl = t & 15, f0 = sl * 8;
    for (int i = beg + slot; i < end; i += 16) {
        float w = esc[i] * inv;
        u16x8 hh = *(const u16x8*)(xhi + (size_t)i * H + f0);
        u16x8 ll = *(const u16x8*)(xlo + (size_t)i * H + f0);
        f16x8 v;
#pragma unroll
        for (int j = 0; j < 8; ++j)
            v[j] = (f16)((bf2f(hh[j]) + bf2f(ll[j])) * w);
        *(f16x8*)(x16 + (size_t)i * H + f0) = v;
    }
}

// ---------------- Set2Set: fused gates + LSTM, 8 graphs per block ----------------
__device__ __forceinline__ float sigmoidf_(float v) { return 1.f / (1.f + expf(-v)); }

__global__ void __launch_bounds__(256) k_gateslstm(
    const float* __restrict__ qstar, const float* __restrict__ Wih, const float* __restrict__ Whh,
    const float* __restrict__ bih, const float* __restrict__ bhh,
    float* __restrict__ cs, float* __restrict__ hs)
{
    __shared__ float qs[8][256];
    __shared__ float hh[8][128];
    __shared__ float gs[8][512];
    int t = threadIdx.x;
    int b0 = blockIdx.x * 8;
    for (int i = t; i < 8 * 256; i += 256) qs[i >> 8][i & 255] = qstar[b0 * 256 + i];
    for (int i = t; i < 8 * 128; i += 256) hh[i >> 7][i & 127] = hs[b0 * 128 + i];
    __syncthreads();
    for (int gg = t; gg < 512; gg += 256) {
        float acc[8];
        float bb = bih[gg] + bhh[gg];
#pragma unroll
        for (int g = 0; g < 8; ++g) acc[g] = bb;
        const float4* w4 = (const float4*)(Wih + (size_t)gg * 256);
        for (int k = 0; k < 64; ++k) {
            float4 w = w4[k];
#pragma unroll
            for (int g = 0; g < 8; ++g) {
                float4 q = *(const float4*)&qs[g][k * 4];
                acc[g] += q.x * w.x + q.y * w.y + q.z * w.z + q.w * w.w;
            }
        }
        const float4* v4 = (const float4*)(Whh + (size_t)gg * 128);
        for (int k = 0; k < 32; ++k) {
            float4 w = v4[k];
#pragma unroll
            for (int g = 0; g < 8; ++g) {
                float4 q = *(const float4*)&hh[g][k * 4];
                acc[g] += q.x * w.x + q.y * w.y + q.z * w.z + q.w * w.w;
            }
        }
#pragma unroll
        for (int g = 0; g < 8; ++g) gs[g][gg] = acc[g];
    }
    __syncthreads();
    for (int i = t; i < 1024; i += 256) {
        int g = i >> 7, f = i & 127;
        int idx = (b0 + g) * 128 + f;
        float gi = gs[g][f], gf = gs[g][128 + f], gg2 = gs[g][256 + f], go = gs[g][384 + f];
        float c = sigmoidf_(gf) * cs[idx] + sigmoidf_(gi) * tanhf(gg2);
        cs[idx] = c;
        hs[idx] = sigmoidf_(go) * tanhf(c);
    }
}

// ---------------- Set2Set fused attention: en + softmax + r, one block per graph, fp16 x ----------------
__global__ void __launch_bounds__(256) k_s2s(const f16* __restrict__ x16, const float* __restrict__ hs,
                                             const int* __restrict__ goff,
                                             float* __restrict__ esc, float* __restrict__ qstar)
{
    __shared__ float q[128];
    __shared__ float red[4], red2[4];
    __shared__ float partr[3][128];
    int b = blockIdx.x, t = threadIdx.x;
    int beg = goff[b], end = goff[b + 1];
    if (t < 128) q[t] = hs[b * 128 + t];
    __syncthreads();

    int wv = t >> 6, ln = t & 63;
    float m = -INFINITY;
    for (int i = beg + wv; i < end; i += 4) {
        u32 xp = *(const u32*)(x16 + (size_t)i * H + ln * 2);
        float xl = (float)__builtin_bit_cast(f16, (u16)(xp & 0xFFFF));
        float xh = (float)__builtin_bit_cast(f16, (u16)(xp >> 16));
        float pd = xl * q[ln * 2] + xh * q[ln * 2 + 1];
        for (int off = 32; off; off >>= 1) pd += __shfl_down(pd, off);
        pd = __shfl(pd, 0);
        if (ln == 0) esc[i] = pd;
        m = fmaxf(m, pd);
    }
    if (ln == 0) red[wv] = m;
    __syncthreads();
    float m0 = fmaxf(fmaxf(red[0], red[1]), fmaxf(red[2], red[3]));
    float s = 0.f;
    for (int i = beg + t; i < end; i += 256) {
        float e = expf(esc[i] - m0);
        esc[i] = e;
        s += e;
    }
    for (int off = 32; off; off >>= 1) s += __shfl_down(s, off);
    if (ln == 0) red2[wv] = s;
    __syncthreads();
    float s0 = red2[0] + red2[1] + red2[2] + red2[3];
    float inv = (s0 > 0.f) ? 1.f / s0 : 0.f;
    int q4 = t >> 6, f2 = (t & 63) * 2;
    float a0 = 0.f, a1 = 0.f;
    for (int i = beg + q4; i < end; i += 4) {
        float w = esc[i];
        u32 xp = *(const u32*)(x16 + (size_t)i * H + f2);
        a0 += w * (float)__builtin_bit_cast(f16, (u16)(xp & 0xFFFF));
        a1 += w * (float)__builtin_bit_cast(f16, (u16)(xp >> 16));
    }
    if (q4 > 0) { partr[q4 - 1][f2] = a0; partr[q4 - 1][f2 + 1] = a1; }
    __syncthreads();
    if (q4 == 0) {
        a0 += partr[0][f2] + partr[1][f2] + partr[2][f2];
        a1 += partr[0][f2 + 1] + partr[1][f2 + 1] + partr[2][f2 + 1];
        qstar[b * 256 + f2] = q[f2];
        qstar[b * 256 + f2 + 1] = q[f2 + 1];
        qstar[b * 256 + 128 + f2] = a0 * inv;
        qstar[b * 256 + 128 + f2 + 1] = a1 * inv;
    }
}

// ---------------- head ----------------
__global__ void __launch_bounds__(256) k_head1(const float* __restrict__ qstar, const float* __restrict__ W,
                                               const float* __restrict__ bias, float* __restrict__ y1)
{
    __shared__ float qs[256];
    int b = blockIdx.x, t = threadIdx.x;
    qs[t] = qstar[b * 256 + t];
    __syncthreads();
    float acc = bias[t];
    for (int k = 0; k < 256; ++k) acc += qs[k] * W[k * 256 + t];
    y1[b * 256 + t] = fmaxf(acc, 0.f);
}

__global__ void __launch_bounds__(256) k_head2(const float* __restrict__ y1, const float* __restrict__ W1,
                                               const float* __restrict__ b1, const float* __restrict__ W2,
                                               const float* __restrict__ b2, float* __restrict__ out)
{
    __shared__ float ys[256];
    __shared__ float z[32];
    int b = blockIdx.x, t = threadIdx.x;
    ys[t] = y1[b * 256 + t];
    __syncthreads();
    if (t < 32) {
        float acc = b1[t];
        for (int k = 0; k < 256; ++k) acc += ys[k] * W1[k * 32 + t];
        z[t] = fmaxf(acc, 0.f);
    }
    __syncthreads();
    if (t == 0) {
        float s = b2[0];
        for (int j = 0; j < 32; ++j) s += z[j] * W2[j];
        out[b] = s;
    }
}

// ---------------- launch ----------------
extern "C" void kernel_launch(void* const* d_in, const int* in_sizes, int n_in,
                              void* d_out, int out_size, void* d_ws, size_t ws_size,
                              hipStream_t stream)
{
    const float* in_x        = (const float*)d_in[0];
    const int*   edge_index  = (const int*)d_in[1];
    const float* edge_dist   = (const float*)d_in[2];
    const float* global_info = (const float*)d_in[3];
    const int*   batch       = (const int*)d_in[4];
    const float* lin_W  = (const float*)d_in[5];
    const float* lin_b  = (const float*)d_in[6];
    const float* conv_W = (const float*)d_in[7];
    const float* conv_b = (const float*)d_in[8];
    const float* bn_g   = (const float*)d_in[9];
    const float* bn_b   = (const float*)d_in[10];
    const float* gat_in_W  = (const float*)d_in[11];
    const float* gat_in_b  = (const float*)d_in[12];
    const float* gat_lin_W = (const float*)d_in[13];
    const float* gat_lin_b = (const float*)d_in[14];
    const float* gat_out_W = (const float*)d_in[15];
    const float* gat_out_b = (const float*)d_in[16];
    const float* lstm_Wih = (const float*)d_in[17];
    const float* lstm_Whh = (const float*)d_in[18];
    const float* lstm_bih = (const float*)d_in[19];
    const float* lstm_bhh = (const float*)d_in[20];
    const float* mlp_W  = (const float*)d_in[21];
    const float* mlp_b  = (const float*)d_in[22];
    const float* out1_W = (const float*)d_in[23];
    const float* out1_b = (const float*)d_in[24];
    const float* out2_W = (const float*)d_in[25];
    const float* out2_b = (const float*)d_in[26];
    float* out = (float*)d_out;

    const int* e_src = edge_index;
    const int* e_dst = edge_index + NE;

    char* p = (char*)d_ws;
    auto alloc = [&](size_t bytes) -> void* {
        void* r = (void*)p;
        p += (bytes + 255) & ~(size_t)255;
        return r;
    };
    u16*    cx_hi = (u16*)alloc((size_t)NN * H * 2);
    u16*    cx_lo = (u16*)alloc((size_t)NN * H * 2);
    float*  xw    = (float*)alloc((size_t)NN * H * 4);   // fp16 xwh (conv) / gi hi (gat) / fp16 x (s2s)
    float*  agg   = (float*)alloc((size_t)NN * H * 4);   // fp16 aggh; CSR: degcnt+rank
    u16*    wthi  = (u16*)alloc((size_t)160000 * 2);
    u16*    wtlo  = (u16*)alloc((size_t)160000 * 2);
    float*  dinv  = (float*)alloc((size_t)NN * 4);
    float*  selfn = (float*)alloc((size_t)NN * 4);
    int*    cnt   = (int*)alloc((size_t)NN * 4);
    int*    rp    = (int*)alloc((size_t)(NN + 1) * 4);
    int*    bsum  = (int*)alloc(128 * 4);
    int*    boff  = (int*)alloc(128 * 4);
    u32*    ew    = (u32*)alloc((size_t)NE * 4);         // packed (w:f16<<17 | src); Set2Set aliases
    double* stats = (double*)alloc(256 * 8);
    float*  scale = (float*)alloc(128 * 4);
    float*  shift = (float*)alloc(128 * 4);

    f16*   xwh    = (f16*)xw;
    f16*   aggh   = (f16*)agg;
    u64*   degcnt = (u64*)agg;
    int*   rank   = (int*)((char*)agg + (1 << 20));
    u16*   gi_hi  = (u16*)xw;                        // gat phase: g hi plane in xw region
    float* esc    = dinv;
    int*   goff   = cnt;
    float* hs     = (float*)ew;
    float* csb    = hs + NB * H;
    float* qstar  = csb + NB * H;
    float* y1     = qstar + NB * 2 * H;

    const int GB_E = (NE + 255) / 256;
    const int GB_N = (NN + 255) / 256;
    const int NCH = (NN + 1023) / 1024;
    const int GB_MG = (NN + GBM - 1) / GBM;
    const int GB_SPMM = (NN + 31) / 32;

    // ---- all weight splits, one launch ----
    WJobs jobs;
    const float* Wl[9] = {lin_W, conv_W, conv_W + (size_t)H * H, conv_W + (size_t)2 * H * H,
                          conv_W + (size_t)3 * H * H, conv_W + (size_t)4 * H * H,
                          gat_in_W, gat_lin_W, gat_lin_W + (size_t)H * H};
    int Ks[9]  = {DIN, H, H, H, H, H, H + DGI, H, H};
    int Kps[9] = {96, H, H, H, H, H, 256, H, H};
    long long eoffs[9];
    long long eo = 0;
    for (int i = 0; i < 9; ++i) {
        jobs.W[i] = Wl[i]; jobs.K[i] = Ks[i]; jobs.Kpad[i] = Kps[i]; jobs.eoff[i] = eo;
        eoffs[i] = eo;
        eo += (long long)128 * Kps[i];
    }
    k_splitW_all<<<dim3(128, 2, 9), 128, 0, stream>>>(jobs, wthi, wtlo);

    // ---- graph norm + CSR ----
    hipMemsetAsync(degcnt, 0, (size_t)NN * 8, stream);
    hipMemsetAsync(stats, 0, 256 * 8, stream);
    k_deg2<<<GB_E, 256, 0, stream>>>(e_dst, edge_dist, degcnt, rank);
    k_dinv2<<<GB_N, 256, 0, stream>>>(degcnt, dinv, selfn, cnt);
    k_blocksum<<<NCH, 256, 0, stream>>>(cnt, bsum, NN);
    k_scanbsum<<<1, 64, 0, stream>>>(bsum, boff, NCH, rp + NN, NE);
    k_scanchunk<<<NCH, 1024, 0, stream>>>(cnt, boff, rp, NN);
    k_place2<<<GB_E, 256, 0, stream>>>(e_src, e_dst, edge_dist, dinv, rp, rank, ew);

    // ---- input projection: A staged directly from fp32 in_x ----
    k_mgemm<1, 1, 96, 2, 1><<<GB_MG, 256, 0, stream>>>(nullptr, nullptr, H, 96, nullptr, nullptr, H,
                                                       wthi + eoffs[0], wtlo + eoffs[0], lin_b,
                                                       nullptr, cx_hi, cx_lo, H, nullptr,
                                                       nullptr, nullptr, nullptr,
                                                       nullptr, nullptr, nullptr, nullptr, nullptr,
                                                       in_x, DIN, NN);

    // ---- conv stack (bnres of layer l-1 fused into A-staging of mgemm l) ----
    for (int l = 0; l < NL; ++l) {
        if (l == 0) {
            k_mgemm<0, 2, 128, 0, 1><<<GB_MG, 256, 0, stream>>>(cx_hi, cx_lo, H, H, cx_hi, cx_lo, H,
                                                                wthi + eoffs[1 + l], wtlo + eoffs[1 + l], nullptr,
                                                                nullptr, nullptr, nullptr, 0, xwh,
                                                                nullptr, nullptr, nullptr,
                                                                nullptr, nullptr, nullptr, nullptr, nullptr,
                                                                nullptr, 0, NN);
        } else {
            k_mgemm<0, 2, 128, 1, 1><<<GB_MG, 256, 0, stream>>>(cx_hi, cx_lo, H, H, cx_hi, cx_lo, H,
                                                                wthi + eoffs[1 + l], wtlo + eoffs[1 + l], nullptr,
                                                                nullptr, nullptr, nullptr, 0, xwh,
                                                                nullptr, nullptr, nullptr,
                                                                aggh, scale, shift, cx_hi, cx_lo,
                                                                nullptr, 0, NN);
        }
        k_spmm<<<GB_SPMM, 256, 0, stream>>>(xwh, rp, ew, selfn, conv_b + (size_t)l * H, aggh, stats);
        k_finalize<<<1, 128, 0, stream>>>(stats, bn_g, bn_b, scale, shift);
    }

    // ---- global attention (g path bf16 hi-only) ----
    k_mgemm<1, 4, 256, 3, 1><<<GB_MG, 256, 0, stream>>>(cx_hi, cx_lo, H, H, nullptr, nullptr, H,
                                                        wthi + eoffs[6], wtlo + eoffs[6], gat_in_b,
                                                        nullptr, gi_hi, nullptr, H, nullptr,
                                                        nullptr, nullptr, nullptr,
                                                        aggh, scale, shift, cx_hi, cx_lo,
                                                        global_info, DGI, NN);
    k_mgemm<1, 4, 128, 0, 0><<<GB_MG, 256, 0, stream>>>(gi_hi, nullptr, H, H, gi_hi, nullptr, H,
                                                        wthi + eoffs[7], wtlo + eoffs[7], gat_lin_b,
                                                        nullptr, gi_hi, nullptr, H, nullptr,
                                                        nullptr, nullptr, nullptr,
                                                        nullptr, nullptr, nullptr, nullptr, nullptr,
                                                        nullptr, 0, NN);
    k_mgemm<1, 3, 128, 0, 0><<<GB_MG, 256, 0, stream>>>(gi_hi, nullptr, H, H, gi_hi, nullptr, H,
                                                        wthi + eoffs[8], wtlo + eoffs[8], gat_lin_b + H,
                                                        nullptr, nullptr, nullptr, 0, nullptr,
                                                        gat_out_W, gat_out_b, esc,
                                                        nullptr, nullptr, nullptr, nullptr, nullptr,
                                                        nullptr, 0, NN);
    k_goff2<<<GB_N, 256, 0, stream>>>(batch, goff);
    // fused softmax + x scale (gi region dead after gat3; x16 overwrites it)
    k_ssmx<<<NB, 256, 0, stream>>>(esc, goff, cx_hi, cx_lo, (f16*)xw);

    // ---- Set2Set (hs/csb/qstar alias ew region, dead after conv stack) ----
    hipMemsetAsync(hs, 0, (size_t)NB * H * 4, stream);
    hipMemsetAsync(csb, 0, (size_t)NB * H * 4, stream);
    hipMemsetAsync(qstar, 0, (size_t)NB * 2 * H * 4, stream);
    for (int it = 0; it < 3; ++it) {
        k_gateslstm<<<NB / 8, 256, 0, stream>>>(qstar, lstm_Wih, lstm_Whh, lstm_bih, lstm_bhh, csb, hs);
        k_s2s<<<NB, 256, 0, stream>>>((const f16*)xw, hs, goff, esc, qstar);
    }

    // ---- head ----
    k_head1<<<NB, 256, 0, stream>>>(qstar, mlp_W, mlp_b, y1);
    k_head2<<<NB, 256, 0, stream>>>(y1, out1_W, out1_b, out2_W, out2_b, out);
}